// Round 5
// baseline (1776.603 us; speedup 1.0000x reference)
//
#include <hip/hip_runtime.h>
#include <hip/hip_bf16.h>
#include <type_traits>

#define DD    512
#define HH    8
#define HD    64
#define NLAYER 6
#define DFFN  2048
#define LATD  256
#define BB    4
#define LQQ   512
#define LCC   128

typedef unsigned short u16;
typedef __attribute__((ext_vector_type(8))) short bf16x8;
typedef __attribute__((ext_vector_type(4))) float f32x4;
typedef __attribute__((ext_vector_type(4))) unsigned short u16x4;

__device__ __forceinline__ u16 f2bf(float f) {
    __hip_bfloat16 h = __float2bfloat16(f);
    return __builtin_bit_cast(u16, h);
}
__device__ __forceinline__ float bf2f(u16 u) {
    return __uint_as_float(((unsigned int)u) << 16);
}

// ---------------------------------------------------------------------------
// MFMA bf16 GEMM, all operands bf16, B is [N][K] row-major.
// BK=64, LDS double-buffer + 2-slot register pipeline (round-7, verified).
// MULTI: blockIdx.z selects (B,C) from up to 3; else z=zb*Hdim+zh batches.
// wt: transposed epilogue C[gn*ldct + (gm>>wt_shift)*sbT + (gm&mask)].
// normal: v=alpha*acc + bias[n]; act==1 exact gelu; += res[(gm>>rs)*ldres+gn].
// ---------------------------------------------------------------------------
template<int BM, int BN, typename TC, bool MULTI>
__global__ __launch_bounds__(256)
void k_g(const u16* __restrict__ A, long long sAb, long long sAh, int lda,
         const u16* __restrict__ B1, const u16* __restrict__ B2_, const u16* __restrict__ B3_,
         long long sBb, long long sBh, int ldb,
         TC* __restrict__ C1, TC* __restrict__ C2_, TC* __restrict__ C3_,
         long long sCb, long long sCh, int ldc,
         int K, int Hdim, float alpha,
         const float* __restrict__ bias,
         const float* __restrict__ res, int ldres, int res_shift,
         float beta2, const u16* __restrict__ add2, long long s2b, long long s2h,
         int act, int wt_mask, int wt_shift, long long sbT, int ldct)
{
    constexpr int SK = 72;
    constexpr int FM = BM / 32, FN = BN / 32;
    constexpr int PA = BM / 32, PB = BN / 32;

    const int z = blockIdx.z;
    const u16* Bm;
    TC* C;
    int wt;
    if constexpr (MULTI) {
        Bm = (z == 0) ? B1 : ((z == 1) ? B2_ : B3_);
        C  = (z == 0) ? C1 : ((z == 1) ? C2_ : C3_);
        wt = (wt_mask >> z) & 1;
    } else {
        const int zb = z / Hdim, zh = z % Hdim;
        A += (size_t)(zb * sAb + zh * sAh);
        Bm = B1 + (size_t)(zb * sBb + zh * sBh);
        C  = C1 + (size_t)(zb * sCb + zh * sCh);
        if (add2) add2 += (size_t)(zb * s2b + zh * s2h);
        wt = wt_mask & 1;
    }

    __shared__ u16 Asm[2][BM * SK];
    __shared__ u16 Bsm[2][BN * SK];

    const int t    = threadIdx.x;
    const int wid  = t >> 6, lane = t & 63;
    const int q    = lane >> 4, c = lane & 15;
    const int wm   = (wid >> 1) * (BM / 2), wn = (wid & 1) * (BN / 2);
    const int m0   = blockIdx.y * BM, n0 = blockIdx.x * BN;

    f32x4 acc[FM][FN];
    #pragma unroll
    for (int i = 0; i < FM; i++)
        #pragma unroll
        for (int j = 0; j < FN; j++) acc[i][j] = (f32x4){0.f, 0.f, 0.f, 0.f};

    uint4 ra[2][PA], rb[2][PB];
    const int NI = K >> 6;

    auto loadg = [&](int slot, int kt) {
        #pragma unroll
        for (int p = 0; p < PA; p++) {
            const int idx = p * 256 + t, r = idx >> 3, kg = (idx & 7) << 3;
            ra[slot][p] = *(const uint4*)(A + (size_t)(m0 + r) * lda + kt + kg);
        }
        #pragma unroll
        for (int p = 0; p < PB; p++) {
            const int idx = p * 256 + t, r = idx >> 3, kg = (idx & 7) << 3;
            rb[slot][p] = *(const uint4*)(Bm + (size_t)(n0 + r) * ldb + kt + kg);
        }
    };
    auto store = [&](int buf, int slot) {
        #pragma unroll
        for (int p = 0; p < PA; p++) {
            const int idx = p * 256 + t, r = idx >> 3, kg = (idx & 7) << 3;
            *(uint4*)&Asm[buf][r * SK + kg] = ra[slot][p];
        }
        #pragma unroll
        for (int p = 0; p < PB; p++) {
            const int idx = p * 256 + t, r = idx >> 3, kg = (idx & 7) << 3;
            *(uint4*)&Bsm[buf][r * SK + kg] = rb[slot][p];
        }
    };

    loadg(0, 0);
    if (NI > 1) loadg(1, 64);
    store(0, 0);

    for (int it = 0; it < NI; it++) {
        __syncthreads();
        const int cur = it & 1, nxt = cur ^ 1;
        if (it + 1 < NI) store(nxt, nxt);
        if (it + 2 < NI) loadg(cur, (it + 2) << 6);
        #pragma unroll
        for (int s = 0; s < 2; s++) {
            bf16x8 af[FM], bfv[FN];
            #pragma unroll
            for (int fm = 0; fm < FM; fm++)
                af[fm] = *(const bf16x8*)&Asm[cur][(wm + fm * 16 + c) * SK + s * 32 + q * 8];
            #pragma unroll
            for (int fn = 0; fn < FN; fn++)
                bfv[fn] = *(const bf16x8*)&Bsm[cur][(wn + fn * 16 + c) * SK + s * 32 + q * 8];
            #pragma unroll
            for (int fm = 0; fm < FM; fm++)
                #pragma unroll
                for (int fn = 0; fn < FN; fn++)
                    acc[fm][fn] = __builtin_amdgcn_mfma_f32_16x16x32_bf16(
                        af[fm], bfv[fn], acc[fm][fn], 0, 0, 0);
        }
    }

    if (wt) {
        if constexpr (std::is_same<TC, u16>::value) {
            #pragma unroll
            for (int fm = 0; fm < FM; fm++) {
                const int gm0 = m0 + wm + fm * 16 + q * 4;
                const long long roff =
                    (long long)(gm0 >> wt_shift) * sbT + (gm0 & ((1 << wt_shift) - 1));
                #pragma unroll
                for (int fn = 0; fn < FN; fn++) {
                    const int gn = n0 + wn + fn * 16 + c;
                    const long long a0 = (long long)gn * ldct + roff;
                    u16x4 o;
                    if (add2) {
                        const u16x4 av = *(const u16x4*)&add2[a0];
                        #pragma unroll
                        for (int r = 0; r < 4; r++)
                            o[r] = f2bf(alpha * acc[fm][fn][r] + beta2 * bf2f(av[r]));
                    } else {
                        #pragma unroll
                        for (int r = 0; r < 4; r++)
                            o[r] = f2bf(alpha * acc[fm][fn][r]);
                    }
                    *(u16x4*)&C[a0] = o;
                }
            }
        }
    } else {
        #pragma unroll
        for (int fm = 0; fm < FM; fm++) {
            #pragma unroll
            for (int reg = 0; reg < 4; reg++) {
                const int gm = m0 + wm + fm * 16 + q * 4 + reg;
                #pragma unroll
                for (int fn = 0; fn < FN; fn++) {
                    const int gn = n0 + wn + fn * 16 + c;
                    float v = alpha * acc[fm][fn][reg];
                    if (bias) v += bias[gn];
                    if (act == 1) v = 0.5f * v * (1.0f + erff(v * 0.7071067811865475f));
                    if (res)  v += res[(size_t)(gm >> res_shift) * ldres + gn];
                    if constexpr (std::is_same<TC, u16>::value)
                        C[(size_t)gm * ldc + gn] = f2bf(v);
                    else
                        C[(size_t)gm * ldc + gn] = v;
                }
            }
        }
    }
}

// ---------------------------------------------------------------------------
// 128x128-tile GEMM (m97 structure): global_load_lds width-16 staging,
// XOR-swizzled LDS (linear dest + inverse-swizzled global src + swizzled
// ds_read -> 2-way bank conflicts only). 4 waves (2x2), 64x64 per wave.
// A [M][K] bf16, B [N][K] bf16 row-major, K = per-z-chunk depth (mult of 64);
// blockIdx.z selects K-chunk z*K (split-K).
// ATOMIC: fp32 atomicAdd into C (bias added by z==0 only); else normal
// epilogue: v = acc + bias[n]; act==1 exact gelu; += res; store TC.
// ---------------------------------------------------------------------------
template<typename TC, bool ATOMIC>
__global__ __launch_bounds__(256)
void k_g128(const u16* __restrict__ A, int lda,
            const u16* __restrict__ B, int ldb,
            TC* __restrict__ C, int ldc, int K,
            const float* __restrict__ bias,
            const float* __restrict__ res, int ldres, int act)
{
    __shared__ u16 As[128 * 64];
    __shared__ u16 Bs[128 * 64];

    const int t = threadIdx.x, wid = t >> 6, lane = t & 63;
    const int q = lane >> 4, c = lane & 15;
    const int wr = wid >> 1, wc = wid & 1;
    const int m0 = blockIdx.y * 128, n0 = blockIdx.x * 128;
    const int kz = blockIdx.z * K;

    const int lr  = lane >> 3;   // row within 8-row chunk
    const int lkb = lane & 7;    // dest 16B-block within row

    f32x4 acc[4][4];
    #pragma unroll
    for (int i = 0; i < 4; i++)
        #pragma unroll
        for (int j = 0; j < 4; j++) acc[i][j] = (f32x4){0.f, 0.f, 0.f, 0.f};

    const int NI = K >> 6;
    for (int it = 0; it < NI; it++) {
        const int kt = kz + (it << 6);
        #pragma unroll
        for (int j = 0; j < 4; j++) {
            const int r  = wid * 32 + j * 8 + lr;
            const int kb = lkb ^ (r & 7);          // inverse-swizzled source block
            const u16* ga = A + (size_t)(m0 + r) * lda + kt + kb * 8;
            const u16* gb = B + (size_t)(n0 + r) * ldb + kt + kb * 8;
            u16* la = &As[(wid * 32 + j * 8) * 64];   // wave-uniform LDS base
            u16* lb = &Bs[(wid * 32 + j * 8) * 64];
            __builtin_amdgcn_global_load_lds(
                (const __attribute__((address_space(1))) void*)ga,
                (__attribute__((address_space(3))) void*)la, 16, 0, 0);
            __builtin_amdgcn_global_load_lds(
                (const __attribute__((address_space(1))) void*)gb,
                (__attribute__((address_space(3))) void*)lb, 16, 0, 0);
        }
        __syncthreads();
        #pragma unroll
        for (int s = 0; s < 2; s++) {
            bf16x8 af[4], bfv[4];
            #pragma unroll
            for (int fm = 0; fm < 4; fm++) {
                const int row = wr * 64 + fm * 16 + c;
                const int blk = (s * 4 + q) ^ (row & 7);   // swizzled read
                af[fm] = *(const bf16x8*)&As[row * 64 + blk * 8];
            }
            #pragma unroll
            for (int fn = 0; fn < 4; fn++) {
                const int row = wc * 64 + fn * 16 + c;
                const int blk = (s * 4 + q) ^ (row & 7);
                bfv[fn] = *(const bf16x8*)&Bs[row * 64 + blk * 8];
            }
            #pragma unroll
            for (int fm = 0; fm < 4; fm++)
                #pragma unroll
                for (int fn = 0; fn < 4; fn++)
                    acc[fm][fn] = __builtin_amdgcn_mfma_f32_16x16x32_bf16(
                        af[fm], bfv[fn], acc[fm][fn], 0, 0, 0);
        }
        __syncthreads();
    }

    #pragma unroll
    for (int fm = 0; fm < 4; fm++) {
        #pragma unroll
        for (int reg = 0; reg < 4; reg++) {
            const int gm = m0 + wr * 64 + fm * 16 + q * 4 + reg;
            #pragma unroll
            for (int fn = 0; fn < 4; fn++) {
                const int gn = n0 + wc * 64 + fn * 16 + c;
                float v = acc[fm][fn][reg];
                if constexpr (ATOMIC) {
                    if (bias && blockIdx.z == 0) v += bias[gn];
                    atomicAdd((float*)&C[(size_t)gm * ldc + gn], v);
                } else {
                    if (bias) v += bias[gn];
                    if (act == 1) v = 0.5f * v * (1.0f + erff(v * 0.7071067811865475f));
                    if (res)  v += res[(size_t)gm * ldres + gn];
                    if constexpr (std::is_same<TC, u16>::value)
                        C[(size_t)gm * ldc + gn] = f2bf(v);
                    else
                        C[(size_t)gm * ldc + gn] = v;
                }
            }
        }
    }
}

// ---------------------------------------------------------------------------
// Fused attention: one block = 64 q-rows x one (b,h) head.
// MODE 0 (cross) : LK=128, key mask, epilogue writes ob rows [B*LQ, DD].
// MODE 1 (self A): LK=512, u = P@v, epilogue wT[b,h,64,512] = (0.5u+0.5v)^T.
// MODE 2 (self B): LK=512, RECOMPUTES S+softmax (bit-identical to MODE 1),
//                  then ob = P @ wT (vT arg = wT buffer), row-major epilogue.
// ---------------------------------------------------------------------------
template<int MODE>
__global__ __launch_bounds__(256)
void k_attn(const u16* __restrict__ qb, const u16* __restrict__ kb,
            const u16* __restrict__ vT, u16* __restrict__ uout,
            const float* __restrict__ mask, float alpha)
{
    constexpr bool CROSS = (MODE == 0);
    constexpr int LK  = CROSS ? LCC : LQQ;
    constexpr int NCT = LK / 128;
    constexpr int NJ  = LK / 16;
    constexpr int SM1 = 64 * 72 * 2 + (CROSS ? 1 : 2) * 128 * 72 * 2;
    constexpr int SM2 = 2 * 64 * 136 * 2;
    constexpr int SMEM = SM1 > SM2 ? SM1 : SM2;
    __shared__ char smem[SMEM];
    u16* Qs = (u16*)smem;
    u16* Ks = (u16*)(smem + 64 * 72 * 2);
    u16* Ps = (u16*)smem;
    u16* Vs = (u16*)(smem + 64 * 136 * 2);

    const int z = blockIdx.z, b = z >> 3, hh = z & 7;
    const int m0 = blockIdx.y * 64;
    const int t = threadIdx.x, w = t >> 6, lane = t & 63;
    const int q = lane >> 4, c = lane & 15;

    const u16* qbase = qb + ((size_t)(b * LQQ + m0)) * DD + hh * HD;
    const u16* kbase = kb + ((size_t)b * LK) * DD + hh * HD;
    const u16* vbase = vT + (size_t)z * HD * LK;

    // ---- stage Q (64 x 64) ----
    #pragma unroll
    for (int p = 0; p < 2; p++) {
        const int idx = p * 256 + t, r = idx >> 3, kg = (idx & 7) << 3;
        *(uint4*)&Qs[r * 72 + kg] = *(const uint4*)(qbase + (size_t)r * DD + kg);
    }

    f32x4 acc[NJ];
    #pragma unroll
    for (int j = 0; j < NJ; j++) acc[j] = (f32x4){0.f, 0.f, 0.f, 0.f};

    auto stageK = [&](u16* dst, int ct) {
        #pragma unroll
        for (int p = 0; p < 4; p++) {
            const int idx = p * 256 + t, r = idx >> 3, kg = (idx & 7) << 3;
            *(uint4*)&dst[r * 72 + kg] =
                *(const uint4*)(kbase + (size_t)(ct * 128 + r) * DD + kg);
        }
    };

    stageK(Ks, 0);
    __syncthreads();
    #pragma unroll
    for (int ct = 0; ct < NCT; ct++) {
        u16* cur = Ks + (!CROSS ? (ct & 1) * (128 * 72) : 0);
        if (!CROSS && ct + 1 < NCT)
            stageK(Ks + ((ct + 1) & 1) * (128 * 72), ct + 1);
        #pragma unroll
        for (int s = 0; s < 2; s++) {
            const bf16x8 af = *(const bf16x8*)&Qs[(w * 16 + c) * 72 + s * 32 + q * 8];
            #pragma unroll
            for (int fn = 0; fn < 8; fn++) {
                const bf16x8 bv = *(const bf16x8*)&cur[(fn * 16 + c) * 72 + s * 32 + q * 8];
                acc[ct * 8 + fn] = __builtin_amdgcn_mfma_f32_16x16x32_bf16(
                    af, bv, acc[ct * 8 + fn], 0, 0, 0);
            }
        }
        if (!CROSS && ct + 1 < NCT) __syncthreads();
    }

    // ---- row softmax (rows q*4+reg per wave; cols j*16+c) ----
    bool msk[NJ];
    #pragma unroll
    for (int j = 0; j < NJ; j++) {
        msk[j] = false;
        if (CROSS && mask) msk[j] = (mask[b * LCC + j * 16 + c] == 0.0f);
    }
    float mx[4] = {-3.402823466e38f, -3.402823466e38f, -3.402823466e38f, -3.402823466e38f};
    #pragma unroll
    for (int j = 0; j < NJ; j++)
        #pragma unroll
        for (int r = 0; r < 4; r++) {
            float x = alpha * acc[j][r];
            if (msk[j]) x = -3.402823466e38f;
            acc[j][r] = x;
            mx[r] = fmaxf(mx[r], x);
        }
    #pragma unroll
    for (int r = 0; r < 4; r++)
        #pragma unroll
        for (int m = 8; m; m >>= 1) mx[r] = fmaxf(mx[r], __shfl_xor(mx[r], m, 64));
    float sum[4] = {0.f, 0.f, 0.f, 0.f};
    #pragma unroll
    for (int j = 0; j < NJ; j++)
        #pragma unroll
        for (int r = 0; r < 4; r++) {
            const float e = expf(acc[j][r] - mx[r]);
            acc[j][r] = e;
            sum[r] += e;
        }
    #pragma unroll
    for (int r = 0; r < 4; r++)
        #pragma unroll
        for (int m = 8; m; m >>= 1) sum[r] += __shfl_xor(sum[r], m, 64);
    #pragma unroll
    for (int r = 0; r < 4; r++) sum[r] = 1.0f / sum[r];
    #pragma unroll
    for (int j = 0; j < NJ; j++)
        #pragma unroll
        for (int r = 0; r < 4; r++) acc[j][r] *= sum[r];

    // ---- phase 2: u = P @ v (MODE 0/1) or ob = P @ wT (MODE 2) ----
    f32x4 ua[4];
    #pragma unroll
    for (int fn = 0; fn < 4; fn++) ua[fn] = (f32x4){0.f, 0.f, 0.f, 0.f};

    __syncthreads();   // phase boundary: Qs/Ks -> Ps/Vs alias
    #pragma unroll
    for (int ct = 0; ct < NCT; ct++) {
        #pragma unroll
        for (int j = 0; j < 8; j++)
            #pragma unroll
            for (int r = 0; r < 4; r++)
                Ps[(w * 16 + q * 4 + r) * 136 + j * 16 + c] = f2bf(acc[ct * 8 + j][r]);
        #pragma unroll
        for (int p = 0; p < 4; p++) {
            const int idx = p * 256 + t, rr = idx >> 4, kg = (idx & 15) << 3;
            *(uint4*)&Vs[rr * 136 + kg] =
                *(const uint4*)(vbase + (size_t)rr * LK + ct * 128 + kg);
        }
        __syncthreads();
        #pragma unroll
        for (int ks = 0; ks < 4; ks++) {
            const bf16x8 af = *(const bf16x8*)&Ps[(w * 16 + c) * 136 + ks * 32 + q * 8];
            #pragma unroll
            for (int fn = 0; fn < 4; fn++) {
                const bf16x8 bv = *(const bf16x8*)&Vs[(fn * 16 + c) * 136 + ks * 32 + q * 8];
                ua[fn] = __builtin_amdgcn_mfma_f32_16x16x32_bf16(af, bv, ua[fn], 0, 0, 0);
            }
        }
        if (ct + 1 < NCT) __syncthreads();
    }

    // ---- epilogue ----
    if (MODE == 1) {
        #pragma unroll
        for (int fn = 0; fn < 4; fn++) {
            const int col = fn * 16 + c;
            const size_t a0 = ((size_t)z * HD + col) * LQQ + m0 + w * 16 + q * 4;
            const u16x4 vv = *(const u16x4*)&vT[a0];
            u16x4 o;
            #pragma unroll
            for (int r = 0; r < 4; r++)
                o[r] = f2bf(0.5f * ua[fn][r] + 0.5f * bf2f(vv[r]));
            *(u16x4*)&uout[a0] = o;
        }
    } else {
        #pragma unroll
        for (int fn = 0; fn < 4; fn++)
            #pragma unroll
            for (int r = 0; r < 4; r++)
                uout[((size_t)b * LQQ + m0 + w * 16 + q * 4 + r) * DD + hh * HD + fn * 16 + c] =
                    f2bf(ua[fn][r]);
    }
}

// ---------------------------------------------------------------------------
#define NSEG 14
struct CvtArgs {
    const float* src[NSEG];
    u16*         dst[NSEG];
    int          beg[NSEG + 1];
    int          n4[NSEG];
};

__global__ __launch_bounds__(256)
void k_cvtm(CvtArgs a)
{
    const int blk = blockIdx.x;
    int s = 0;
    #pragma unroll
    for (int i = 1; i < NSEG; i++) if (blk >= a.beg[i]) s = i;
    const int i4 = (blk - a.beg[s]) * 256 + threadIdx.x;
    if (i4 >= a.n4[s]) return;
    const float4 v = *(const float4*)(a.src[s] + (size_t)i4 * 4);
    u16x4 u = { f2bf(v.x), f2bf(v.y), f2bf(v.z), f2bf(v.w) };
    *(u16x4*)(a.dst[s] + (size_t)i4 * 4) = u;
}

// ---------------------------------------------------------------------------
__global__ __launch_bounds__(256)
void k_ln(const float* __restrict__ X, u16* __restrict__ Y,
          const float* __restrict__ g, const float* __restrict__ b)
{
    const int row  = blockIdx.x * 4 + threadIdx.y;
    const int lane = threadIdx.x;
    const float* x = X + (size_t)row * DD;
    float v[8];
    float s = 0.0f;
    #pragma unroll
    for (int i = 0; i < 8; i++) { v[i] = x[lane + i * 64]; s += v[i]; }
    #pragma unroll
    for (int off = 32; off; off >>= 1) s += __shfl_xor(s, off, 64);
    const float m = s * (1.0f / 512.0f);
    float qq = 0.0f;
    #pragma unroll
    for (int i = 0; i < 8; i++) { const float d = v[i] - m; qq += d * d; }
    #pragma unroll
    for (int off = 32; off; off >>= 1) qq += __shfl_xor(qq, off, 64);
    const float r = rsqrtf(qq * (1.0f / 512.0f) + 1e-5f);
    u16* y = Y + (size_t)row * DD;
    #pragma unroll
    for (int i = 0; i < 8; i++) {
        const int c = lane + i * 64;
        y[c] = f2bf((v[i] - m) * r * g[c] + b[c]);
    }
}

// ---------------------------------------------------------------------------
__global__ void k_emb(const int* __restrict__ t, float* __restrict__ emb)
{
    const int idx = blockIdx.x * 256 + threadIdx.x;
    if (idx >= BB * DD) return;
    const int b = idx / DD, c = idx % DD;
    const int j = (c < 256) ? c : (c - 256);
    const float freq = expf((float)j * (-9.210340371976184f / 255.0f));
    const float arg = (float)t[b] * freq;
    emb[idx] = (c < 256) ? sinf(arg) : cosf(arg);
}

__global__ __launch_bounds__(256)
void k_wlin(const float* __restrict__ in, int K,
            const float* __restrict__ W, const float* __restrict__ bias,
            float* __restrict__ out, int N, int act)
{
    const int gw   = blockIdx.x * 4 + (threadIdx.x >> 6);
    const int lane = threadIdx.x & 63;
    const int b = gw / N, n = gw % N;
    const float* x = in + (size_t)b * K;
    const float* w = W + (size_t)n * K;
    float s = 0.0f;
    for (int k = lane; k < K; k += 64) s += x[k] * w[k];
    #pragma unroll
    for (int off = 32; off; off >>= 1) s += __shfl_xor(s, off, 64);
    if (lane == 0) {
        s += bias[n];
        if (act == 2) s = s / (1.0f + expf(-s));
        out[gw] = s;
    }
}

// ---------------------------------------------------------------------------

extern "C" void kernel_launch(void* const* d_in, const int* in_sizes, int n_in,
                              void* d_out, int out_size, void* d_ws, size_t ws_size,
                              hipStream_t stream)
{
    const float* x_t   = (const float*)d_in[0];
    const int*   tarr  = (const int*)  d_in[1];
    const float* cond  = (const float*)d_in[2];
    const float* cmask = (const float*)d_in[3];
    const float* sa_qw = (const float*)d_in[4];
    const float* sa_kw = (const float*)d_in[5];
    const float* sa_vw = (const float*)d_in[6];
    const float* sa_ow = (const float*)d_in[7];
    const float* sa_ob = (const float*)d_in[8];
    const float* ca_qw = (const float*)d_in[9];
    const float* ca_kw = (const float*)d_in[10];
    const float* ca_vw = (const float*)d_in[11];
    const float* ca_ow = (const float*)d_in[12];
    const float* ca_ob = (const float*)d_in[13];
    const float* f1w   = (const float*)d_in[14];
    const float* f1b   = (const float*)d_in[15];
    const float* f2w   = (const float*)d_in[16];
    const float* f2b   = (const float*)d_in[17];
    const float* n1g   = (const float*)d_in[18];
    const float* n1b   = (const float*)d_in[19];
    const float* n2g   = (const float*)d_in[20];
    const float* n2b   = (const float*)d_in[21];
    const float* n3g   = (const float*)d_in[22];
    const float* n3b   = (const float*)d_in[23];
    const float* tm1w  = (const float*)d_in[24];
    const float* tm1b  = (const float*)d_in[25];
    const float* tm2w  = (const float*)d_in[26];
    const float* tm2b  = (const float*)d_in[27];
    const float* ttw   = (const float*)d_in[28];
    const float* ttb   = (const float*)d_in[29];
    const float* pinw  = (const float*)d_in[30];
    const float* pinb  = (const float*)d_in[31];
    const float* poutw = (const float*)d_in[32];
    const float* poutb = (const float*)d_in[33];
    const float* fng   = (const float*)d_in[34];
    const float* fnb   = (const float*)d_in[35];

    const int M = BB * LQQ; // 2048
    const size_t MB = 1048576;

    char* w8 = (char*)d_ws;
    float* h   = (float*)(w8);                      // [2048,512] fp32  4 MB
    u16*  xn  = (u16*)(w8 +  4 * MB);               // 2 MB
    u16*  qb  = (u16*)(w8 +  6 * MB);               // 2 MB
    u16*  kb  = (u16*)(w8 +  8 * MB);               // 2 MB (self K)
    u16*  vbT = (u16*)(w8 + 10 * MB);               // [B,H,64,512] 2 MB
    u16*  ubT = (u16*)(w8 + 12 * MB);               // [B,H,64,512] wT 2 MB
    u16*  ob  = (u16*)(w8 + 14 * MB);               // 2 MB
    u16*  a1  = (u16*)(w8 + 16 * MB);               // FFN hidden 8 MB
    u16*  xtb = (u16*)(w8 + 16 * MB);               // aliases a1 (dead before FFN)
    u16*  cdb = (u16*)(w8 + 17 * MB);               // aliases a1 (dead before FFN)
    u16*  kbc6 = (u16*)(w8 + 32 * MB);              // 6 x [B*LCC, DD] = 3 MB
    u16*  vcT6 = (u16*)(w8 + 35 * MB);              // 6 x [B,H,64,128] = 3 MB
    float* emb = (float*)(w8 + 38 * MB);
    float* h1t = emb + BB * DD;
    float* te  = h1t + BB * DFFN;
    float* ttv = te  + BB * DD;
    u16* wq  = (u16*)(w8 + 39 * MB);
    u16* wk  = (u16*)(w8 + 42 * MB);
    u16* wv  = (u16*)(w8 + 45 * MB);
    u16* wo  = (u16*)(w8 + 48 * MB);
    u16* cwq = (u16*)(w8 + 51 * MB);
    u16* cwk = (u16*)(w8 + 54 * MB);
    u16* cwv = (u16*)(w8 + 57 * MB);
    u16* cwo = (u16*)(w8 + 60 * MB);
    u16* w1  = (u16*)(w8 + 63 * MB);                // 12 MB
    u16* w2  = (u16*)(w8 + 75 * MB);                // 12 MB
    u16* wpi = (u16*)(w8 + 87 * MB);                // 256 KB
    u16* wpo = (u16*)(w8 + 87 * MB + 262144);       // 256 KB

    const dim3 T256(256);
    const dim3 LN_B(64, 4);
    const long long ZVT = (long long)HH * HD * LQQ; // 262144
    const long long ZWT = (long long)HH * HD * LCC; // 65536

    // ---- one fused bf16 conversion dispatch ----
    {
        const int NW4 = NLAYER * DD * DD / 4;
        const int NF4 = NLAYER * DFFN * DD / 4;
        CvtArgs a;
        const float* srcs[NSEG] = { sa_qw, sa_kw, sa_vw, sa_ow, ca_qw, ca_kw, ca_vw, ca_ow,
                                    f1w, f2w, pinw, poutw, x_t, cond };
        u16* dsts[NSEG] = { wq, wk, wv, wo, cwq, cwk, cwv, cwo,
                            w1, w2, wpi, wpo, xtb, cdb };
        const int n4s[NSEG] = { NW4, NW4, NW4, NW4, NW4, NW4, NW4, NW4,
                                NF4, NF4, DD * LATD / 4, LATD * DD / 4,
                                M * LATD / 4, BB * LCC * DD / 4 };
        int acc = 0;
        for (int i = 0; i < NSEG; i++) {
            a.src[i] = srcs[i]; a.dst[i] = dsts[i]; a.n4[i] = n4s[i];
            a.beg[i] = acc; acc += (n4s[i] + 255) / 256;
        }
        a.beg[NSEG] = acc;
        k_cvtm<<<acc, T256, 0, stream>>>(a);
    }

    // ---- time embedding path ----
    k_emb<<<(BB * DD + 255) / 256, 256, 0, stream>>>(tarr, emb);
    k_wlin<<<(BB * DFFN) / 4, T256, 0, stream>>>(emb, DD, tm1w, tm1b, h1t, DFFN, 2);
    k_wlin<<<(BB * DD) / 4,   T256, 0, stream>>>(h1t, DFFN, tm2w, tm2b, te, DD, 0);
    k_wlin<<<(BB * DD) / 4,   T256, 0, stream>>>(te, DD, ttw, ttb, ttv, DD, 0);

    // ---- all-layer cross K: kbc6[L] = cond @ ckw[L]^T  (z = layer) ----
    k_g<32, 64, u16, false><<<dim3(DD / 64, (BB * LCC) / 32, NLAYER), T256, 0, stream>>>(
        cdb, 0, 0, DD, cwk, nullptr, nullptr, 0, (long long)DD * DD, DD,
        kbc6, nullptr, nullptr, 0, (long long)BB * LCC * DD, DD,
        DD, NLAYER, 1.0f, nullptr, nullptr, 0, 0, 0.0f, nullptr, 0, 0, 0, 0, 0, 0, 0);
    // ---- all-layer cross V (transposed): vcT6[L] ----
    k_g<32, 64, u16, false><<<dim3(DD / 64, (BB * LCC) / 32, NLAYER), T256, 0, stream>>>(
        cdb, 0, 0, DD, cwv, nullptr, nullptr, 0, (long long)DD * DD, DD,
        vcT6, nullptr, nullptr, 0, (long long)BB * HH * HD * LCC, DD,
        DD, NLAYER, 1.0f, nullptr, nullptr, 0, 0, 0.0f, nullptr, 0, 0, 0,
        /*wt=*/1, /*shift=*/7, /*sbT=*/ZWT, /*ldct=*/LCC);

    // ---- input projection: h = x_t @ pinw.T + pinb + ttv[b] ----
    k_g<32, 64, float, false><<<dim3(DD / 64, M / 32, 1), T256, 0, stream>>>(
        xtb, 0, 0, LATD, wpi, nullptr, nullptr, 0, 0, LATD,
        h, nullptr, nullptr, 0, 0, DD,
        LATD, 1, 1.0f, pinb, ttv, DD, 9, 0.0f, nullptr, 0, 0, 0, 0, 0, 0, 0);

    for (int L = 0; L < NLAYER; L++) {
        const size_t LW = (size_t)L * DD * DD;

        // ======== self-attention with QGFD (P never materialized) ========
        k_ln<<<M / 4, LN_B, 0, stream>>>(h, xn, n1g + (size_t)L * DD, n1b + (size_t)L * DD);

        // fused QKV (z: 0=q, 1=k, 2=v transposed)
        k_g<64, 64, u16, true><<<dim3(DD / 64, M / 64, 3), T256, 0, stream>>>(
            xn, 0, 0, DD, wq + LW, wk + LW, wv + LW, 0, 0, DD,
            qb, kb, vbT, 0, 0, DD,
            DD, 1, 1.0f, nullptr, nullptr, 0, 0, 0.0f, nullptr, 0, 0, 0,
            /*wt_mask=*/4, /*wt_shift=*/9, /*sbT=*/ZVT, /*ldct=*/LQQ);

        // pass A: S+softmax+u=P@v, wT = (0.5u+0.5v)^T   (no P write)
        k_attn<1><<<dim3(1, LQQ / 64, BB * HH), T256, 0, stream>>>(
            qb, kb, vbT, ubT, nullptr, 0.125f);

        // pass B: recompute S+softmax, ob = P @ wT
        k_attn<2><<<dim3(1, LQQ / 64, BB * HH), T256, 0, stream>>>(
            qb, kb, ubT, ob, nullptr, 0.125f);

        // h += ob @ ow.T + obias   (128x128 split-K=4, fp32 atomicAdd into h)
        k_g128<float, true><<<dim3(DD / 128, M / 128, 4), T256, 0, stream>>>(
            ob, DD, wo + LW, DD,
            h, DD, 128, sa_ob + (size_t)L * DD, nullptr, 0, 0);

        // ======== cross-attention ========
        k_ln<<<M / 4, LN_B, 0, stream>>>(h, xn, n2g + (size_t)L * DD, n2b + (size_t)L * DD);

        k_g<32, 64, u16, false><<<dim3(DD / 64, M / 32, 1), T256, 0, stream>>>(
            xn, 0, 0, DD, cwq + LW, nullptr, nullptr, 0, 0, DD,
            qb, nullptr, nullptr, 0, 0, DD,
            DD, 1, 1.0f, nullptr, nullptr, 0, 0, 0.0f, nullptr, 0, 0, 0, 0, 0, 0, 0);

        // fused Sc+mask+softmax+Pc@vc -> ob
        k_attn<0><<<dim3(1, LQQ / 64, BB * HH), T256, 0, stream>>>(
            qb, kbc6 + (size_t)L * BB * LCC * DD, vcT6 + (size_t)L * BB * HH * HD * LCC,
            ob, cmask, 0.125f);

        // h += ob @ cow.T + cob   (128x128 split-K=4, fp32 atomicAdd into h)
        k_g128<float, true><<<dim3(DD / 128, M / 128, 4), T256, 0, stream>>>(
            ob, DD, cwo + LW, DD,
            h, DD, 128, ca_ob + (size_t)L * DD, nullptr, 0, 0);

        // ======== FFN ========
        k_ln<<<M / 4, LN_B, 0, stream>>>(h, xn, n3g + (size_t)L * DD, n3b + (size_t)L * DD);

        // w1: 128x128 m97-structure kernel (grid 16x16 = 256 blocks = 1/CU)
        k_g128<u16, false><<<dim3(DFFN / 128, M / 128, 1), T256, 0, stream>>>(
            xn, DD, w1 + (size_t)L * DFFN * DD, DD,
            a1, DFFN, DD, f1b + (size_t)L * DFFN, nullptr, 0, /*act=*/1);

        // w2: 128x128 split-K=4 (grid 4x16x4 = 256 blocks), fp32 atomicAdd
        // into h (residual already there; bias added by z==0 chunk)
        k_g128<float, true><<<dim3(DD / 128, M / 128, 4), T256, 0, stream>>>(
            a1, DFFN, w2 + (size_t)L * DD * DFFN, DFFN,
            h, DD, 512, f2b + (size_t)L * DD, nullptr, 0, 0);
    }

    // ---- final LN + output projection ----
    k_ln<<<M / 4, LN_B, 0, stream>>>(h, xn, fng, fnb);
    k_g<32, 32, float, false><<<dim3(LATD / 32, M / 32, 1), T256, 0, stream>>>(
        xn, 0, 0, DD, wpo, nullptr, nullptr, 0, 0, DD,
        (float*)d_out, nullptr, nullptr, 0, 0, LATD,
        DD, 1, 1.0f, poutb, nullptr, 0, 0, 0.0f, nullptr, 0, 0, 0, 0, 0, 0, 0);
}

// Round 6
// 1356.490 us; speedup vs baseline: 1.3097x; 1.3097x over previous
//
#include <hip/hip_runtime.h>
#include <hip/hip_bf16.h>
#include <type_traits>

#define DD    512
#define HH    8
#define HD    64
#define NLAYER 6
#define DFFN  2048
#define LATD  256
#define BB    4
#define LQQ   512
#define LCC   128

typedef unsigned short u16;
typedef __attribute__((ext_vector_type(8))) short bf16x8;
typedef __attribute__((ext_vector_type(4))) float f32x4;
typedef __attribute__((ext_vector_type(4))) unsigned short u16x4;

__device__ __forceinline__ u16 f2bf(float f) {
    __hip_bfloat16 h = __float2bfloat16(f);
    return __builtin_bit_cast(u16, h);
}
__device__ __forceinline__ float bf2f(u16 u) {
    return __uint_as_float(((unsigned int)u) << 16);
}

// ---------------------------------------------------------------------------
// MFMA bf16 GEMM, all operands bf16, B is [N][K] row-major.
// BK=64, LDS double-buffer + 2-slot register pipeline (round-7, verified).
// MULTI: blockIdx.z selects (B,C) from up to 3; else z=zb*Hdim+zh batches.
// wt: transposed epilogue C[gn*ldct + (gm>>wt_shift)*sbT + (gm&mask)].
// normal: v=alpha*acc + bias[n]; act==1 exact gelu; += res[(gm>>rs)*ldres+gn].
// ---------------------------------------------------------------------------
template<int BM, int BN, typename TC, bool MULTI>
__global__ __launch_bounds__(256)
void k_g(const u16* __restrict__ A, long long sAb, long long sAh, int lda,
         const u16* __restrict__ B1, const u16* __restrict__ B2_, const u16* __restrict__ B3_,
         long long sBb, long long sBh, int ldb,
         TC* __restrict__ C1, TC* __restrict__ C2_, TC* __restrict__ C3_,
         long long sCb, long long sCh, int ldc,
         int K, int Hdim, float alpha,
         const float* __restrict__ bias,
         const float* __restrict__ res, int ldres, int res_shift,
         float beta2, const u16* __restrict__ add2, long long s2b, long long s2h,
         int act, int wt_mask, int wt_shift, long long sbT, int ldct)
{
    constexpr int SK = 72;
    constexpr int FM = BM / 32, FN = BN / 32;
    constexpr int PA = BM / 32, PB = BN / 32;

    const int z = blockIdx.z;
    const u16* Bm;
    TC* C;
    int wt;
    if constexpr (MULTI) {
        Bm = (z == 0) ? B1 : ((z == 1) ? B2_ : B3_);
        C  = (z == 0) ? C1 : ((z == 1) ? C2_ : C3_);
        wt = (wt_mask >> z) & 1;
    } else {
        const int zb = z / Hdim, zh = z % Hdim;
        A += (size_t)(zb * sAb + zh * sAh);
        Bm = B1 + (size_t)(zb * sBb + zh * sBh);
        C  = C1 + (size_t)(zb * sCb + zh * sCh);
        if (add2) add2 += (size_t)(zb * s2b + zh * s2h);
        wt = wt_mask & 1;
    }

    __shared__ u16 Asm[2][BM * SK];
    __shared__ u16 Bsm[2][BN * SK];

    const int t    = threadIdx.x;
    const int wid  = t >> 6, lane = t & 63;
    const int q    = lane >> 4, c = lane & 15;
    const int wm   = (wid >> 1) * (BM / 2), wn = (wid & 1) * (BN / 2);
    const int m0   = blockIdx.y * BM, n0 = blockIdx.x * BN;

    f32x4 acc[FM][FN];
    #pragma unroll
    for (int i = 0; i < FM; i++)
        #pragma unroll
        for (int j = 0; j < FN; j++) acc[i][j] = (f32x4){0.f, 0.f, 0.f, 0.f};

    uint4 ra[2][PA], rb[2][PB];
    const int NI = K >> 6;

    auto loadg = [&](int slot, int kt) {
        #pragma unroll
        for (int p = 0; p < PA; p++) {
            const int idx = p * 256 + t, r = idx >> 3, kg = (idx & 7) << 3;
            ra[slot][p] = *(const uint4*)(A + (size_t)(m0 + r) * lda + kt + kg);
        }
        #pragma unroll
        for (int p = 0; p < PB; p++) {
            const int idx = p * 256 + t, r = idx >> 3, kg = (idx & 7) << 3;
            rb[slot][p] = *(const uint4*)(Bm + (size_t)(n0 + r) * ldb + kt + kg);
        }
    };
    auto store = [&](int buf, int slot) {
        #pragma unroll
        for (int p = 0; p < PA; p++) {
            const int idx = p * 256 + t, r = idx >> 3, kg = (idx & 7) << 3;
            *(uint4*)&Asm[buf][r * SK + kg] = ra[slot][p];
        }
        #pragma unroll
        for (int p = 0; p < PB; p++) {
            const int idx = p * 256 + t, r = idx >> 3, kg = (idx & 7) << 3;
            *(uint4*)&Bsm[buf][r * SK + kg] = rb[slot][p];
        }
    };

    loadg(0, 0);
    if (NI > 1) loadg(1, 64);
    store(0, 0);

    for (int it = 0; it < NI; it++) {
        __syncthreads();
        const int cur = it & 1, nxt = cur ^ 1;
        if (it + 1 < NI) store(nxt, nxt);
        if (it + 2 < NI) loadg(cur, (it + 2) << 6);
        #pragma unroll
        for (int s = 0; s < 2; s++) {
            bf16x8 af[FM], bfv[FN];
            #pragma unroll
            for (int fm = 0; fm < FM; fm++)
                af[fm] = *(const bf16x8*)&Asm[cur][(wm + fm * 16 + c) * SK + s * 32 + q * 8];
            #pragma unroll
            for (int fn = 0; fn < FN; fn++)
                bfv[fn] = *(const bf16x8*)&Bsm[cur][(wn + fn * 16 + c) * SK + s * 32 + q * 8];
            #pragma unroll
            for (int fm = 0; fm < FM; fm++)
                #pragma unroll
                for (int fn = 0; fn < FN; fn++)
                    acc[fm][fn] = __builtin_amdgcn_mfma_f32_16x16x32_bf16(
                        af[fm], bfv[fn], acc[fm][fn], 0, 0, 0);
        }
    }

    if (wt) {
        if constexpr (std::is_same<TC, u16>::value) {
            #pragma unroll
            for (int fm = 0; fm < FM; fm++) {
                const int gm0 = m0 + wm + fm * 16 + q * 4;
                const long long roff =
                    (long long)(gm0 >> wt_shift) * sbT + (gm0 & ((1 << wt_shift) - 1));
                #pragma unroll
                for (int fn = 0; fn < FN; fn++) {
                    const int gn = n0 + wn + fn * 16 + c;
                    const long long a0 = (long long)gn * ldct + roff;
                    u16x4 o;
                    if (add2) {
                        const u16x4 av = *(const u16x4*)&add2[a0];
                        #pragma unroll
                        for (int r = 0; r < 4; r++)
                            o[r] = f2bf(alpha * acc[fm][fn][r] + beta2 * bf2f(av[r]));
                    } else {
                        #pragma unroll
                        for (int r = 0; r < 4; r++)
                            o[r] = f2bf(alpha * acc[fm][fn][r]);
                    }
                    *(u16x4*)&C[a0] = o;
                }
            }
        }
    } else {
        #pragma unroll
        for (int fm = 0; fm < FM; fm++) {
            #pragma unroll
            for (int reg = 0; reg < 4; reg++) {
                const int gm = m0 + wm + fm * 16 + q * 4 + reg;
                #pragma unroll
                for (int fn = 0; fn < FN; fn++) {
                    const int gn = n0 + wn + fn * 16 + c;
                    float v = alpha * acc[fm][fn][reg];
                    if (bias) v += bias[gn];
                    if (act == 1) v = 0.5f * v * (1.0f + erff(v * 0.7071067811865475f));
                    if (res)  v += res[(size_t)(gm >> res_shift) * ldres + gn];
                    if constexpr (std::is_same<TC, u16>::value)
                        C[(size_t)gm * ldc + gn] = f2bf(v);
                    else
                        C[(size_t)gm * ldc + gn] = v;
                }
            }
        }
    }
}

// ---------------------------------------------------------------------------
// 128x128-tile GEMM (m97 structure): global_load_lds width-16 staging,
// XOR-swizzled LDS. 4 waves (2x2), 64x64 per wave.
// A [M][K] bf16, B [N][K] bf16 row-major, K = per-z-chunk depth (mult of 64);
// blockIdx.z selects K-chunk z*K (split-K).
// PART: plain fp32 stores of raw acc into C + z*zstr (partial buffers,
//       NO atomics — reduction happens in the following k_ln2).
// else: v = acc + bias[n]; act==1 exact gelu; += res; store TC.
// ---------------------------------------------------------------------------
template<typename TC, bool PART>
__global__ __launch_bounds__(256)
void k_g128(const u16* __restrict__ A, int lda,
            const u16* __restrict__ B, int ldb,
            TC* __restrict__ C, int ldc, int K,
            const float* __restrict__ bias,
            const float* __restrict__ res, int ldres, int act,
            long long zstr)
{
    __shared__ u16 As[128 * 64];
    __shared__ u16 Bs[128 * 64];

    const int t = threadIdx.x, wid = t >> 6, lane = t & 63;
    const int q = lane >> 4, c = lane & 15;
    const int wr = wid >> 1, wc = wid & 1;
    const int m0 = blockIdx.y * 128, n0 = blockIdx.x * 128;
    const int kz = blockIdx.z * K;

    const int lr  = lane >> 3;   // row within 8-row chunk
    const int lkb = lane & 7;    // dest 16B-block within row

    f32x4 acc[4][4];
    #pragma unroll
    for (int i = 0; i < 4; i++)
        #pragma unroll
        for (int j = 0; j < 4; j++) acc[i][j] = (f32x4){0.f, 0.f, 0.f, 0.f};

    const int NI = K >> 6;
    for (int it = 0; it < NI; it++) {
        const int kt = kz + (it << 6);
        #pragma unroll
        for (int j = 0; j < 4; j++) {
            const int r  = wid * 32 + j * 8 + lr;
            const int kb = lkb ^ (r & 7);          // inverse-swizzled source block
            const u16* ga = A + (size_t)(m0 + r) * lda + kt + kb * 8;
            const u16* gb = B + (size_t)(n0 + r) * ldb + kt + kb * 8;
            u16* la = &As[(wid * 32 + j * 8) * 64];   // wave-uniform LDS base
            u16* lb = &Bs[(wid * 32 + j * 8) * 64];
            __builtin_amdgcn_global_load_lds(
                (const __attribute__((address_space(1))) void*)ga,
                (__attribute__((address_space(3))) void*)la, 16, 0, 0);
            __builtin_amdgcn_global_load_lds(
                (const __attribute__((address_space(1))) void*)gb,
                (__attribute__((address_space(3))) void*)lb, 16, 0, 0);
        }
        __syncthreads();
        #pragma unroll
        for (int s = 0; s < 2; s++) {
            bf16x8 af[4], bfv[4];
            #pragma unroll
            for (int fm = 0; fm < 4; fm++) {
                const int row = wr * 64 + fm * 16 + c;
                const int blk = (s * 4 + q) ^ (row & 7);   // swizzled read
                af[fm] = *(const bf16x8*)&As[row * 64 + blk * 8];
            }
            #pragma unroll
            for (int fn = 0; fn < 4; fn++) {
                const int row = wc * 64 + fn * 16 + c;
                const int blk = (s * 4 + q) ^ (row & 7);
                bfv[fn] = *(const bf16x8*)&Bs[row * 64 + blk * 8];
            }
            #pragma unroll
            for (int fm = 0; fm < 4; fm++)
                #pragma unroll
                for (int fn = 0; fn < 4; fn++)
                    acc[fm][fn] = __builtin_amdgcn_mfma_f32_16x16x32_bf16(
                        af[fm], bfv[fn], acc[fm][fn], 0, 0, 0);
        }
        __syncthreads();
    }

    #pragma unroll
    for (int fm = 0; fm < 4; fm++) {
        #pragma unroll
        for (int reg = 0; reg < 4; reg++) {
            const int gm = m0 + wr * 64 + fm * 16 + q * 4 + reg;
            #pragma unroll
            for (int fn = 0; fn < 4; fn++) {
                const int gn = n0 + wc * 64 + fn * 16 + c;
                float v = acc[fm][fn][reg];
                if constexpr (PART) {
                    ((float*)C)[(size_t)blockIdx.z * zstr + (size_t)gm * ldc + gn] = v;
                } else {
                    if (bias) v += bias[gn];
                    if (act == 1) v = 0.5f * v * (1.0f + erff(v * 0.7071067811865475f));
                    if (res)  v += res[(size_t)gm * ldres + gn];
                    if constexpr (std::is_same<TC, u16>::value)
                        C[(size_t)gm * ldc + gn] = f2bf(v);
                    else
                        C[(size_t)gm * ldc + gn] = v;
                }
            }
        }
    }
}

// ---------------------------------------------------------------------------
// Fused attention: one block = 64 q-rows x one (b,h) head.
// MODE 0 (cross) : LK=128, key mask, epilogue writes ob rows [B*LQ, DD].
// MODE 1 (self A): LK=512, u = P@v, epilogue wT[b,h,64,512] = (0.5u+0.5v)^T.
// MODE 2 (self B): LK=512, RECOMPUTES S+softmax (bit-identical to MODE 1),
//                  then ob = P @ wT (vT arg = wT buffer), row-major epilogue.
// ---------------------------------------------------------------------------
template<int MODE>
__global__ __launch_bounds__(256)
void k_attn(const u16* __restrict__ qb, const u16* __restrict__ kb,
            const u16* __restrict__ vT, u16* __restrict__ uout,
            const float* __restrict__ mask, float alpha)
{
    constexpr bool CROSS = (MODE == 0);
    constexpr int LK  = CROSS ? LCC : LQQ;
    constexpr int NCT = LK / 128;
    constexpr int NJ  = LK / 16;
    constexpr int SM1 = 64 * 72 * 2 + (CROSS ? 1 : 2) * 128 * 72 * 2;
    constexpr int SM2 = 2 * 64 * 136 * 2;
    constexpr int SMEM = SM1 > SM2 ? SM1 : SM2;
    __shared__ char smem[SMEM];
    u16* Qs = (u16*)smem;
    u16* Ks = (u16*)(smem + 64 * 72 * 2);
    u16* Ps = (u16*)smem;
    u16* Vs = (u16*)(smem + 64 * 136 * 2);

    const int z = blockIdx.z, b = z >> 3, hh = z & 7;
    const int m0 = blockIdx.y * 64;
    const int t = threadIdx.x, w = t >> 6, lane = t & 63;
    const int q = lane >> 4, c = lane & 15;

    const u16* qbase = qb + ((size_t)(b * LQQ + m0)) * DD + hh * HD;
    const u16* kbase = kb + ((size_t)b * LK) * DD + hh * HD;
    const u16* vbase = vT + (size_t)z * HD * LK;

    // ---- stage Q (64 x 64) ----
    #pragma unroll
    for (int p = 0; p < 2; p++) {
        const int idx = p * 256 + t, r = idx >> 3, kg = (idx & 7) << 3;
        *(uint4*)&Qs[r * 72 + kg] = *(const uint4*)(qbase + (size_t)r * DD + kg);
    }

    f32x4 acc[NJ];
    #pragma unroll
    for (int j = 0; j < NJ; j++) acc[j] = (f32x4){0.f, 0.f, 0.f, 0.f};

    auto stageK = [&](u16* dst, int ct) {
        #pragma unroll
        for (int p = 0; p < 4; p++) {
            const int idx = p * 256 + t, r = idx >> 3, kg = (idx & 7) << 3;
            *(uint4*)&dst[r * 72 + kg] =
                *(const uint4*)(kbase + (size_t)(ct * 128 + r) * DD + kg);
        }
    };

    stageK(Ks, 0);
    __syncthreads();
    #pragma unroll
    for (int ct = 0; ct < NCT; ct++) {
        u16* cur = Ks + (!CROSS ? (ct & 1) * (128 * 72) : 0);
        if (!CROSS && ct + 1 < NCT)
            stageK(Ks + ((ct + 1) & 1) * (128 * 72), ct + 1);
        #pragma unroll
        for (int s = 0; s < 2; s++) {
            const bf16x8 af = *(const bf16x8*)&Qs[(w * 16 + c) * 72 + s * 32 + q * 8];
            #pragma unroll
            for (int fn = 0; fn < 8; fn++) {
                const bf16x8 bv = *(const bf16x8*)&cur[(fn * 16 + c) * 72 + s * 32 + q * 8];
                acc[ct * 8 + fn] = __builtin_amdgcn_mfma_f32_16x16x32_bf16(
                    af, bv, acc[ct * 8 + fn], 0, 0, 0);
            }
        }
        if (!CROSS && ct + 1 < NCT) __syncthreads();
    }

    // ---- row softmax (rows q*4+reg per wave; cols j*16+c) ----
    bool msk[NJ];
    #pragma unroll
    for (int j = 0; j < NJ; j++) {
        msk[j] = false;
        if (CROSS && mask) msk[j] = (mask[b * LCC + j * 16 + c] == 0.0f);
    }
    float mx[4] = {-3.402823466e38f, -3.402823466e38f, -3.402823466e38f, -3.402823466e38f};
    #pragma unroll
    for (int j = 0; j < NJ; j++)
        #pragma unroll
        for (int r = 0; r < 4; r++) {
            float x = alpha * acc[j][r];
            if (msk[j]) x = -3.402823466e38f;
            acc[j][r] = x;
            mx[r] = fmaxf(mx[r], x);
        }
    #pragma unroll
    for (int r = 0; r < 4; r++)
        #pragma unroll
        for (int m = 8; m; m >>= 1) mx[r] = fmaxf(mx[r], __shfl_xor(mx[r], m, 64));
    float sum[4] = {0.f, 0.f, 0.f, 0.f};
    #pragma unroll
    for (int j = 0; j < NJ; j++)
        #pragma unroll
        for (int r = 0; r < 4; r++) {
            const float e = expf(acc[j][r] - mx[r]);
            acc[j][r] = e;
            sum[r] += e;
        }
    #pragma unroll
    for (int r = 0; r < 4; r++)
        #pragma unroll
        for (int m = 8; m; m >>= 1) sum[r] += __shfl_xor(sum[r], m, 64);
    #pragma unroll
    for (int r = 0; r < 4; r++) sum[r] = 1.0f / sum[r];
    #pragma unroll
    for (int j = 0; j < NJ; j++)
        #pragma unroll
        for (int r = 0; r < 4; r++) acc[j][r] *= sum[r];

    // ---- phase 2: u = P @ v (MODE 0/1) or ob = P @ wT (MODE 2) ----
    f32x4 ua[4];
    #pragma unroll
    for (int fn = 0; fn < 4; fn++) ua[fn] = (f32x4){0.f, 0.f, 0.f, 0.f};

    __syncthreads();   // phase boundary: Qs/Ks -> Ps/Vs alias
    #pragma unroll
    for (int ct = 0; ct < NCT; ct++) {
        #pragma unroll
        for (int j = 0; j < 8; j++)
            #pragma unroll
            for (int r = 0; r < 4; r++)
                Ps[(w * 16 + q * 4 + r) * 136 + j * 16 + c] = f2bf(acc[ct * 8 + j][r]);
        #pragma unroll
        for (int p = 0; p < 4; p++) {
            const int idx = p * 256 + t, rr = idx >> 4, kg = (idx & 15) << 3;
            *(uint4*)&Vs[rr * 136 + kg] =
                *(const uint4*)(vbase + (size_t)rr * LK + ct * 128 + kg);
        }
        __syncthreads();
        #pragma unroll
        for (int ks = 0; ks < 4; ks++) {
            const bf16x8 af = *(const bf16x8*)&Ps[(w * 16 + c) * 136 + ks * 32 + q * 8];
            #pragma unroll
            for (int fn = 0; fn < 4; fn++) {
                const bf16x8 bv = *(const bf16x8*)&Vs[(fn * 16 + c) * 136 + ks * 32 + q * 8];
                ua[fn] = __builtin_amdgcn_mfma_f32_16x16x32_bf16(af, bv, ua[fn], 0, 0, 0);
            }
        }
        if (ct + 1 < NCT) __syncthreads();
    }

    // ---- epilogue ----
    if (MODE == 1) {
        #pragma unroll
        for (int fn = 0; fn < 4; fn++) {
            const int col = fn * 16 + c;
            const size_t a0 = ((size_t)z * HD + col) * LQQ + m0 + w * 16 + q * 4;
            const u16x4 vv = *(const u16x4*)&vT[a0];
            u16x4 o;
            #pragma unroll
            for (int r = 0; r < 4; r++)
                o[r] = f2bf(0.5f * ua[fn][r] + 0.5f * bf2f(vv[r]));
            *(u16x4*)&uout[a0] = o;
        }
    } else {
        #pragma unroll
        for (int fn = 0; fn < 4; fn++)
            #pragma unroll
            for (int r = 0; r < 4; r++)
                uout[((size_t)b * LQQ + m0 + w * 16 + q * 4 + r) * DD + hh * HD + fn * 16 + c] =
                    f2bf(ua[fn][r]);
    }
}

// ---------------------------------------------------------------------------
#define NSEG 14
struct CvtArgs {
    const float* src[NSEG];
    u16*         dst[NSEG];
    int          beg[NSEG + 1];
    int          n4[NSEG];
};

__global__ __launch_bounds__(256)
void k_cvtm(CvtArgs a)
{
    const int blk = blockIdx.x;
    int s = 0;
    #pragma unroll
    for (int i = 1; i < NSEG; i++) if (blk >= a.beg[i]) s = i;
    const int i4 = (blk - a.beg[s]) * 256 + threadIdx.x;
    if (i4 >= a.n4[s]) return;
    const float4 v = *(const float4*)(a.src[s] + (size_t)i4 * 4);
    u16x4 u = { f2bf(v.x), f2bf(v.y), f2bf(v.z), f2bf(v.w) };
    *(u16x4*)(a.dst[s] + (size_t)i4 * 4) = u;
}

// ---------------------------------------------------------------------------
// Plain LayerNorm: xn = LN(h) (h unchanged).
// ---------------------------------------------------------------------------
__global__ __launch_bounds__(256)
void k_ln(const float* __restrict__ X, u16* __restrict__ Y,
          const float* __restrict__ g, const float* __restrict__ b)
{
    const int row  = blockIdx.x * 4 + threadIdx.y;
    const int lane = threadIdx.x;
    const float* x = X + (size_t)row * DD;
    float v[8];
    float s = 0.0f;
    #pragma unroll
    for (int i = 0; i < 8; i++) { v[i] = x[lane + i * 64]; s += v[i]; }
    #pragma unroll
    for (int off = 32; off; off >>= 1) s += __shfl_xor(s, off, 64);
    const float m = s * (1.0f / 512.0f);
    float qq = 0.0f;
    #pragma unroll
    for (int i = 0; i < 8; i++) { const float d = v[i] - m; qq += d * d; }
    #pragma unroll
    for (int off = 32; off; off >>= 1) qq += __shfl_xor(qq, off, 64);
    const float r = rsqrtf(qq * (1.0f / 512.0f) + 1e-5f);
    u16* y = Y + (size_t)row * DD;
    #pragma unroll
    for (int i = 0; i < 8; i++) {
        const int c = lane + i * 64;
        y[c] = f2bf((v[i] - m) * r * g[c] + b[c]);
    }
}

// ---------------------------------------------------------------------------
// Accumulating LayerNorm: h += p0 + p1 + bias (split-K partial reduce fused),
// then xn = LN(h). Replaces the residual epilogue of the preceding GEMM.
// ---------------------------------------------------------------------------
__global__ __launch_bounds__(256)
void k_ln2(float* __restrict__ H, const float* __restrict__ P, long long zstr,
           const float* __restrict__ bias, u16* __restrict__ Y,
           const float* __restrict__ g, const float* __restrict__ b)
{
    const int row  = blockIdx.x * 4 + threadIdx.y;
    const int lane = threadIdx.x;
    float* x = H + (size_t)row * DD;
    const float* p0 = P + (size_t)row * DD;
    const float* p1 = p0 + zstr;
    float v[8];
    float s = 0.0f;
    #pragma unroll
    for (int i = 0; i < 8; i++) {
        const int c = lane + i * 64;
        const float t = x[c] + p0[c] + p1[c] + bias[c];
        v[i] = t;
        s += t;
    }
    #pragma unroll
    for (int off = 32; off; off >>= 1) s += __shfl_xor(s, off, 64);
    const float m = s * (1.0f / 512.0f);
    float qq = 0.0f;
    #pragma unroll
    for (int i = 0; i < 8; i++) { const float d = v[i] - m; qq += d * d; }
    #pragma unroll
    for (int off = 32; off; off >>= 1) qq += __shfl_xor(qq, off, 64);
    const float r = rsqrtf(qq * (1.0f / 512.0f) + 1e-5f);
    u16* y = Y + (size_t)row * DD;
    #pragma unroll
    for (int i = 0; i < 8; i++) {
        const int c = lane + i * 64;
        x[c] = v[i];                                   // write back h
        y[c] = f2bf((v[i] - m) * r * g[c] + b[c]);     // normalized
    }
}

// ---------------------------------------------------------------------------
__global__ void k_emb(const int* __restrict__ t, float* __restrict__ emb)
{
    const int idx = blockIdx.x * 256 + threadIdx.x;
    if (idx >= BB * DD) return;
    const int b = idx / DD, c = idx % DD;
    const int j = (c < 256) ? c : (c - 256);
    const float freq = expf((float)j * (-9.210340371976184f / 255.0f));
    const float arg = (float)t[b] * freq;
    emb[idx] = (c < 256) ? sinf(arg) : cosf(arg);
}

__global__ __launch_bounds__(256)
void k_wlin(const float* __restrict__ in, int K,
            const float* __restrict__ W, const float* __restrict__ bias,
            float* __restrict__ out, int N, int act)
{
    const int gw   = blockIdx.x * 4 + (threadIdx.x >> 6);
    const int lane = threadIdx.x & 63;
    const int b = gw / N, n = gw % N;
    const float* x = in + (size_t)b * K;
    const float* w = W + (size_t)n * K;
    float s = 0.0f;
    for (int k = lane; k < K; k += 64) s += x[k] * w[k];
    #pragma unroll
    for (int off = 32; off; off >>= 1) s += __shfl_xor(s, off, 64);
    if (lane == 0) {
        s += bias[n];
        if (act == 2) s = s / (1.0f + expf(-s));
        out[gw] = s;
    }
}

// ---------------------------------------------------------------------------

extern "C" void kernel_launch(void* const* d_in, const int* in_sizes, int n_in,
                              void* d_out, int out_size, void* d_ws, size_t ws_size,
                              hipStream_t stream)
{
    const float* x_t   = (const float*)d_in[0];
    const int*   tarr  = (const int*)  d_in[1];
    const float* cond  = (const float*)d_in[2];
    const float* cmask = (const float*)d_in[3];
    const float* sa_qw = (const float*)d_in[4];
    const float* sa_kw = (const float*)d_in[5];
    const float* sa_vw = (const float*)d_in[6];
    const float* sa_ow = (const float*)d_in[7];
    const float* sa_ob = (const float*)d_in[8];
    const float* ca_qw = (const float*)d_in[9];
    const float* ca_kw = (const float*)d_in[10];
    const float* ca_vw = (const float*)d_in[11];
    const float* ca_ow = (const float*)d_in[12];
    const float* ca_ob = (const float*)d_in[13];
    const float* f1w   = (const float*)d_in[14];
    const float* f1b   = (const float*)d_in[15];
    const float* f2w   = (const float*)d_in[16];
    const float* f2b   = (const float*)d_in[17];
    const float* n1g   = (const float*)d_in[18];
    const float* n1b   = (const float*)d_in[19];
    const float* n2g   = (const float*)d_in[20];
    const float* n2b   = (const float*)d_in[21];
    const float* n3g   = (const float*)d_in[22];
    const float* n3b   = (const float*)d_in[23];
    const float* tm1w  = (const float*)d_in[24];
    const float* tm1b  = (const float*)d_in[25];
    const float* tm2w  = (const float*)d_in[26];
    const float* tm2b  = (const float*)d_in[27];
    const float* ttw   = (const float*)d_in[28];
    const float* ttb   = (const float*)d_in[29];
    const float* pinw  = (const float*)d_in[30];
    const float* pinb  = (const float*)d_in[31];
    const float* poutw = (const float*)d_in[32];
    const float* poutb = (const float*)d_in[33];
    const float* fng   = (const float*)d_in[34];
    const float* fnb   = (const float*)d_in[35];

    const int M = BB * LQQ; // 2048
    const size_t MB = 1048576;

    char* w8 = (char*)d_ws;
    float* h   = (float*)(w8);                      // [2048,512] fp32  4 MB
    u16*  xn  = (u16*)(w8 +  4 * MB);               // 2 MB
    u16*  qb  = (u16*)(w8 +  6 * MB);               // 2 MB
    u16*  kb  = (u16*)(w8 +  8 * MB);               // 2 MB (self K)
    u16*  vbT = (u16*)(w8 + 10 * MB);               // [B,H,64,512] 2 MB
    u16*  ubT = (u16*)(w8 + 12 * MB);               // [B,H,64,512] wT 2 MB
    u16*  ob  = (u16*)(w8 + 14 * MB);               // 2 MB
    u16*  a1  = (u16*)(w8 + 16 * MB);               // FFN hidden 8 MB
    u16*  xtb = (u16*)(w8 + 16 * MB);               // aliases a1 (dead before FFN)
    u16*  cdb = (u16*)(w8 + 17 * MB);               // aliases a1 (dead before FFN)
    float* pp  = (float*)(w8 + 24 * MB);            // split-K partials 2x4MB
    u16*  kbc6 = (u16*)(w8 + 32 * MB);              // 6 x [B*LCC, DD] = 3 MB
    u16*  vcT6 = (u16*)(w8 + 35 * MB);              // 6 x [B,H,64,128] = 3 MB
    float* emb = (float*)(w8 + 38 * MB);
    float* h1t = emb + BB * DD;
    float* te  = h1t + BB * DFFN;
    float* ttv = te  + BB * DD;
    u16* wq  = (u16*)(w8 + 39 * MB);
    u16* wk  = (u16*)(w8 + 42 * MB);
    u16* wv  = (u16*)(w8 + 45 * MB);
    u16* wo  = (u16*)(w8 + 48 * MB);
    u16* cwq = (u16*)(w8 + 51 * MB);
    u16* cwk = (u16*)(w8 + 54 * MB);
    u16* cwv = (u16*)(w8 + 57 * MB);
    u16* cwo = (u16*)(w8 + 60 * MB);
    u16* w1  = (u16*)(w8 + 63 * MB);                // 12 MB
    u16* w2  = (u16*)(w8 + 75 * MB);                // 12 MB
    u16* wpi = (u16*)(w8 + 87 * MB);                // 256 KB
    u16* wpo = (u16*)(w8 + 87 * MB + 262144);       // 256 KB

    const dim3 T256(256);
    const dim3 LN_B(64, 4);
    const long long ZVT = (long long)HH * HD * LQQ; // 262144
    const long long ZWT = (long long)HH * HD * LCC; // 65536
    const long long ZP  = (long long)M * DD;        // partial stride 1048576

    // ---- one fused bf16 conversion dispatch ----
    {
        const int NW4 = NLAYER * DD * DD / 4;
        const int NF4 = NLAYER * DFFN * DD / 4;
        CvtArgs a;
        const float* srcs[NSEG] = { sa_qw, sa_kw, sa_vw, sa_ow, ca_qw, ca_kw, ca_vw, ca_ow,
                                    f1w, f2w, pinw, poutw, x_t, cond };
        u16* dsts[NSEG] = { wq, wk, wv, wo, cwq, cwk, cwv, cwo,
                            w1, w2, wpi, wpo, xtb, cdb };
        const int n4s[NSEG] = { NW4, NW4, NW4, NW4, NW4, NW4, NW4, NW4,
                                NF4, NF4, DD * LATD / 4, LATD * DD / 4,
                                M * LATD / 4, BB * LCC * DD / 4 };
        int acc = 0;
        for (int i = 0; i < NSEG; i++) {
            a.src[i] = srcs[i]; a.dst[i] = dsts[i]; a.n4[i] = n4s[i];
            a.beg[i] = acc; acc += (n4s[i] + 255) / 256;
        }
        a.beg[NSEG] = acc;
        k_cvtm<<<acc, T256, 0, stream>>>(a);
    }

    // ---- time embedding path ----
    k_emb<<<(BB * DD + 255) / 256, 256, 0, stream>>>(tarr, emb);
    k_wlin<<<(BB * DFFN) / 4, T256, 0, stream>>>(emb, DD, tm1w, tm1b, h1t, DFFN, 2);
    k_wlin<<<(BB * DD) / 4,   T256, 0, stream>>>(h1t, DFFN, tm2w, tm2b, te, DD, 0);
    k_wlin<<<(BB * DD) / 4,   T256, 0, stream>>>(te, DD, ttw, ttb, ttv, DD, 0);

    // ---- all-layer cross K: kbc6[L] = cond @ ckw[L]^T  (z = layer) ----
    k_g<32, 64, u16, false><<<dim3(DD / 64, (BB * LCC) / 32, NLAYER), T256, 0, stream>>>(
        cdb, 0, 0, DD, cwk, nullptr, nullptr, 0, (long long)DD * DD, DD,
        kbc6, nullptr, nullptr, 0, (long long)BB * LCC * DD, DD,
        DD, NLAYER, 1.0f, nullptr, nullptr, 0, 0, 0.0f, nullptr, 0, 0, 0, 0, 0, 0, 0);
    // ---- all-layer cross V (transposed): vcT6[L] ----
    k_g<32, 64, u16, false><<<dim3(DD / 64, (BB * LCC) / 32, NLAYER), T256, 0, stream>>>(
        cdb, 0, 0, DD, cwv, nullptr, nullptr, 0, (long long)DD * DD, DD,
        vcT6, nullptr, nullptr, 0, (long long)BB * HH * HD * LCC, DD,
        DD, NLAYER, 1.0f, nullptr, nullptr, 0, 0, 0.0f, nullptr, 0, 0, 0,
        /*wt=*/1, /*shift=*/7, /*sbT=*/ZWT, /*ldct=*/LCC);

    // ---- input projection: h = x_t @ pinw.T + pinb + ttv[b] ----
    k_g<32, 64, float, false><<<dim3(DD / 64, M / 32, 1), T256, 0, stream>>>(
        xtb, 0, 0, LATD, wpi, nullptr, nullptr, 0, 0, LATD,
        h, nullptr, nullptr, 0, 0, DD,
        LATD, 1, 1.0f, pinb, ttv, DD, 9, 0.0f, nullptr, 0, 0, 0, 0, 0, 0, 0);

    for (int L = 0; L < NLAYER; L++) {
        const size_t LW = (size_t)L * DD * DD;

        // ======== self-attention with QGFD (P never materialized) ========
        // n1 LN: layer 0 plain; layers 1..5 also reduce prev layer's w2 partials
        if (L == 0)
            k_ln<<<M / 4, LN_B, 0, stream>>>(h, xn,
                n1g + (size_t)L * DD, n1b + (size_t)L * DD);
        else
            k_ln2<<<M / 4, LN_B, 0, stream>>>(h, pp, ZP,
                f2b + (size_t)(L - 1) * DD, xn,
                n1g + (size_t)L * DD, n1b + (size_t)L * DD);

        // fused QKV (z: 0=q, 1=k, 2=v transposed)
        k_g<64, 64, u16, true><<<dim3(DD / 64, M / 64, 3), T256, 0, stream>>>(
            xn, 0, 0, DD, wq + LW, wk + LW, wv + LW, 0, 0, DD,
            qb, kb, vbT, 0, 0, DD,
            DD, 1, 1.0f, nullptr, nullptr, 0, 0, 0.0f, nullptr, 0, 0, 0,
            /*wt_mask=*/4, /*wt_shift=*/9, /*sbT=*/ZVT, /*ldct=*/LQQ);

        // pass A: S+softmax+u=P@v, wT = (0.5u+0.5v)^T   (no P write)
        k_attn<1><<<dim3(1, LQQ / 64, BB * HH), T256, 0, stream>>>(
            qb, kb, vbT, ubT, nullptr, 0.125f);

        // pass B: recompute S+softmax, ob = P @ wT
        k_attn<2><<<dim3(1, LQQ / 64, BB * HH), T256, 0, stream>>>(
            qb, kb, ubT, ob, nullptr, 0.125f);

        // ob @ ow.T -> split-K=2 partials (no atomics)
        k_g128<float, true><<<dim3(DD / 128, M / 128, 2), T256, 0, stream>>>(
            ob, DD, wo + LW, DD, pp, DD, 256, nullptr, nullptr, 0, 0, ZP);

        // n2 LN + reduce wo partials + sa_ob bias
        k_ln2<<<M / 4, LN_B, 0, stream>>>(h, pp, ZP,
            sa_ob + (size_t)L * DD, xn,
            n2g + (size_t)L * DD, n2b + (size_t)L * DD);

        // ======== cross-attention ========
        k_g<32, 64, u16, false><<<dim3(DD / 64, M / 32, 1), T256, 0, stream>>>(
            xn, 0, 0, DD, cwq + LW, nullptr, nullptr, 0, 0, DD,
            qb, nullptr, nullptr, 0, 0, DD,
            DD, 1, 1.0f, nullptr, nullptr, 0, 0, 0.0f, nullptr, 0, 0, 0, 0, 0, 0, 0);

        // fused Sc+mask+softmax+Pc@vc -> ob
        k_attn<0><<<dim3(1, LQQ / 64, BB * HH), T256, 0, stream>>>(
            qb, kbc6 + (size_t)L * BB * LCC * DD, vcT6 + (size_t)L * BB * HH * HD * LCC,
            ob, cmask, 0.125f);

        // ob @ cow.T -> split-K=2 partials
        k_g128<float, true><<<dim3(DD / 128, M / 128, 2), T256, 0, stream>>>(
            ob, DD, cwo + LW, DD, pp, DD, 256, nullptr, nullptr, 0, 0, ZP);

        // n3 LN + reduce cwo partials + ca_ob bias
        k_ln2<<<M / 4, LN_B, 0, stream>>>(h, pp, ZP,
            ca_ob + (size_t)L * DD, xn,
            n3g + (size_t)L * DD, n3b + (size_t)L * DD);

        // ======== FFN ========
        // w1: 128x128 m97-structure kernel (grid 16x16 = 256 blocks = 1/CU)
        k_g128<u16, false><<<dim3(DFFN / 128, M / 128, 1), T256, 0, stream>>>(
            xn, DD, w1 + (size_t)L * DFFN * DD, DD,
            a1, DFFN, DD, f1b + (size_t)L * DFFN, nullptr, 0, /*act=*/1, 0);

        // w2: split-K=2 partials (K=1024 per chunk); reduced by next n1/final LN
        k_g128<float, true><<<dim3(DD / 128, M / 128, 2), T256, 0, stream>>>(
            a1, DFFN, w2 + (size_t)L * DD * DFFN, DFFN, pp, DD, 1024,
            nullptr, nullptr, 0, 0, ZP);
    }

    // ---- final LN (+ last layer w2 partial reduce) + output projection ----
    k_ln2<<<M / 4, LN_B, 0, stream>>>(h, pp, ZP,
        f2b + (size_t)(NLAYER - 1) * DD, xn, fng, fnb);
    k_g<32, 32, float, false><<<dim3(LATD / 32, M / 32, 1), T256, 0, stream>>>(
        xn, 0, 0, DD, wpo, nullptr, nullptr, 0, 0, DD,
        (float*)d_out, nullptr, nullptr, 0, 0, LATD,
        DD, 1, 1.0f, poutb, nullptr, 0, 0, 0.0f, nullptr, 0, 0, 0, 0, 0, 0, 0);
}

// Round 7
// 1228.866 us; speedup vs baseline: 1.4457x; 1.1039x over previous
//
#include <hip/hip_runtime.h>
#include <hip/hip_bf16.h>
#include <type_traits>

#define DD    512
#define HH    8
#define HD    64
#define NLAYER 6
#define DFFN  2048
#define LATD  256
#define BB    4
#define LQQ   512
#define LCC   128

typedef unsigned short u16;
typedef __attribute__((ext_vector_type(8))) short bf16x8;
typedef __attribute__((ext_vector_type(4))) float f32x4;
typedef __attribute__((ext_vector_type(4))) unsigned short u16x4;

__device__ __forceinline__ u16 f2bf(float f) {
    __hip_bfloat16 h = __float2bfloat16(f);
    return __builtin_bit_cast(u16, h);
}
__device__ __forceinline__ float bf2f(u16 u) {
    return __uint_as_float(((unsigned int)u) << 16);
}

// ---------------------------------------------------------------------------
// MFMA bf16 GEMM, all operands bf16, B is [N][K] row-major (legacy 32/64 tile,
// kept only for the small final projection).
// ---------------------------------------------------------------------------
template<int BM, int BN, typename TC, bool MULTI>
__global__ __launch_bounds__(256)
void k_g(const u16* __restrict__ A, long long sAb, long long sAh, int lda,
         const u16* __restrict__ B1, const u16* __restrict__ B2_, const u16* __restrict__ B3_,
         long long sBb, long long sBh, int ldb,
         TC* __restrict__ C1, TC* __restrict__ C2_, TC* __restrict__ C3_,
         long long sCb, long long sCh, int ldc,
         int K, int Hdim, float alpha,
         const float* __restrict__ bias,
         const float* __restrict__ res, int ldres, int res_shift,
         float beta2, const u16* __restrict__ add2, long long s2b, long long s2h,
         int act, int wt_mask, int wt_shift, long long sbT, int ldct)
{
    constexpr int SK = 72;
    constexpr int FM = BM / 32, FN = BN / 32;
    constexpr int PA = BM / 32, PB = BN / 32;

    const int z = blockIdx.z;
    const u16* Bm;
    TC* C;
    int wt;
    if constexpr (MULTI) {
        Bm = (z == 0) ? B1 : ((z == 1) ? B2_ : B3_);
        C  = (z == 0) ? C1 : ((z == 1) ? C2_ : C3_);
        wt = (wt_mask >> z) & 1;
    } else {
        const int zb = z / Hdim, zh = z % Hdim;
        A += (size_t)(zb * sAb + zh * sAh);
        Bm = B1 + (size_t)(zb * sBb + zh * sBh);
        C  = C1 + (size_t)(zb * sCb + zh * sCh);
        if (add2) add2 += (size_t)(zb * s2b + zh * s2h);
        wt = wt_mask & 1;
    }

    __shared__ u16 Asm[2][BM * SK];
    __shared__ u16 Bsm[2][BN * SK];

    const int t    = threadIdx.x;
    const int wid  = t >> 6, lane = t & 63;
    const int q    = lane >> 4, c = lane & 15;
    const int wm   = (wid >> 1) * (BM / 2), wn = (wid & 1) * (BN / 2);
    const int m0   = blockIdx.y * BM, n0 = blockIdx.x * BN;

    f32x4 acc[FM][FN];
    #pragma unroll
    for (int i = 0; i < FM; i++)
        #pragma unroll
        for (int j = 0; j < FN; j++) acc[i][j] = (f32x4){0.f, 0.f, 0.f, 0.f};

    uint4 ra[2][PA], rb[2][PB];
    const int NI = K >> 6;

    auto loadg = [&](int slot, int kt) {
        #pragma unroll
        for (int p = 0; p < PA; p++) {
            const int idx = p * 256 + t, r = idx >> 3, kg = (idx & 7) << 3;
            ra[slot][p] = *(const uint4*)(A + (size_t)(m0 + r) * lda + kt + kg);
        }
        #pragma unroll
        for (int p = 0; p < PB; p++) {
            const int idx = p * 256 + t, r = idx >> 3, kg = (idx & 7) << 3;
            rb[slot][p] = *(const uint4*)(Bm + (size_t)(n0 + r) * ldb + kt + kg);
        }
    };
    auto store = [&](int buf, int slot) {
        #pragma unroll
        for (int p = 0; p < PA; p++) {
            const int idx = p * 256 + t, r = idx >> 3, kg = (idx & 7) << 3;
            *(uint4*)&Asm[buf][r * SK + kg] = ra[slot][p];
        }
        #pragma unroll
        for (int p = 0; p < PB; p++) {
            const int idx = p * 256 + t, r = idx >> 3, kg = (idx & 7) << 3;
            *(uint4*)&Bsm[buf][r * SK + kg] = rb[slot][p];
        }
    };

    loadg(0, 0);
    if (NI > 1) loadg(1, 64);
    store(0, 0);

    for (int it = 0; it < NI; it++) {
        __syncthreads();
        const int cur = it & 1, nxt = cur ^ 1;
        if (it + 1 < NI) store(nxt, nxt);
        if (it + 2 < NI) loadg(cur, (it + 2) << 6);
        #pragma unroll
        for (int s = 0; s < 2; s++) {
            bf16x8 af[FM], bfv[FN];
            #pragma unroll
            for (int fm = 0; fm < FM; fm++)
                af[fm] = *(const bf16x8*)&Asm[cur][(wm + fm * 16 + c) * SK + s * 32 + q * 8];
            #pragma unroll
            for (int fn = 0; fn < FN; fn++)
                bfv[fn] = *(const bf16x8*)&Bsm[cur][(wn + fn * 16 + c) * SK + s * 32 + q * 8];
            #pragma unroll
            for (int fm = 0; fm < FM; fm++)
                #pragma unroll
                for (int fn = 0; fn < FN; fn++)
                    acc[fm][fn] = __builtin_amdgcn_mfma_f32_16x16x32_bf16(
                        af[fm], bfv[fn], acc[fm][fn], 0, 0, 0);
        }
    }

    if (wt) {
        if constexpr (std::is_same<TC, u16>::value) {
            #pragma unroll
            for (int fm = 0; fm < FM; fm++) {
                const int gm0 = m0 + wm + fm * 16 + q * 4;
                const long long roff =
                    (long long)(gm0 >> wt_shift) * sbT + (gm0 & ((1 << wt_shift) - 1));
                #pragma unroll
                for (int fn = 0; fn < FN; fn++) {
                    const int gn = n0 + wn + fn * 16 + c;
                    const long long a0 = (long long)gn * ldct + roff;
                    u16x4 o;
                    if (add2) {
                        const u16x4 av = *(const u16x4*)&add2[a0];
                        #pragma unroll
                        for (int r = 0; r < 4; r++)
                            o[r] = f2bf(alpha * acc[fm][fn][r] + beta2 * bf2f(av[r]));
                    } else {
                        #pragma unroll
                        for (int r = 0; r < 4; r++)
                            o[r] = f2bf(alpha * acc[fm][fn][r]);
                    }
                    *(u16x4*)&C[a0] = o;
                }
            }
        }
    } else {
        #pragma unroll
        for (int fm = 0; fm < FM; fm++) {
            #pragma unroll
            for (int reg = 0; reg < 4; reg++) {
                const int gm = m0 + wm + fm * 16 + q * 4 + reg;
                #pragma unroll
                for (int fn = 0; fn < FN; fn++) {
                    const int gn = n0 + wn + fn * 16 + c;
                    float v = alpha * acc[fm][fn][reg];
                    if (bias) v += bias[gn];
                    if (act == 1) v = 0.5f * v * (1.0f + erff(v * 0.7071067811865475f));
                    if (res)  v += res[(size_t)(gm >> res_shift) * ldres + gn];
                    if constexpr (std::is_same<TC, u16>::value)
                        C[(size_t)gm * ldc + gn] = f2bf(v);
                    else
                        C[(size_t)gm * ldc + gn] = v;
                }
            }
        }
    }
}

// ---------------------------------------------------------------------------
// Shared 128x128-tile MFMA core (m97 structure): global_load_lds width-16
// staging, XOR-swizzled LDS, 4 waves (2x2), 64x64/wave, BK=64.
// Defined as a macro-free inline pattern via lambda-less duplication below.
// ---------------------------------------------------------------------------
#define G128_CORE(Aptr, LDA, Bptr, LDB, KZ, NIV)                               \
    {                                                                          \
        for (int it = 0; it < (NIV); it++) {                                   \
            const int kt = (KZ) + (it << 6);                                   \
            _Pragma("unroll")                                                  \
            for (int j = 0; j < 4; j++) {                                      \
                const int r  = wid * 32 + j * 8 + lr;                          \
                const int kb = lkb ^ (r & 7);                                  \
                const u16* ga = (Aptr) + (size_t)(m0 + r) * (LDA) + kt + kb * 8;\
                const u16* gb = (Bptr) + (size_t)(n0 + r) * (LDB) + kt + kb * 8;\
                u16* la = &As[(wid * 32 + j * 8) * 64];                        \
                u16* lb = &Bs[(wid * 32 + j * 8) * 64];                        \
                __builtin_amdgcn_global_load_lds(                              \
                    (const __attribute__((address_space(1))) void*)ga,         \
                    (__attribute__((address_space(3))) void*)la, 16, 0, 0);    \
                __builtin_amdgcn_global_load_lds(                              \
                    (const __attribute__((address_space(1))) void*)gb,         \
                    (__attribute__((address_space(3))) void*)lb, 16, 0, 0);    \
            }                                                                  \
            __syncthreads();                                                   \
            _Pragma("unroll")                                                  \
            for (int s = 0; s < 2; s++) {                                      \
                bf16x8 af[4], bfv[4];                                          \
                _Pragma("unroll")                                              \
                for (int fm = 0; fm < 4; fm++) {                               \
                    const int row = wr * 64 + fm * 16 + c;                     \
                    const int blk = (s * 4 + q) ^ (row & 7);                   \
                    af[fm] = *(const bf16x8*)&As[row * 64 + blk * 8];          \
                }                                                              \
                _Pragma("unroll")                                              \
                for (int fn = 0; fn < 4; fn++) {                               \
                    const int row = wc * 64 + fn * 16 + c;                     \
                    const int blk = (s * 4 + q) ^ (row & 7);                   \
                    bfv[fn] = *(const bf16x8*)&Bs[row * 64 + blk * 8];         \
                }                                                              \
                _Pragma("unroll")                                              \
                for (int fm = 0; fm < 4; fm++)                                 \
                    _Pragma("unroll")                                          \
                    for (int fn = 0; fn < 4; fn++)                             \
                        acc[fm][fn] = __builtin_amdgcn_mfma_f32_16x16x32_bf16( \
                            af[fm], bfv[fn], acc[fm][fn], 0, 0, 0);            \
            }                                                                  \
            __syncthreads();                                                   \
        }                                                                      \
    }

#define G128_PROLOG                                                            \
    __shared__ u16 As[128 * 64];                                               \
    __shared__ u16 Bs[128 * 64];                                               \
    const int t = threadIdx.x, wid = t >> 6, lane = t & 63;                    \
    const int q = lane >> 4, c = lane & 15;                                    \
    const int wr = wid >> 1, wc = wid & 1;                                     \
    const int m0 = blockIdx.y * 128, n0 = blockIdx.x * 128;                    \
    const int lr  = lane >> 3;                                                 \
    const int lkb = lane & 7;                                                  \
    f32x4 acc[4][4];                                                           \
    _Pragma("unroll")                                                          \
    for (int i = 0; i < 4; i++)                                                \
        _Pragma("unroll")                                                      \
        for (int j = 0; j < 4; j++) acc[i][j] = (f32x4){0.f, 0.f, 0.f, 0.f};

// ---------------------------------------------------------------------------
// General 128x128 GEMM. PART: raw fp32 partial stores into C+z*zstr (split-K,
// z = K-chunk). Else: v = acc + bias[n]; act==1 gelu; += res[(gm>>rshift)*ldres
// + gn]; store TC.
// ---------------------------------------------------------------------------
template<typename TC, bool PART>
__global__ __launch_bounds__(256)
void k_g128(const u16* __restrict__ A, int lda,
            const u16* __restrict__ B, int ldb,
            TC* __restrict__ C, int ldc, int K,
            const float* __restrict__ bias,
            const float* __restrict__ res, int ldres, int rshift, int act,
            long long zstr)
{
    G128_PROLOG
    const int kz = blockIdx.z * K;
    const int NI = K >> 6;
    G128_CORE(A, lda, B, ldb, kz, NI)

    #pragma unroll
    for (int fm = 0; fm < 4; fm++) {
        #pragma unroll
        for (int reg = 0; reg < 4; reg++) {
            const int gm = m0 + wr * 64 + fm * 16 + q * 4 + reg;
            #pragma unroll
            for (int fn = 0; fn < 4; fn++) {
                const int gn = n0 + wc * 64 + fn * 16 + c;
                float v = acc[fm][fn][reg];
                if constexpr (PART) {
                    ((float*)C)[(size_t)blockIdx.z * zstr + (size_t)gm * ldc + gn] = v;
                } else {
                    if (bias) v += bias[gn];
                    if (act == 1) v = 0.5f * v * (1.0f + erff(v * 0.7071067811865475f));
                    if (res)  v += res[(size_t)(gm >> rshift) * ldres + gn];
                    if constexpr (std::is_same<TC, u16>::value)
                        C[(size_t)gm * ldc + gn] = f2bf(v);
                    else
                        C[(size_t)gm * ldc + gn] = v;
                }
            }
        }
    }
}

// ---------------------------------------------------------------------------
// QKV triple 128x128 GEMM: z selects (B,C); z==2 writes V with transposed
// epilogue vbT[b, gn, row] (sbT = H*HD*LQ, ldct = LQ, 512 rows/batch).
// ---------------------------------------------------------------------------
__global__ __launch_bounds__(256)
void k_g128q(const u16* __restrict__ A, int lda,
             const u16* __restrict__ B1, const u16* __restrict__ B2,
             const u16* __restrict__ B3, int ldb,
             u16* __restrict__ C1, u16* __restrict__ C2, u16* __restrict__ C3,
             int ldc, int K, long long sbT, int ldct)
{
    const int z = blockIdx.z;
    const u16* B = (z == 0) ? B1 : ((z == 1) ? B2 : B3);
    u16* C = (z == 0) ? C1 : ((z == 1) ? C2 : C3);

    G128_PROLOG
    const int NI = K >> 6;
    G128_CORE(A, lda, B, ldb, 0, NI)

    if (z == 2) {
        #pragma unroll
        for (int fm = 0; fm < 4; fm++) {
            const int gm0 = m0 + wr * 64 + fm * 16 + q * 4;
            const long long roff = (long long)(gm0 >> 9) * sbT + (gm0 & 511);
            #pragma unroll
            for (int fn = 0; fn < 4; fn++) {
                const int gn = n0 + wc * 64 + fn * 16 + c;
                const long long a0 = (long long)gn * ldct + roff;
                u16x4 o;
                #pragma unroll
                for (int r = 0; r < 4; r++) o[r] = f2bf(acc[fm][fn][r]);
                *(u16x4*)&C[a0] = o;
            }
        }
    } else {
        #pragma unroll
        for (int fm = 0; fm < 4; fm++)
            #pragma unroll
            for (int reg = 0; reg < 4; reg++) {
                const int gm = m0 + wr * 64 + fm * 16 + q * 4 + reg;
                #pragma unroll
                for (int fn = 0; fn < 4; fn++) {
                    const int gn = n0 + wc * 64 + fn * 16 + c;
                    C[(size_t)gm * ldc + gn] = f2bf(acc[fm][fn][reg]);
                }
            }
    }
}

// ---------------------------------------------------------------------------
// z-batched 128x128 GEMM (z strides A/B/C — used for per-layer cross K/V).
// WT: transposed epilogue C[gn*ldct + (gm>>SH)*sbT + (gm & (2^SH-1))].
// ---------------------------------------------------------------------------
template<bool WT, int SH>
__global__ __launch_bounds__(256)
void k_g128b(const u16* __restrict__ A, long long sAz, int lda,
             const u16* __restrict__ B, long long sBz, int ldb,
             u16* __restrict__ C, long long sCz, int ldc, int K,
             long long sbT, int ldct)
{
    const int z = blockIdx.z;
    A += (size_t)z * sAz;
    B += (size_t)z * sBz;
    C += (size_t)z * sCz;

    G128_PROLOG
    const int NI = K >> 6;
    G128_CORE(A, lda, B, ldb, 0, NI)

    if constexpr (WT) {
        #pragma unroll
        for (int fm = 0; fm < 4; fm++) {
            const int gm0 = m0 + wr * 64 + fm * 16 + q * 4;
            const long long roff =
                (long long)(gm0 >> SH) * sbT + (gm0 & ((1 << SH) - 1));
            #pragma unroll
            for (int fn = 0; fn < 4; fn++) {
                const int gn = n0 + wc * 64 + fn * 16 + c;
                const long long a0 = (long long)gn * ldct + roff;
                u16x4 o;
                #pragma unroll
                for (int r = 0; r < 4; r++) o[r] = f2bf(acc[fm][fn][r]);
                *(u16x4*)&C[a0] = o;
            }
        }
    } else {
        #pragma unroll
        for (int fm = 0; fm < 4; fm++)
            #pragma unroll
            for (int reg = 0; reg < 4; reg++) {
                const int gm = m0 + wr * 64 + fm * 16 + q * 4 + reg;
                #pragma unroll
                for (int fn = 0; fn < 4; fn++) {
                    const int gn = n0 + wc * 64 + fn * 16 + c;
                    C[(size_t)gm * ldc + gn] = f2bf(acc[fm][fn][reg]);
                }
            }
    }
}

// ---------------------------------------------------------------------------
// Fused attention: one block = 64 q-rows x one (b,h) head.
// MODE 0 (cross) : LK=128, key mask, epilogue writes ob rows [B*LQ, DD].
// MODE 1 (self A): LK=512, u = P@v, epilogue wT[b,h,64,512] = (0.5u+0.5v)^T.
// MODE 2 (self B): LK=512, RECOMPUTES S+softmax (bit-identical to MODE 1),
//                  then ob = P @ wT (vT arg = wT buffer), row-major epilogue.
// ---------------------------------------------------------------------------
template<int MODE>
__global__ __launch_bounds__(256)
void k_attn(const u16* __restrict__ qb, const u16* __restrict__ kb,
            const u16* __restrict__ vT, u16* __restrict__ uout,
            const float* __restrict__ mask, float alpha)
{
    constexpr bool CROSS = (MODE == 0);
    constexpr int LK  = CROSS ? LCC : LQQ;
    constexpr int NCT = LK / 128;
    constexpr int NJ  = LK / 16;
    constexpr int SM1 = 64 * 72 * 2 + (CROSS ? 1 : 2) * 128 * 72 * 2;
    constexpr int SM2 = 2 * 64 * 136 * 2;
    constexpr int SMEM = SM1 > SM2 ? SM1 : SM2;
    __shared__ char smem[SMEM];
    u16* Qs = (u16*)smem;
    u16* Ks = (u16*)(smem + 64 * 72 * 2);
    u16* Ps = (u16*)smem;
    u16* Vs = (u16*)(smem + 64 * 136 * 2);

    const int z = blockIdx.z, b = z >> 3, hh = z & 7;
    const int m0 = blockIdx.y * 64;
    const int t = threadIdx.x, w = t >> 6, lane = t & 63;
    const int q = lane >> 4, c = lane & 15;

    const u16* qbase = qb + ((size_t)(b * LQQ + m0)) * DD + hh * HD;
    const u16* kbase = kb + ((size_t)b * LK) * DD + hh * HD;
    const u16* vbase = vT + (size_t)z * HD * LK;

    // ---- stage Q (64 x 64) ----
    #pragma unroll
    for (int p = 0; p < 2; p++) {
        const int idx = p * 256 + t, r = idx >> 3, kg = (idx & 7) << 3;
        *(uint4*)&Qs[r * 72 + kg] = *(const uint4*)(qbase + (size_t)r * DD + kg);
    }

    f32x4 acc[NJ];
    #pragma unroll
    for (int j = 0; j < NJ; j++) acc[j] = (f32x4){0.f, 0.f, 0.f, 0.f};

    auto stageK = [&](u16* dst, int ct) {
        #pragma unroll
        for (int p = 0; p < 4; p++) {
            const int idx = p * 256 + t, r = idx >> 3, kg = (idx & 7) << 3;
            *(uint4*)&dst[r * 72 + kg] =
                *(const uint4*)(kbase + (size_t)(ct * 128 + r) * DD + kg);
        }
    };

    stageK(Ks, 0);
    __syncthreads();
    #pragma unroll
    for (int ct = 0; ct < NCT; ct++) {
        u16* cur = Ks + (!CROSS ? (ct & 1) * (128 * 72) : 0);
        if (!CROSS && ct + 1 < NCT)
            stageK(Ks + ((ct + 1) & 1) * (128 * 72), ct + 1);
        #pragma unroll
        for (int s = 0; s < 2; s++) {
            const bf16x8 af = *(const bf16x8*)&Qs[(w * 16 + c) * 72 + s * 32 + q * 8];
            #pragma unroll
            for (int fn = 0; fn < 8; fn++) {
                const bf16x8 bv = *(const bf16x8*)&cur[(fn * 16 + c) * 72 + s * 32 + q * 8];
                acc[ct * 8 + fn] = __builtin_amdgcn_mfma_f32_16x16x32_bf16(
                    af, bv, acc[ct * 8 + fn], 0, 0, 0);
            }
        }
        if (!CROSS && ct + 1 < NCT) __syncthreads();
    }

    // ---- row softmax (rows q*4+reg per wave; cols j*16+c) ----
    bool msk[NJ];
    #pragma unroll
    for (int j = 0; j < NJ; j++) {
        msk[j] = false;
        if (CROSS && mask) msk[j] = (mask[b * LCC + j * 16 + c] == 0.0f);
    }
    float mx[4] = {-3.402823466e38f, -3.402823466e38f, -3.402823466e38f, -3.402823466e38f};
    #pragma unroll
    for (int j = 0; j < NJ; j++)
        #pragma unroll
        for (int r = 0; r < 4; r++) {
            float x = alpha * acc[j][r];
            if (msk[j]) x = -3.402823466e38f;
            acc[j][r] = x;
            mx[r] = fmaxf(mx[r], x);
        }
    #pragma unroll
    for (int r = 0; r < 4; r++)
        #pragma unroll
        for (int m = 8; m; m >>= 1) mx[r] = fmaxf(mx[r], __shfl_xor(mx[r], m, 64));
    float sum[4] = {0.f, 0.f, 0.f, 0.f};
    #pragma unroll
    for (int j = 0; j < NJ; j++)
        #pragma unroll
        for (int r = 0; r < 4; r++) {
            const float e = expf(acc[j][r] - mx[r]);
            acc[j][r] = e;
            sum[r] += e;
        }
    #pragma unroll
    for (int r = 0; r < 4; r++)
        #pragma unroll
        for (int m = 8; m; m >>= 1) sum[r] += __shfl_xor(sum[r], m, 64);
    #pragma unroll
    for (int r = 0; r < 4; r++) sum[r] = 1.0f / sum[r];
    #pragma unroll
    for (int j = 0; j < NJ; j++)
        #pragma unroll
        for (int r = 0; r < 4; r++) acc[j][r] *= sum[r];

    // ---- phase 2: u = P @ v (MODE 0/1) or ob = P @ wT (MODE 2) ----
    f32x4 ua[4];
    #pragma unroll
    for (int fn = 0; fn < 4; fn++) ua[fn] = (f32x4){0.f, 0.f, 0.f, 0.f};

    __syncthreads();   // phase boundary: Qs/Ks -> Ps/Vs alias
    #pragma unroll
    for (int ct = 0; ct < NCT; ct++) {
        #pragma unroll
        for (int j = 0; j < 8; j++)
            #pragma unroll
            for (int r = 0; r < 4; r++)
                Ps[(w * 16 + q * 4 + r) * 136 + j * 16 + c] = f2bf(acc[ct * 8 + j][r]);
        #pragma unroll
        for (int p = 0; p < 4; p++) {
            const int idx = p * 256 + t, rr = idx >> 4, kg = (idx & 15) << 3;
            *(uint4*)&Vs[rr * 136 + kg] =
                *(const uint4*)(vbase + (size_t)rr * LK + ct * 128 + kg);
        }
        __syncthreads();
        #pragma unroll
        for (int ks = 0; ks < 4; ks++) {
            const bf16x8 af = *(const bf16x8*)&Ps[(w * 16 + c) * 136 + ks * 32 + q * 8];
            #pragma unroll
            for (int fn = 0; fn < 4; fn++) {
                const bf16x8 bv = *(const bf16x8*)&Vs[(fn * 16 + c) * 136 + ks * 32 + q * 8];
                ua[fn] = __builtin_amdgcn_mfma_f32_16x16x32_bf16(af, bv, ua[fn], 0, 0, 0);
            }
        }
        if (ct + 1 < NCT) __syncthreads();
    }

    // ---- epilogue ----
    if (MODE == 1) {
        #pragma unroll
        for (int fn = 0; fn < 4; fn++) {
            const int col = fn * 16 + c;
            const size_t a0 = ((size_t)z * HD + col) * LQQ + m0 + w * 16 + q * 4;
            const u16x4 vv = *(const u16x4*)&vT[a0];
            u16x4 o;
            #pragma unroll
            for (int r = 0; r < 4; r++)
                o[r] = f2bf(0.5f * ua[fn][r] + 0.5f * bf2f(vv[r]));
            *(u16x4*)&uout[a0] = o;
        }
    } else {
        #pragma unroll
        for (int fn = 0; fn < 4; fn++)
            #pragma unroll
            for (int r = 0; r < 4; r++)
                uout[((size_t)b * LQQ + m0 + w * 16 + q * 4 + r) * DD + hh * HD + fn * 16 + c] =
                    f2bf(ua[fn][r]);
    }
}

// ---------------------------------------------------------------------------
#define NSEG 14
struct CvtArgs {
    const float* src[NSEG];
    u16*         dst[NSEG];
    int          beg[NSEG + 1];
    int          n4[NSEG];
};

__global__ __launch_bounds__(256)
void k_cvtm(CvtArgs a)
{
    const int blk = blockIdx.x;
    int s = 0;
    #pragma unroll
    for (int i = 1; i < NSEG; i++) if (blk >= a.beg[i]) s = i;
    const int i4 = (blk - a.beg[s]) * 256 + threadIdx.x;
    if (i4 >= a.n4[s]) return;
    const float4 v = *(const float4*)(a.src[s] + (size_t)i4 * 4);
    u16x4 u = { f2bf(v.x), f2bf(v.y), f2bf(v.z), f2bf(v.w) };
    *(u16x4*)(a.dst[s] + (size_t)i4 * 4) = u;
}

// ---------------------------------------------------------------------------
// Plain LayerNorm: xn = LN(h) (h unchanged).
// ---------------------------------------------------------------------------
__global__ __launch_bounds__(256)
void k_ln(const float* __restrict__ X, u16* __restrict__ Y,
          const float* __restrict__ g, const float* __restrict__ b)
{
    const int row  = blockIdx.x * 4 + threadIdx.y;
    const int lane = threadIdx.x;
    const float* x = X + (size_t)row * DD;
    float v[8];
    float s = 0.0f;
    #pragma unroll
    for (int i = 0; i < 8; i++) { v[i] = x[lane + i * 64]; s += v[i]; }
    #pragma unroll
    for (int off = 32; off; off >>= 1) s += __shfl_xor(s, off, 64);
    const float m = s * (1.0f / 512.0f);
    float qq = 0.0f;
    #pragma unroll
    for (int i = 0; i < 8; i++) { const float d = v[i] - m; qq += d * d; }
    #pragma unroll
    for (int off = 32; off; off >>= 1) qq += __shfl_xor(qq, off, 64);
    const float r = rsqrtf(qq * (1.0f / 512.0f) + 1e-5f);
    u16* y = Y + (size_t)row * DD;
    #pragma unroll
    for (int i = 0; i < 8; i++) {
        const int c = lane + i * 64;
        y[c] = f2bf((v[i] - m) * r * g[c] + b[c]);
    }
}

// ---------------------------------------------------------------------------
// Accumulating LayerNorm: h += p0 + p1 + bias (split-K partial reduce fused),
// then xn = LN(h).
// ---------------------------------------------------------------------------
__global__ __launch_bounds__(256)
void k_ln2(float* __restrict__ H, const float* __restrict__ P, long long zstr,
           const float* __restrict__ bias, u16* __restrict__ Y,
           const float* __restrict__ g, const float* __restrict__ b)
{
    const int row  = blockIdx.x * 4 + threadIdx.y;
    const int lane = threadIdx.x;
    float* x = H + (size_t)row * DD;
    const float* p0 = P + (size_t)row * DD;
    const float* p1 = p0 + zstr;
    float v[8];
    float s = 0.0f;
    #pragma unroll
    for (int i = 0; i < 8; i++) {
        const int c = lane + i * 64;
        const float t = x[c] + p0[c] + p1[c] + bias[c];
        v[i] = t;
        s += t;
    }
    #pragma unroll
    for (int off = 32; off; off >>= 1) s += __shfl_xor(s, off, 64);
    const float m = s * (1.0f / 512.0f);
    float qq = 0.0f;
    #pragma unroll
    for (int i = 0; i < 8; i++) { const float d = v[i] - m; qq += d * d; }
    #pragma unroll
    for (int off = 32; off; off >>= 1) qq += __shfl_xor(qq, off, 64);
    const float r = rsqrtf(qq * (1.0f / 512.0f) + 1e-5f);
    u16* y = Y + (size_t)row * DD;
    #pragma unroll
    for (int i = 0; i < 8; i++) {
        const int c = lane + i * 64;
        x[c] = v[i];                                   // write back h
        y[c] = f2bf((v[i] - m) * r * g[c] + b[c]);     // normalized
    }
}

// ---------------------------------------------------------------------------
__global__ void k_emb(const int* __restrict__ t, float* __restrict__ emb)
{
    const int idx = blockIdx.x * 256 + threadIdx.x;
    if (idx >= BB * DD) return;
    const int b = idx / DD, c = idx % DD;
    const int j = (c < 256) ? c : (c - 256);
    const float freq = expf((float)j * (-9.210340371976184f / 255.0f));
    const float arg = (float)t[b] * freq;
    emb[idx] = (c < 256) ? sinf(arg) : cosf(arg);
}

__global__ __launch_bounds__(256)
void k_wlin(const float* __restrict__ in, int K,
            const float* __restrict__ W, const float* __restrict__ bias,
            float* __restrict__ out, int N, int act)
{
    const int gw   = blockIdx.x * 4 + (threadIdx.x >> 6);
    const int lane = threadIdx.x & 63;
    const int b = gw / N, n = gw % N;
    const float* x = in + (size_t)b * K;
    const float* w = W + (size_t)n * K;
    float s = 0.0f;
    for (int k = lane; k < K; k += 64) s += x[k] * w[k];
    #pragma unroll
    for (int off = 32; off; off >>= 1) s += __shfl_xor(s, off, 64);
    if (lane == 0) {
        s += bias[n];
        if (act == 2) s = s / (1.0f + expf(-s));
        out[gw] = s;
    }
}

// ---------------------------------------------------------------------------

extern "C" void kernel_launch(void* const* d_in, const int* in_sizes, int n_in,
                              void* d_out, int out_size, void* d_ws, size_t ws_size,
                              hipStream_t stream)
{
    const float* x_t   = (const float*)d_in[0];
    const int*   tarr  = (const int*)  d_in[1];
    const float* cond  = (const float*)d_in[2];
    const float* cmask = (const float*)d_in[3];
    const float* sa_qw = (const float*)d_in[4];
    const float* sa_kw = (const float*)d_in[5];
    const float* sa_vw = (const float*)d_in[6];
    const float* sa_ow = (const float*)d_in[7];
    const float* sa_ob = (const float*)d_in[8];
    const float* ca_qw = (const float*)d_in[9];
    const float* ca_kw = (const float*)d_in[10];
    const float* ca_vw = (const float*)d_in[11];
    const float* ca_ow = (const float*)d_in[12];
    const float* ca_ob = (const float*)d_in[13];
    const float* f1w   = (const float*)d_in[14];
    const float* f1b   = (const float*)d_in[15];
    const float* f2w   = (const float*)d_in[16];
    const float* f2b   = (const float*)d_in[17];
    const float* n1g   = (const float*)d_in[18];
    const float* n1b   = (const float*)d_in[19];
    const float* n2g   = (const float*)d_in[20];
    const float* n2b   = (const float*)d_in[21];
    const float* n3g   = (const float*)d_in[22];
    const float* n3b   = (const float*)d_in[23];
    const float* tm1w  = (const float*)d_in[24];
    const float* tm1b  = (const float*)d_in[25];
    const float* tm2w  = (const float*)d_in[26];
    const float* tm2b  = (const float*)d_in[27];
    const float* ttw   = (const float*)d_in[28];
    const float* ttb   = (const float*)d_in[29];
    const float* pinw  = (const float*)d_in[30];
    const float* pinb  = (const float*)d_in[31];
    const float* poutw = (const float*)d_in[32];
    const float* poutb = (const float*)d_in[33];
    const float* fng   = (const float*)d_in[34];
    const float* fnb   = (const float*)d_in[35];

    const int M = BB * LQQ; // 2048
    const size_t MB = 1048576;

    char* w8 = (char*)d_ws;
    float* h   = (float*)(w8);                      // [2048,512] fp32  4 MB
    u16*  xn  = (u16*)(w8 +  4 * MB);               // 2 MB
    u16*  qb  = (u16*)(w8 +  6 * MB);               // 2 MB
    u16*  kb  = (u16*)(w8 +  8 * MB);               // 2 MB (self K)
    u16*  vbT = (u16*)(w8 + 10 * MB);               // [B,H,64,512] 2 MB
    u16*  ubT = (u16*)(w8 + 12 * MB);               // [B,H,64,512] wT 2 MB
    u16*  ob  = (u16*)(w8 + 14 * MB);               // 2 MB
    u16*  a1  = (u16*)(w8 + 16 * MB);               // FFN hidden 8 MB
    u16*  xtb = (u16*)(w8 + 16 * MB);               // aliases a1 (dead before FFN)
    u16*  cdb = (u16*)(w8 + 17 * MB);               // aliases a1 (dead before FFN)
    float* pp  = (float*)(w8 + 24 * MB);            // split-K partials 2x4MB
    u16*  kbc6 = (u16*)(w8 + 32 * MB);              // 6 x [B*LCC, DD] = 3 MB
    u16*  vcT6 = (u16*)(w8 + 35 * MB);              // 6 x [B,H,64,128] = 3 MB
    float* emb = (float*)(w8 + 38 * MB);
    float* h1t = emb + BB * DD;
    float* te  = h1t + BB * DFFN;
    float* ttv = te  + BB * DD;
    u16* wq  = (u16*)(w8 + 39 * MB);
    u16* wk  = (u16*)(w8 + 42 * MB);
    u16* wv  = (u16*)(w8 + 45 * MB);
    u16* wo  = (u16*)(w8 + 48 * MB);
    u16* cwq = (u16*)(w8 + 51 * MB);
    u16* cwk = (u16*)(w8 + 54 * MB);
    u16* cwv = (u16*)(w8 + 57 * MB);
    u16* cwo = (u16*)(w8 + 60 * MB);
    u16* w1  = (u16*)(w8 + 63 * MB);                // 12 MB
    u16* w2  = (u16*)(w8 + 75 * MB);                // 12 MB
    u16* wpi = (u16*)(w8 + 87 * MB);                // 256 KB
    u16* wpo = (u16*)(w8 + 87 * MB + 262144);       // 256 KB

    const dim3 T256(256);
    const dim3 LN_B(64, 4);
    const long long ZVT = (long long)HH * HD * LQQ; // 262144
    const long long ZWT = (long long)HH * HD * LCC; // 65536
    const long long ZP  = (long long)M * DD;        // partial stride 1048576
    const long long WST = (long long)DD * DD;       // 262144

    // ---- one fused bf16 conversion dispatch ----
    {
        const int NW4 = NLAYER * DD * DD / 4;
        const int NF4 = NLAYER * DFFN * DD / 4;
        CvtArgs a;
        const float* srcs[NSEG] = { sa_qw, sa_kw, sa_vw, sa_ow, ca_qw, ca_kw, ca_vw, ca_ow,
                                    f1w, f2w, pinw, poutw, x_t, cond };
        u16* dsts[NSEG] = { wq, wk, wv, wo, cwq, cwk, cwv, cwo,
                            w1, w2, wpi, wpo, xtb, cdb };
        const int n4s[NSEG] = { NW4, NW4, NW4, NW4, NW4, NW4, NW4, NW4,
                                NF4, NF4, DD * LATD / 4, LATD * DD / 4,
                                M * LATD / 4, BB * LCC * DD / 4 };
        int acc = 0;
        for (int i = 0; i < NSEG; i++) {
            a.src[i] = srcs[i]; a.dst[i] = dsts[i]; a.n4[i] = n4s[i];
            a.beg[i] = acc; acc += (n4s[i] + 255) / 256;
        }
        a.beg[NSEG] = acc;
        k_cvtm<<<acc, T256, 0, stream>>>(a);
    }

    // ---- time embedding path ----
    k_emb<<<(BB * DD + 255) / 256, 256, 0, stream>>>(tarr, emb);
    k_wlin<<<(BB * DFFN) / 4, T256, 0, stream>>>(emb, DD, tm1w, tm1b, h1t, DFFN, 2);
    k_wlin<<<(BB * DD) / 4,   T256, 0, stream>>>(h1t, DFFN, tm2w, tm2b, te, DD, 0);
    k_wlin<<<(BB * DD) / 4,   T256, 0, stream>>>(te, DD, ttw, ttb, ttv, DD, 0);

    // ---- all-layer cross K: kbc6[L] = cond @ ckw[L]^T (z = layer) ----
    k_g128b<false, 0><<<dim3(DD / 128, (BB * LCC) / 128, NLAYER), T256, 0, stream>>>(
        cdb, 0, DD, cwk, WST, DD, kbc6, (long long)BB * LCC * DD, DD, DD, 0, 0);
    // ---- all-layer cross V (transposed): vcT6[L] ----
    k_g128b<true, 7><<<dim3(DD / 128, (BB * LCC) / 128, NLAYER), T256, 0, stream>>>(
        cdb, 0, DD, cwv, WST, DD, vcT6, (long long)BB * HH * HD * LCC, DD, DD,
        ZWT, LCC);

    // ---- input projection: h = x_t @ pinw.T + pinb + ttv[b] ----
    k_g128<float, false><<<dim3(DD / 128, M / 128, 1), T256, 0, stream>>>(
        xtb, LATD, wpi, LATD, h, DD, LATD, pinb, ttv, DD, 9, 0, 0);

    for (int L = 0; L < NLAYER; L++) {
        const size_t LW = (size_t)L * DD * DD;

        // ======== self-attention with QGFD (P never materialized) ========
        // n1 LN: layer 0 plain; layers 1..5 also reduce prev layer's w2 partials
        if (L == 0)
            k_ln<<<M / 4, LN_B, 0, stream>>>(h, xn,
                n1g + (size_t)L * DD, n1b + (size_t)L * DD);
        else
            k_ln2<<<M / 4, LN_B, 0, stream>>>(h, pp, ZP,
                f2b + (size_t)(L - 1) * DD, xn,
                n1g + (size_t)L * DD, n1b + (size_t)L * DD);

        // fused QKV (z: 0=q, 1=k, 2=v transposed) — 128x128 structure
        k_g128q<<<dim3(DD / 128, M / 128, 3), T256, 0, stream>>>(
            xn, DD, wq + LW, wk + LW, wv + LW, DD,
            qb, kb, vbT, DD, DD, ZVT, LQQ);

        // pass A: S+softmax+u=P@v, wT = (0.5u+0.5v)^T   (no P write)
        k_attn<1><<<dim3(1, LQQ / 64, BB * HH), T256, 0, stream>>>(
            qb, kb, vbT, ubT, nullptr, 0.125f);

        // pass B: recompute S+softmax, ob = P @ wT
        k_attn<2><<<dim3(1, LQQ / 64, BB * HH), T256, 0, stream>>>(
            qb, kb, ubT, ob, nullptr, 0.125f);

        // ob @ ow.T -> split-K=2 partials (no atomics)
        k_g128<float, true><<<dim3(DD / 128, M / 128, 2), T256, 0, stream>>>(
            ob, DD, wo + LW, DD, pp, DD, 256, nullptr, nullptr, 0, 0, 0, ZP);

        // n2 LN + reduce wo partials + sa_ob bias
        k_ln2<<<M / 4, LN_B, 0, stream>>>(h, pp, ZP,
            sa_ob + (size_t)L * DD, xn,
            n2g + (size_t)L * DD, n2b + (size_t)L * DD);

        // ======== cross-attention ========
        // cq = xn @ cwq^T — 128x128 structure
        k_g128<u16, false><<<dim3(DD / 128, M / 128, 1), T256, 0, stream>>>(
            xn, DD, cwq + LW, DD, qb, DD, DD, nullptr, nullptr, 0, 0, 0, 0);

        // fused Sc+mask+softmax+Pc@vc -> ob
        k_attn<0><<<dim3(1, LQQ / 64, BB * HH), T256, 0, stream>>>(
            qb, kbc6 + (size_t)L * BB * LCC * DD, vcT6 + (size_t)L * BB * HH * HD * LCC,
            ob, cmask, 0.125f);

        // ob @ cow.T -> split-K=2 partials
        k_g128<float, true><<<dim3(DD / 128, M / 128, 2), T256, 0, stream>>>(
            ob, DD, cwo + LW, DD, pp, DD, 256, nullptr, nullptr, 0, 0, 0, ZP);

        // n3 LN + reduce cwo partials + ca_ob bias
        k_ln2<<<M / 4, LN_B, 0, stream>>>(h, pp, ZP,
            ca_ob + (size_t)L * DD, xn,
            n3g + (size_t)L * DD, n3b + (size_t)L * DD);

        // ======== FFN ========
        // w1: 128x128 (grid 16x16 = 256 blocks = 1/CU)
        k_g128<u16, false><<<dim3(DFFN / 128, M / 128, 1), T256, 0, stream>>>(
            xn, DD, w1 + (size_t)L * DFFN * DD, DD,
            a1, DFFN, DD, f1b + (size_t)L * DFFN, nullptr, 0, 0, /*act=*/1, 0);

        // w2: split-K=2 partials (K=1024 per chunk); reduced by next n1/final LN
        k_g128<float, true><<<dim3(DD / 128, M / 128, 2), T256, 0, stream>>>(
            a1, DFFN, w2 + (size_t)L * DD * DFFN, DFFN, pp, DD, 1024,
            nullptr, nullptr, 0, 0, 0, ZP);
    }

    // ---- final LN (+ last layer w2 partial reduce) + output projection ----
    k_ln2<<<M / 4, LN_B, 0, stream>>>(h, pp, ZP,
        f2b + (size_t)(NLAYER - 1) * DD, xn, fng, fnb);
    k_g<32, 32, float, false><<<dim3(LATD / 32, M / 32, 1), T256, 0, stream>>>(
        xn, 0, 0, DD, wpo, nullptr, nullptr, 0, 0, DD,
        (float*)d_out, nullptr, nullptr, 0, 0, LATD,
        DD, 1, 1.0f, poutb, nullptr, 0, 0, 0.0f, nullptr, 0, 0, 0, 0, 0, 0, 0);
}

// Round 9
// 1151.212 us; speedup vs baseline: 1.5432x; 1.0675x over previous
//
#include <hip/hip_runtime.h>
#include <hip/hip_bf16.h>
#include <type_traits>

#define DD    512
#define HH    8
#define HD    64
#define NLAYER 6
#define DFFN  2048
#define LATD  256
#define BB    4
#define LQQ   512
#define LCC   128

typedef unsigned short u16;
typedef __attribute__((ext_vector_type(8))) short bf16x8;
typedef __attribute__((ext_vector_type(4))) float f32x4;
typedef __attribute__((ext_vector_type(4))) unsigned short u16x4;

__device__ __forceinline__ u16 f2bf(float f) {
    __hip_bfloat16 h = __float2bfloat16(f);
    return __builtin_bit_cast(u16, h);
}
__device__ __forceinline__ float bf2f(u16 u) {
    return __uint_as_float(((unsigned int)u) << 16);
}

// ---------------------------------------------------------------------------
// Legacy 32/64-tile MFMA GEMM (kept only for the small final projection).
// ---------------------------------------------------------------------------
template<int BM, int BN, typename TC, bool MULTI>
__global__ __launch_bounds__(256)
void k_g(const u16* __restrict__ A, long long sAb, long long sAh, int lda,
         const u16* __restrict__ B1, const u16* __restrict__ B2_, const u16* __restrict__ B3_,
         long long sBb, long long sBh, int ldb,
         TC* __restrict__ C1, TC* __restrict__ C2_, TC* __restrict__ C3_,
         long long sCb, long long sCh, int ldc,
         int K, int Hdim, float alpha,
         const float* __restrict__ bias,
         const float* __restrict__ res, int ldres, int res_shift,
         float beta2, const u16* __restrict__ add2, long long s2b, long long s2h,
         int act, int wt_mask, int wt_shift, long long sbT, int ldct)
{
    constexpr int SK = 72;
    constexpr int FM = BM / 32, FN = BN / 32;
    constexpr int PA = BM / 32, PB = BN / 32;

    const int z = blockIdx.z;
    const u16* Bm;
    TC* C;
    int wt;
    if constexpr (MULTI) {
        Bm = (z == 0) ? B1 : ((z == 1) ? B2_ : B3_);
        C  = (z == 0) ? C1 : ((z == 1) ? C2_ : C3_);
        wt = (wt_mask >> z) & 1;
    } else {
        const int zb = z / Hdim, zh = z % Hdim;
        A += (size_t)(zb * sAb + zh * sAh);
        Bm = B1 + (size_t)(zb * sBb + zh * sBh);
        C  = C1 + (size_t)(zb * sCb + zh * sCh);
        if (add2) add2 += (size_t)(zb * s2b + zh * s2h);
        wt = wt_mask & 1;
    }

    __shared__ u16 Asm[2][BM * SK];
    __shared__ u16 Bsm[2][BN * SK];

    const int t    = threadIdx.x;
    const int wid  = t >> 6, lane = t & 63;
    const int q    = lane >> 4, c = lane & 15;
    const int wm   = (wid >> 1) * (BM / 2), wn = (wid & 1) * (BN / 2);
    const int m0   = blockIdx.y * BM, n0 = blockIdx.x * BN;

    f32x4 acc[FM][FN];
    #pragma unroll
    for (int i = 0; i < FM; i++)
        #pragma unroll
        for (int j = 0; j < FN; j++) acc[i][j] = (f32x4){0.f, 0.f, 0.f, 0.f};

    uint4 ra[2][PA], rb[2][PB];
    const int NI = K >> 6;

    auto loadg = [&](int slot, int kt) {
        #pragma unroll
        for (int p = 0; p < PA; p++) {
            const int idx = p * 256 + t, r = idx >> 3, kg = (idx & 7) << 3;
            ra[slot][p] = *(const uint4*)(A + (size_t)(m0 + r) * lda + kt + kg);
        }
        #pragma unroll
        for (int p = 0; p < PB; p++) {
            const int idx = p * 256 + t, r = idx >> 3, kg = (idx & 7) << 3;
            rb[slot][p] = *(const uint4*)(Bm + (size_t)(n0 + r) * ldb + kt + kg);
        }
    };
    auto store = [&](int buf, int slot) {
        #pragma unroll
        for (int p = 0; p < PA; p++) {
            const int idx = p * 256 + t, r = idx >> 3, kg = (idx & 7) << 3;
            *(uint4*)&Asm[buf][r * SK + kg] = ra[slot][p];
        }
        #pragma unroll
        for (int p = 0; p < PB; p++) {
            const int idx = p * 256 + t, r = idx >> 3, kg = (idx & 7) << 3;
            *(uint4*)&Bsm[buf][r * SK + kg] = rb[slot][p];
        }
    };

    loadg(0, 0);
    if (NI > 1) loadg(1, 64);
    store(0, 0);

    for (int it = 0; it < NI; it++) {
        __syncthreads();
        const int cur = it & 1, nxt = cur ^ 1;
        if (it + 1 < NI) store(nxt, nxt);
        if (it + 2 < NI) loadg(cur, (it + 2) << 6);
        #pragma unroll
        for (int s = 0; s < 2; s++) {
            bf16x8 af[FM], bfv[FN];
            #pragma unroll
            for (int fm = 0; fm < FM; fm++)
                af[fm] = *(const bf16x8*)&Asm[cur][(wm + fm * 16 + c) * SK + s * 32 + q * 8];
            #pragma unroll
            for (int fn = 0; fn < FN; fn++)
                bfv[fn] = *(const bf16x8*)&Bsm[cur][(wn + fn * 16 + c) * SK + s * 32 + q * 8];
            #pragma unroll
            for (int fm = 0; fm < FM; fm++)
                #pragma unroll
                for (int fn = 0; fn < FN; fn++)
                    acc[fm][fn] = __builtin_amdgcn_mfma_f32_16x16x32_bf16(
                        af[fm], bfv[fn], acc[fm][fn], 0, 0, 0);
        }
    }

    if (wt) {
        if constexpr (std::is_same<TC, u16>::value) {
            #pragma unroll
            for (int fm = 0; fm < FM; fm++) {
                const int gm0 = m0 + wm + fm * 16 + q * 4;
                const long long roff =
                    (long long)(gm0 >> wt_shift) * sbT + (gm0 & ((1 << wt_shift) - 1));
                #pragma unroll
                for (int fn = 0; fn < FN; fn++) {
                    const int gn = n0 + wn + fn * 16 + c;
                    const long long a0 = (long long)gn * ldct + roff;
                    u16x4 o;
                    if (add2) {
                        const u16x4 av = *(const u16x4*)&add2[a0];
                        #pragma unroll
                        for (int r = 0; r < 4; r++)
                            o[r] = f2bf(alpha * acc[fm][fn][r] + beta2 * bf2f(av[r]));
                    } else {
                        #pragma unroll
                        for (int r = 0; r < 4; r++)
                            o[r] = f2bf(alpha * acc[fm][fn][r]);
                    }
                    *(u16x4*)&C[a0] = o;
                }
            }
        }
    } else {
        #pragma unroll
        for (int fm = 0; fm < FM; fm++) {
            #pragma unroll
            for (int reg = 0; reg < 4; reg++) {
                const int gm = m0 + wm + fm * 16 + q * 4 + reg;
                #pragma unroll
                for (int fn = 0; fn < FN; fn++) {
                    const int gn = n0 + wn + fn * 16 + c;
                    float v = alpha * acc[fm][fn][reg];
                    if (bias) v += bias[gn];
                    if (act == 1) v = 0.5f * v * (1.0f + erff(v * 0.7071067811865475f));
                    if (res)  v += res[(size_t)(gm >> res_shift) * ldres + gn];
                    if constexpr (std::is_same<TC, u16>::value)
                        C[(size_t)gm * ldc + gn] = f2bf(v);
                    else
                        C[(size_t)gm * ldc + gn] = v;
                }
            }
        }
    }
}

// ---------------------------------------------------------------------------
// Shared 128x128-tile MFMA core (m97 structure).
// ---------------------------------------------------------------------------
#define G128_CORE(Aptr, LDA, Bptr, LDB, KZ, NIV)                               \
    {                                                                          \
        for (int it = 0; it < (NIV); it++) {                                   \
            const int kt = (KZ) + (it << 6);                                   \
            _Pragma("unroll")                                                  \
            for (int j = 0; j < 4; j++) {                                      \
                const int r  = wid * 32 + j * 8 + lr;                          \
                const int kb = lkb ^ (r & 7);                                  \
                const u16* ga = (Aptr) + (size_t)(m0 + r) * (LDA) + kt + kb * 8;\
                const u16* gb = (Bptr) + (size_t)(n0 + r) * (LDB) + kt + kb * 8;\
                u16* la = &As[(wid * 32 + j * 8) * 64];                        \
                u16* lb = &Bs[(wid * 32 + j * 8) * 64];                        \
                __builtin_amdgcn_global_load_lds(                              \
                    (const __attribute__((address_space(1))) void*)ga,         \
                    (__attribute__((address_space(3))) void*)la, 16, 0, 0);    \
                __builtin_amdgcn_global_load_lds(                              \
                    (const __attribute__((address_space(1))) void*)gb,         \
                    (__attribute__((address_space(3))) void*)lb, 16, 0, 0);    \
            }                                                                  \
            __syncthreads();                                                   \
            _Pragma("unroll")                                                  \
            for (int s = 0; s < 2; s++) {                                      \
                bf16x8 af[4], bfv[4];                                          \
                _Pragma("unroll")                                              \
                for (int fm = 0; fm < 4; fm++) {                               \
                    const int row = wr * 64 + fm * 16 + c;                     \
                    const int blk = (s * 4 + q) ^ (row & 7);                   \
                    af[fm] = *(const bf16x8*)&As[row * 64 + blk * 8];          \
                }                                                              \
                _Pragma("unroll")                                              \
                for (int fn = 0; fn < 4; fn++) {                               \
                    const int row = wc * 64 + fn * 16 + c;                     \
                    const int blk = (s * 4 + q) ^ (row & 7);                   \
                    bfv[fn] = *(const bf16x8*)&Bs[row * 64 + blk * 8];         \
                }                                                              \
                _Pragma("unroll")                                              \
                for (int fm = 0; fm < 4; fm++)                                 \
                    _Pragma("unroll")                                          \
                    for (int fn = 0; fn < 4; fn++)                             \
                        acc[fm][fn] = __builtin_amdgcn_mfma_f32_16x16x32_bf16( \
                            af[fm], bfv[fn], acc[fm][fn], 0, 0, 0);            \
            }                                                                  \
            __syncthreads();                                                   \
        }                                                                      \
    }

#define G128_PROLOG                                                            \
    __shared__ u16 As[128 * 64];                                               \
    __shared__ u16 Bs[128 * 64];                                               \
    const int t = threadIdx.x, wid = t >> 6, lane = t & 63;                    \
    const int q = lane >> 4, c = lane & 15;                                    \
    const int wr = wid >> 1, wc = wid & 1;                                     \
    const int m0 = blockIdx.y * 128, n0 = blockIdx.x * 128;                    \
    const int lr  = lane >> 3;                                                 \
    const int lkb = lane & 7;                                                  \
    f32x4 acc[4][4];                                                           \
    _Pragma("unroll")                                                          \
    for (int i = 0; i < 4; i++)                                                \
        _Pragma("unroll")                                                      \
        for (int j = 0; j < 4; j++) acc[i][j] = (f32x4){0.f, 0.f, 0.f, 0.f};

// ---------------------------------------------------------------------------
// General 128x128 GEMM. PART: raw fp32 partial stores into C+z*zstr (split-K).
// ---------------------------------------------------------------------------
template<typename TC, bool PART>
__global__ __launch_bounds__(256)
void k_g128(const u16* __restrict__ A, int lda,
            const u16* __restrict__ B, int ldb,
            TC* __restrict__ C, int ldc, int K,
            const float* __restrict__ bias,
            const float* __restrict__ res, int ldres, int rshift, int act,
            long long zstr)
{
    G128_PROLOG
    const int kz = blockIdx.z * K;
    const int NI = K >> 6;
    G128_CORE(A, lda, B, ldb, kz, NI)

    #pragma unroll
    for (int fm = 0; fm < 4; fm++) {
        #pragma unroll
        for (int reg = 0; reg < 4; reg++) {
            const int gm = m0 + wr * 64 + fm * 16 + q * 4 + reg;
            #pragma unroll
            for (int fn = 0; fn < 4; fn++) {
                const int gn = n0 + wc * 64 + fn * 16 + c;
                float v = acc[fm][fn][reg];
                if constexpr (PART) {
                    ((float*)C)[(size_t)blockIdx.z * zstr + (size_t)gm * ldc + gn] = v;
                } else {
                    if (bias) v += bias[gn];
                    if (act == 1) v = 0.5f * v * (1.0f + erff(v * 0.7071067811865475f));
                    if (res)  v += res[(size_t)(gm >> rshift) * ldres + gn];
                    if constexpr (std::is_same<TC, u16>::value)
                        C[(size_t)gm * ldc + gn] = f2bf(v);
                    else
                        C[(size_t)gm * ldc + gn] = v;
                }
            }
        }
    }
}

// ---------------------------------------------------------------------------
// QKV triple 128x128 GEMM: z selects (B,C); z==2 writes V transposed.
// ---------------------------------------------------------------------------
__global__ __launch_bounds__(256)
void k_g128q(const u16* __restrict__ A, int lda,
             const u16* __restrict__ B1, const u16* __restrict__ B2,
             const u16* __restrict__ B3, int ldb,
             u16* __restrict__ C1, u16* __restrict__ C2, u16* __restrict__ C3,
             int ldc, int K, long long sbT, int ldct)
{
    const int z = blockIdx.z;
    const u16* B = (z == 0) ? B1 : ((z == 1) ? B2 : B3);
    u16* C = (z == 0) ? C1 : ((z == 1) ? C2 : C3);

    G128_PROLOG
    const int NI = K >> 6;
    G128_CORE(A, lda, B, ldb, 0, NI)

    if (z == 2) {
        #pragma unroll
        for (int fm = 0; fm < 4; fm++) {
            const int gm0 = m0 + wr * 64 + fm * 16 + q * 4;
            const long long roff = (long long)(gm0 >> 9) * sbT + (gm0 & 511);
            #pragma unroll
            for (int fn = 0; fn < 4; fn++) {
                const int gn = n0 + wc * 64 + fn * 16 + c;
                const long long a0 = (long long)gn * ldct + roff;
                u16x4 o;
                #pragma unroll
                for (int r = 0; r < 4; r++) o[r] = f2bf(acc[fm][fn][r]);
                *(u16x4*)&C[a0] = o;
            }
        }
    } else {
        #pragma unroll
        for (int fm = 0; fm < 4; fm++)
            #pragma unroll
            for (int reg = 0; reg < 4; reg++) {
                const int gm = m0 + wr * 64 + fm * 16 + q * 4 + reg;
                #pragma unroll
                for (int fn = 0; fn < 4; fn++) {
                    const int gn = n0 + wc * 64 + fn * 16 + c;
                    C[(size_t)gm * ldc + gn] = f2bf(acc[fm][fn][reg]);
                }
            }
    }
}

// ---------------------------------------------------------------------------
// z-batched 128x128 GEMM (per-layer cross K/V precompute).
// ---------------------------------------------------------------------------
template<bool WT, int SH>
__global__ __launch_bounds__(256)
void k_g128b(const u16* __restrict__ A, long long sAz, int lda,
             const u16* __restrict__ B, long long sBz, int ldb,
             u16* __restrict__ C, long long sCz, int ldc, int K,
             long long sbT, int ldct)
{
    const int z = blockIdx.z;
    A += (size_t)z * sAz;
    B += (size_t)z * sBz;
    C += (size_t)z * sCz;

    G128_PROLOG
    const int NI = K >> 6;
    G128_CORE(A, lda, B, ldb, 0, NI)

    if constexpr (WT) {
        #pragma unroll
        for (int fm = 0; fm < 4; fm++) {
            const int gm0 = m0 + wr * 64 + fm * 16 + q * 4;
            const long long roff =
                (long long)(gm0 >> SH) * sbT + (gm0 & ((1 << SH) - 1));
            #pragma unroll
            for (int fn = 0; fn < 4; fn++) {
                const int gn = n0 + wc * 64 + fn * 16 + c;
                const long long a0 = (long long)gn * ldct + roff;
                u16x4 o;
                #pragma unroll
                for (int r = 0; r < 4; r++) o[r] = f2bf(acc[fm][fn][r]);
                *(u16x4*)&C[a0] = o;
            }
        }
    } else {
        #pragma unroll
        for (int fm = 0; fm < 4; fm++)
            #pragma unroll
            for (int reg = 0; reg < 4; reg++) {
                const int gm = m0 + wr * 64 + fm * 16 + q * 4 + reg;
                #pragma unroll
                for (int fn = 0; fn < 4; fn++) {
                    const int gn = n0 + wc * 64 + fn * 16 + c;
                    C[(size_t)gm * ldc + gn] = f2bf(acc[fm][fn][reg]);
                }
            }
    }
}

// ---------------------------------------------------------------------------
// Self-attention pass A: S=q@k^T, softmax -> P; u=P@v;
// wT=(0.5u+0.5v)^T; ALSO writes P (bf16, bit-identical to the Ps LDS values)
// so pass B (k_pw) can skip the recompute.
// ---------------------------------------------------------------------------
__global__ __launch_bounds__(256)
void k_attn1(const u16* __restrict__ qb, const u16* __restrict__ kb,
             const u16* __restrict__ vT, u16* __restrict__ wT,
             u16* __restrict__ Pg, float alpha)
{
    constexpr int NCT = 4;
    constexpr int NJ  = 32;
    constexpr int SM1 = 64 * 72 * 2 + 2 * 128 * 72 * 2;  // 46080
    constexpr int SM2 = 2 * 64 * 136 * 2;                // 34816
    constexpr int SMEM = SM1 > SM2 ? SM1 : SM2;
    __shared__ char smem[SMEM];
    u16* Qs = (u16*)smem;
    u16* Ks = (u16*)(smem + 64 * 72 * 2);
    u16* Ps = (u16*)smem;
    u16* Vs = (u16*)(smem + 64 * 136 * 2);

    const int z = blockIdx.z, b = z >> 3, hh = z & 7;
    const int m0 = blockIdx.y * 64;
    const int t = threadIdx.x, w = t >> 6, lane = t & 63;
    const int q = lane >> 4, c = lane & 15;

    const u16* qbase = qb + ((size_t)(b * LQQ + m0)) * DD + hh * HD;
    const u16* kbase = kb + ((size_t)b * LQQ) * DD + hh * HD;
    const u16* vbase = vT + (size_t)z * HD * LQQ;

    // ---- stage Q (64 x 64) ----
    #pragma unroll
    for (int p = 0; p < 2; p++) {
        const int idx = p * 256 + t, r = idx >> 3, kg = (idx & 7) << 3;
        *(uint4*)&Qs[r * 72 + kg] = *(const uint4*)(qbase + (size_t)r * DD + kg);
    }

    f32x4 acc[NJ];
    #pragma unroll
    for (int j = 0; j < NJ; j++) acc[j] = (f32x4){0.f, 0.f, 0.f, 0.f};

    auto stageK = [&](u16* dst, int ct) {
        #pragma unroll
        for (int p = 0; p < 4; p++) {
            const int idx = p * 256 + t, r = idx >> 3, kg = (idx & 7) << 3;
            *(uint4*)&dst[r * 72 + kg] =
                *(const uint4*)(kbase + (size_t)(ct * 128 + r) * DD + kg);
        }
    };

    stageK(Ks, 0);
    __syncthreads();
    #pragma unroll
    for (int ct = 0; ct < NCT; ct++) {
        u16* cur = Ks + (ct & 1) * (128 * 72);
        if (ct + 1 < NCT) stageK(Ks + ((ct + 1) & 1) * (128 * 72), ct + 1);
        #pragma unroll
        for (int s = 0; s < 2; s++) {
            const bf16x8 af = *(const bf16x8*)&Qs[(w * 16 + c) * 72 + s * 32 + q * 8];
            #pragma unroll
            for (int fn = 0; fn < 8; fn++) {
                const bf16x8 bv = *(const bf16x8*)&cur[(fn * 16 + c) * 72 + s * 32 + q * 8];
                acc[ct * 8 + fn] = __builtin_amdgcn_mfma_f32_16x16x32_bf16(
                    af, bv, acc[ct * 8 + fn], 0, 0, 0);
            }
        }
        if (ct + 1 < NCT) __syncthreads();
    }

    // ---- row softmax ----
    float mx[4] = {-3.402823466e38f, -3.402823466e38f, -3.402823466e38f, -3.402823466e38f};
    #pragma unroll
    for (int j = 0; j < NJ; j++)
        #pragma unroll
        for (int r = 0; r < 4; r++) {
            const float x = alpha * acc[j][r];
            acc[j][r] = x;
            mx[r] = fmaxf(mx[r], x);
        }
    #pragma unroll
    for (int r = 0; r < 4; r++)
        #pragma unroll
        for (int m = 8; m; m >>= 1) mx[r] = fmaxf(mx[r], __shfl_xor(mx[r], m, 64));
    float sum[4] = {0.f, 0.f, 0.f, 0.f};
    #pragma unroll
    for (int j = 0; j < NJ; j++)
        #pragma unroll
        for (int r = 0; r < 4; r++) {
            const float e = expf(acc[j][r] - mx[r]);
            acc[j][r] = e;
            sum[r] += e;
        }
    #pragma unroll
    for (int r = 0; r < 4; r++)
        #pragma unroll
        for (int m = 8; m; m >>= 1) sum[r] += __shfl_xor(sum[r], m, 64);
    #pragma unroll
    for (int r = 0; r < 4; r++) sum[r] = 1.0f / sum[r];
    #pragma unroll
    for (int j = 0; j < NJ; j++)
        #pragma unroll
        for (int r = 0; r < 4; r++) acc[j][r] *= sum[r];

    // ---- phase 2: u = P @ v (writing P to HBM alongside the Ps stores) ----
    f32x4 ua[4];
    #pragma unroll
    for (int fn = 0; fn < 4; fn++) ua[fn] = (f32x4){0.f, 0.f, 0.f, 0.f};

    __syncthreads();   // Qs/Ks -> Ps/Vs alias
    #pragma unroll
    for (int ct = 0; ct < NCT; ct++) {
        #pragma unroll
        for (int j = 0; j < 8; j++)
            #pragma unroll
            for (int r = 0; r < 4; r++) {
                const u16 pv = f2bf(acc[ct * 8 + j][r]);
                Ps[(w * 16 + q * 4 + r) * 136 + j * 16 + c] = pv;
                Pg[((size_t)z * LQQ + m0 + w * 16 + q * 4 + r) * LQQ +
                   ct * 128 + j * 16 + c] = pv;
            }
        #pragma unroll
        for (int p = 0; p < 4; p++) {
            const int idx = p * 256 + t, rr = idx >> 4, kg = (idx & 15) << 3;
            *(uint4*)&Vs[rr * 136 + kg] =
                *(const uint4*)(vbase + (size_t)rr * LQQ + ct * 128 + kg);
        }
        __syncthreads();
        #pragma unroll
        for (int ks = 0; ks < 4; ks++) {
            const bf16x8 af = *(const bf16x8*)&Ps[(w * 16 + c) * 136 + ks * 32 + q * 8];
            #pragma unroll
            for (int fn = 0; fn < 4; fn++) {
                const bf16x8 bv = *(const bf16x8*)&Vs[(fn * 16 + c) * 136 + ks * 32 + q * 8];
                ua[fn] = __builtin_amdgcn_mfma_f32_16x16x32_bf16(af, bv, ua[fn], 0, 0, 0);
            }
        }
        if (ct + 1 < NCT) __syncthreads();
    }

    // wT = (0.5*u + 0.5*v)^T
    #pragma unroll
    for (int fn = 0; fn < 4; fn++) {
        const int col = fn * 16 + c;
        const size_t a0 = ((size_t)z * HD + col) * LQQ + m0 + w * 16 + q * 4;
        const u16x4 vv = *(const u16x4*)&vT[a0];
        u16x4 o;
        #pragma unroll
        for (int r = 0; r < 4; r++)
            o[r] = f2bf(0.5f * ua[fn][r] + 0.5f * bf2f(vv[r]));
        *(u16x4*)&wT[a0] = o;
    }
}

// ---------------------------------------------------------------------------
// Self-attention pass B: ob = P @ wT (P from HBM, no recompute).
// ---------------------------------------------------------------------------
__global__ __launch_bounds__(256)
void k_pw(const u16* __restrict__ Pg, const u16* __restrict__ wT,
          u16* __restrict__ uout)
{
    __shared__ u16 smem[2 * 64 * 136];
    u16* Ps = smem;
    u16* Vs = smem + 64 * 136;

    const int z = blockIdx.z, b = z >> 3, hh = z & 7;
    const int m0 = blockIdx.y * 64;
    const int t = threadIdx.x, w = t >> 6, lane = t & 63;
    const int q = lane >> 4, c = lane & 15;

    const u16* pbase = Pg + ((size_t)z * LQQ + m0) * LQQ;
    const u16* vbase = wT + (size_t)z * HD * LQQ;

    f32x4 ua[4];
    #pragma unroll
    for (int fn = 0; fn < 4; fn++) ua[fn] = (f32x4){0.f, 0.f, 0.f, 0.f};

    #pragma unroll
    for (int ct = 0; ct < 4; ct++) {
        #pragma unroll
        for (int p = 0; p < 4; p++) {
            const int idx = p * 256 + t, rr = idx >> 4, kg = (idx & 15) << 3;
            *(uint4*)&Ps[rr * 136 + kg] =
                *(const uint4*)(pbase + (size_t)rr * LQQ + ct * 128 + kg);
            *(uint4*)&Vs[rr * 136 + kg] =
                *(const uint4*)(vbase + (size_t)rr * LQQ + ct * 128 + kg);
        }
        __syncthreads();
        #pragma unroll
        for (int ks = 0; ks < 4; ks++) {
            const bf16x8 af = *(const bf16x8*)&Ps[(w * 16 + c) * 136 + ks * 32 + q * 8];
            #pragma unroll
            for (int fn = 0; fn < 4; fn++) {
                const bf16x8 bv = *(const bf16x8*)&Vs[(fn * 16 + c) * 136 + ks * 32 + q * 8];
                ua[fn] = __builtin_amdgcn_mfma_f32_16x16x32_bf16(af, bv, ua[fn], 0, 0, 0);
            }
        }
        if (ct + 1 < 4) __syncthreads();
    }

    #pragma unroll
    for (int fn = 0; fn < 4; fn++)
        #pragma unroll
        for (int r = 0; r < 4; r++)
            uout[((size_t)b * LQQ + m0 + w * 16 + q * 4 + r) * DD + hh * HD + fn * 16 + c] =
                f2bf(ua[fn][r]);
}

// ---------------------------------------------------------------------------
// Cross-attention with FUSED Q projection: q = xn[m0..64] @ cwq[h-slice]^T
// computed per block (no redundancy: each block owns its (rows, head) slice).
// Then S=q@k^T + mask + softmax, ob = P@vc. LK=128.
// ---------------------------------------------------------------------------
__global__ __launch_bounds__(256)
void k_attn0(const u16* __restrict__ xnp, const u16* __restrict__ wqp,
             const u16* __restrict__ kbp, const u16* __restrict__ vT,
             u16* __restrict__ uout, const float* __restrict__ mask,
             float alpha)
{
    constexpr int NJ = 8;
    constexpr int SMEM = 2 * 64 * 136 * 2;   // 34816 (covers 27648 phase-1)
    __shared__ char smem[SMEM];
    u16* Qs = (u16*)smem;
    u16* Ks = (u16*)(smem + 64 * 72 * 2);
    u16* Xs = Ks;                  // mini-GEMM staging (aliases Ks region)
    u16* Ws = Ks + 64 * 72;
    u16* Ps = (u16*)smem;
    u16* Vs = (u16*)(smem + 64 * 136 * 2);

    const int z = blockIdx.z, b = z >> 3, hh = z & 7;
    const int m0 = blockIdx.y * 64;
    const int t = threadIdx.x, w = t >> 6, lane = t & 63;
    const int q = lane >> 4, c = lane & 15;

    const u16* xbase = xnp + ((size_t)(b * LQQ + m0)) * DD;
    const u16* wbase = wqp + (size_t)(hh * HD) * DD;
    const u16* kbase = kbp + ((size_t)b * LCC) * DD + hh * HD;
    const u16* vbase = vT + (size_t)z * HD * LCC;

    // ---- fused Q projection: q[64x64] = xn-slice @ wq-slice^T (K=512) ----
    f32x4 qa[4];
    #pragma unroll
    for (int fn = 0; fn < 4; fn++) qa[fn] = (f32x4){0.f, 0.f, 0.f, 0.f};
    for (int kc = 0; kc < 8; kc++) {
        #pragma unroll
        for (int p = 0; p < 2; p++) {
            const int idx = p * 256 + t, r = idx >> 3, kg = (idx & 7) << 3;
            *(uint4*)&Xs[r * 72 + kg] =
                *(const uint4*)(xbase + (size_t)r * DD + kc * 64 + kg);
            *(uint4*)&Ws[r * 72 + kg] =
                *(const uint4*)(wbase + (size_t)r * DD + kc * 64 + kg);
        }
        __syncthreads();
        #pragma unroll
        for (int s = 0; s < 2; s++) {
            const bf16x8 af = *(const bf16x8*)&Xs[(w * 16 + c) * 72 + s * 32 + q * 8];
            #pragma unroll
            for (int fn = 0; fn < 4; fn++) {
                const bf16x8 bv = *(const bf16x8*)&Ws[(fn * 16 + c) * 72 + s * 32 + q * 8];
                qa[fn] = __builtin_amdgcn_mfma_f32_16x16x32_bf16(af, bv, qa[fn], 0, 0, 0);
            }
        }
        __syncthreads();
    }
    // write q to Qs (row = w*16+q*4+r, col = fn*16+c)
    #pragma unroll
    for (int fn = 0; fn < 4; fn++)
        #pragma unroll
        for (int r = 0; r < 4; r++)
            Qs[(w * 16 + q * 4 + r) * 72 + fn * 16 + c] = f2bf(qa[fn][r]);

    // ---- stage K (128 x 64) ----
    #pragma unroll
    for (int p = 0; p < 4; p++) {
        const int idx = p * 256 + t, r = idx >> 3, kg = (idx & 7) << 3;
        *(uint4*)&Ks[r * 72 + kg] = *(const uint4*)(kbase + (size_t)r * DD + kg);
    }
    __syncthreads();

    f32x4 acc[NJ];
    #pragma unroll
    for (int j = 0; j < NJ; j++) acc[j] = (f32x4){0.f, 0.f, 0.f, 0.f};

    #pragma unroll
    for (int s = 0; s < 2; s++) {
        const bf16x8 af = *(const bf16x8*)&Qs[(w * 16 + c) * 72 + s * 32 + q * 8];
        #pragma unroll
        for (int fn = 0; fn < 8; fn++) {
            const bf16x8 bv = *(const bf16x8*)&Ks[(fn * 16 + c) * 72 + s * 32 + q * 8];
            acc[fn] = __builtin_amdgcn_mfma_f32_16x16x32_bf16(af, bv, acc[fn], 0, 0, 0);
        }
    }

    // ---- row softmax with key mask ----
    bool msk[NJ];
    #pragma unroll
    for (int j = 0; j < NJ; j++)
        msk[j] = (mask[b * LCC + j * 16 + c] == 0.0f);
    float mx[4] = {-3.402823466e38f, -3.402823466e38f, -3.402823466e38f, -3.402823466e38f};
    #pragma unroll
    for (int j = 0; j < NJ; j++)
        #pragma unroll
        for (int r = 0; r < 4; r++) {
            float x = alpha * acc[j][r];
            if (msk[j]) x = -3.402823466e38f;
            acc[j][r] = x;
            mx[r] = fmaxf(mx[r], x);
        }
    #pragma unroll
    for (int r = 0; r < 4; r++)
        #pragma unroll
        for (int m = 8; m; m >>= 1) mx[r] = fmaxf(mx[r], __shfl_xor(mx[r], m, 64));
    float sum[4] = {0.f, 0.f, 0.f, 0.f};
    #pragma unroll
    for (int j = 0; j < NJ; j++)
        #pragma unroll
        for (int r = 0; r < 4; r++) {
            const float e = expf(acc[j][r] - mx[r]);
            acc[j][r] = e;
            sum[r] += e;
        }
    #pragma unroll
    for (int r = 0; r < 4; r++)
        #pragma unroll
        for (int m = 8; m; m >>= 1) sum[r] += __shfl_xor(sum[r], m, 64);
    #pragma unroll
    for (int r = 0; r < 4; r++) sum[r] = 1.0f / sum[r];
    #pragma unroll
    for (int j = 0; j < NJ; j++)
        #pragma unroll
        for (int r = 0; r < 4; r++) acc[j][r] *= sum[r];

    // ---- phase 2: ob = P @ vc ----
    f32x4 ua[4];
    #pragma unroll
    for (int fn = 0; fn < 4; fn++) ua[fn] = (f32x4){0.f, 0.f, 0.f, 0.f};

    __syncthreads();   // Qs/Ks -> Ps/Vs alias
    #pragma unroll
    for (int j = 0; j < 8; j++)
        #pragma unroll
        for (int r = 0; r < 4; r++)
            Ps[(w * 16 + q * 4 + r) * 136 + j * 16 + c] = f2bf(acc[j][r]);
    #pragma unroll
    for (int p = 0; p < 4; p++) {
        const int idx = p * 256 + t, rr = idx >> 4, kg = (idx & 15) << 3;
        *(uint4*)&Vs[rr * 136 + kg] =
            *(const uint4*)(vbase + (size_t)rr * LCC + kg);
    }
    __syncthreads();
    #pragma unroll
    for (int ks = 0; ks < 4; ks++) {
        const bf16x8 af = *(const bf16x8*)&Ps[(w * 16 + c) * 136 + ks * 32 + q * 8];
        #pragma unroll
        for (int fn = 0; fn < 4; fn++) {
            const bf16x8 bv = *(const bf16x8*)&Vs[(fn * 16 + c) * 136 + ks * 32 + q * 8];
            ua[fn] = __builtin_amdgcn_mfma_f32_16x16x32_bf16(af, bv, ua[fn], 0, 0, 0);
        }
    }

    #pragma unroll
    for (int fn = 0; fn < 4; fn++)
        #pragma unroll
        for (int r = 0; r < 4; r++)
            uout[((size_t)b * LQQ + m0 + w * 16 + q * 4 + r) * DD + hh * HD + fn * 16 + c] =
                f2bf(ua[fn][r]);
}

// ---------------------------------------------------------------------------
#define NSEG 14
struct CvtArgs {
    const float* src[NSEG];
    u16*         dst[NSEG];
    int          beg[NSEG + 1];
    int          n4[NSEG];
};

__global__ __launch_bounds__(256)
void k_cvtm(CvtArgs a)
{
    const int blk = blockIdx.x;
    int s = 0;
    #pragma unroll
    for (int i = 1; i < NSEG; i++) if (blk >= a.beg[i]) s = i;
    const int i4 = (blk - a.beg[s]) * 256 + threadIdx.x;
    if (i4 >= a.n4[s]) return;
    const float4 v = *(const float4*)(a.src[s] + (size_t)i4 * 4);
    u16x4 u = { f2bf(v.x), f2bf(v.y), f2bf(v.z), f2bf(v.w) };
    *(u16x4*)(a.dst[s] + (size_t)i4 * 4) = u;
}

// ---------------------------------------------------------------------------
__global__ __launch_bounds__(256)
void k_ln(const float* __restrict__ X, u16* __restrict__ Y,
          const float* __restrict__ g, const float* __restrict__ b)
{
    const int row  = blockIdx.x * 4 + threadIdx.y;
    const int lane = threadIdx.x;
    const float* x = X + (size_t)row * DD;
    float v[8];
    float s = 0.0f;
    #pragma unroll
    for (int i = 0; i < 8; i++) { v[i] = x[lane + i * 64]; s += v[i]; }
    #pragma unroll
    for (int off = 32; off; off >>= 1) s += __shfl_xor(s, off, 64);
    const float m = s * (1.0f / 512.0f);
    float qq = 0.0f;
    #pragma unroll
    for (int i = 0; i < 8; i++) { const float d = v[i] - m; qq += d * d; }
    #pragma unroll
    for (int off = 32; off; off >>= 1) qq += __shfl_xor(qq, off, 64);
    const float r = rsqrtf(qq * (1.0f / 512.0f) + 1e-5f);
    u16* y = Y + (size_t)row * DD;
    #pragma unroll
    for (int i = 0; i < 8; i++) {
        const int c = lane + i * 64;
        y[c] = f2bf((v[i] - m) * r * g[c] + b[c]);
    }
}

// ---------------------------------------------------------------------------
// Accumulating LayerNorm: h += sum(NP partials) + bias, then xn = LN(h).
// ---------------------------------------------------------------------------
template<int NP>
__global__ __launch_bounds__(256)
void k_ln2(float* __restrict__ H, const float* __restrict__ P, long long zstr,
           const float* __restrict__ bias, u16* __restrict__ Y,
           const float* __restrict__ g, const float* __restrict__ b)
{
    const int row  = blockIdx.x * 4 + threadIdx.y;
    const int lane = threadIdx.x;
    float* x = H + (size_t)row * DD;
    const float* pb = P + (size_t)row * DD;
    float v[8];
    float s = 0.0f;
    #pragma unroll
    for (int i = 0; i < 8; i++) {
        const int c = lane + i * 64;
        float t = x[c] + bias[c];
        #pragma unroll
        for (int p = 0; p < NP; p++) t += pb[(size_t)p * zstr + c];
        v[i] = t;
        s += t;
    }
    #pragma unroll
    for (int off = 32; off; off >>= 1) s += __shfl_xor(s, off, 64);
    const float m = s * (1.0f / 512.0f);
    float qq = 0.0f;
    #pragma unroll
    for (int i = 0; i < 8; i++) { const float d = v[i] - m; qq += d * d; }
    #pragma unroll
    for (int off = 32; off; off >>= 1) qq += __shfl_xor(qq, off, 64);
    const float r = rsqrtf(qq * (1.0f / 512.0f) + 1e-5f);
    u16* y = Y + (size_t)row * DD;
    #pragma unroll
    for (int i = 0; i < 8; i++) {
        const int c = lane + i * 64;
        x[c] = v[i];
        y[c] = f2bf((v[i] - m) * r * g[c] + b[c]);
    }
}

// ---------------------------------------------------------------------------
__global__ void k_emb(const int* __restrict__ t, float* __restrict__ emb)
{
    const int idx = blockIdx.x * 256 + threadIdx.x;
    if (idx >= BB * DD) return;
    const int b = idx / DD, c = idx % DD;
    const int j = (c < 256) ? c : (c - 256);
    const float freq = expf((float)j * (-9.210340371976184f / 255.0f));
    const float arg = (float)t[b] * freq;
    emb[idx] = (c < 256) ? sinf(arg) : cosf(arg);
}

__global__ __launch_bounds__(256)
void k_wlin(const float* __restrict__ in, int K,
            const float* __restrict__ W, const float* __restrict__ bias,
            float* __restrict__ out, int N, int act)
{
    const int gw   = blockIdx.x * 4 + (threadIdx.x >> 6);
    const int lane = threadIdx.x & 63;
    const int b = gw / N, n = gw % N;
    const float* x = in + (size_t)b * K;
    const float* w = W + (size_t)n * K;
    float s = 0.0f;
    for (int k = lane; k < K; k += 64) s += x[k] * w[k];
    #pragma unroll
    for (int off = 32; off; off >>= 1) s += __shfl_xor(s, off, 64);
    if (lane == 0) {
        s += bias[n];
        if (act == 2) s = s / (1.0f + expf(-s));
        out[gw] = s;
    }
}

// ---------------------------------------------------------------------------

extern "C" void kernel_launch(void* const* d_in, const int* in_sizes, int n_in,
                              void* d_out, int out_size, void* d_ws, size_t ws_size,
                              hipStream_t stream)
{
    const float* x_t   = (const float*)d_in[0];
    const int*   tarr  = (const int*)  d_in[1];
    const float* cond  = (const float*)d_in[2];
    const float* cmask = (const float*)d_in[3];
    const float* sa_qw = (const float*)d_in[4];
    const float* sa_kw = (const float*)d_in[5];
    const float* sa_vw = (const float*)d_in[6];
    const float* sa_ow = (const float*)d_in[7];
    const float* sa_ob = (const float*)d_in[8];
    const float* ca_qw = (const float*)d_in[9];
    const float* ca_kw = (const float*)d_in[10];
    const float* ca_vw = (const float*)d_in[11];
    const float* ca_ow = (const float*)d_in[12];
    const float* ca_ob = (const float*)d_in[13];
    const float* f1w   = (const float*)d_in[14];
    const float* f1b   = (const float*)d_in[15];
    const float* f2w   = (const float*)d_in[16];
    const float* f2b   = (const float*)d_in[17];
    const float* n1g   = (const float*)d_in[18];
    const float* n1b   = (const float*)d_in[19];
    const float* n2g   = (const float*)d_in[20];
    const float* n2b   = (const float*)d_in[21];
    const float* n3g   = (const float*)d_in[22];
    const float* n3b   = (const float*)d_in[23];
    const float* tm1w  = (const float*)d_in[24];
    const float* tm1b  = (const float*)d_in[25];
    const float* tm2w  = (const float*)d_in[26];
    const float* tm2b  = (const float*)d_in[27];
    const float* ttw   = (const float*)d_in[28];
    const float* ttb   = (const float*)d_in[29];
    const float* pinw  = (const float*)d_in[30];
    const float* pinb  = (const float*)d_in[31];
    const float* poutw = (const float*)d_in[32];
    const float* poutb = (const float*)d_in[33];
    const float* fng   = (const float*)d_in[34];
    const float* fnb   = (const float*)d_in[35];

    const int M = BB * LQQ; // 2048
    const size_t MB = 1048576;

    char* w8 = (char*)d_ws;
    float* h   = (float*)(w8);                      // [2048,512] fp32  4 MB
    u16*  xn  = (u16*)(w8 +  4 * MB);               // 2 MB
    u16*  qb  = (u16*)(w8 +  6 * MB);               // 2 MB
    u16*  kb  = (u16*)(w8 +  8 * MB);               // 2 MB (self K)
    u16*  vbT = (u16*)(w8 + 10 * MB);               // [B,H,64,512] 2 MB
    u16*  ubT = (u16*)(w8 + 12 * MB);               // [B,H,64,512] wT 2 MB
    u16*  ob  = (u16*)(w8 + 14 * MB);               // 2 MB
    u16*  a1  = (u16*)(w8 + 16 * MB);               // FFN hidden 8 MB
    u16*  xtb = (u16*)(w8 + 16 * MB);               // aliases a1 (dead before FFN)
    u16*  cdb = (u16*)(w8 + 17 * MB);               // aliases a1 (dead before FFN)
    u16*  kbc6 = (u16*)(w8 + 32 * MB);              // 6 x [B*LCC, DD] = 3 MB
    u16*  vcT6 = (u16*)(w8 + 35 * MB);              // 6 x [B,H,64,128] = 3 MB
    float* emb = (float*)(w8 + 38 * MB);
    float* h1t = emb + BB * DD;
    float* te  = h1t + BB * DFFN;
    float* ttv = te  + BB * DD;
    u16* wq  = (u16*)(w8 + 39 * MB);
    u16* wk  = (u16*)(w8 + 42 * MB);
    u16* wv  = (u16*)(w8 + 45 * MB);
    u16* wo  = (u16*)(w8 + 48 * MB);
    u16* cwq = (u16*)(w8 + 51 * MB);
    u16* cwk = (u16*)(w8 + 54 * MB);
    u16* cwv = (u16*)(w8 + 57 * MB);
    u16* cwo = (u16*)(w8 + 60 * MB);
    u16* w1  = (u16*)(w8 + 63 * MB);                // 12 MB
    u16* w2  = (u16*)(w8 + 75 * MB);                // 12 MB
    u16* wpi = (u16*)(w8 + 87 * MB);                // 256 KB
    u16* wpo = (u16*)(w8 + 87 * MB + 262144);       // 256 KB
    float* pp  = (float*)(w8 + 88 * MB);            // split-K partials 4x4MB
    u16*  Pg  = (u16*)(w8 + 104 * MB);              // P [B*H,512,512] bf16 16 MB

    const dim3 T256(256);
    const dim3 LN_B(64, 4);
    const long long ZVT = (long long)HH * HD * LQQ; // 262144
    const long long ZWT = (long long)HH * HD * LCC; // 65536
    const long long ZP  = (long long)M * DD;        // partial stride 1048576
    const long long WST = (long long)DD * DD;       // 262144

    // ---- one fused bf16 conversion dispatch ----
    {
        const int NW4 = NLAYER * DD * DD / 4;
        const int NF4 = NLAYER * DFFN * DD / 4;
        CvtArgs a;
        const float* srcs[NSEG] = { sa_qw, sa_kw, sa_vw, sa_ow, ca_qw, ca_kw, ca_vw, ca_ow,
                                    f1w, f2w, pinw, poutw, x_t, cond };
        u16* dsts[NSEG] = { wq, wk, wv, wo, cwq, cwk, cwv, cwo,
                            w1, w2, wpi, wpo, xtb, cdb };
        const int n4s[NSEG] = { NW4, NW4, NW4, NW4, NW4, NW4, NW4, NW4,
                                NF4, NF4, DD * LATD / 4, LATD * DD / 4,
                                M * LATD / 4, BB * LCC * DD / 4 };
        int acc = 0;
        for (int i = 0; i < NSEG; i++) {
            a.src[i] = srcs[i]; a.dst[i] = dsts[i]; a.n4[i] = n4s[i];
            a.beg[i] = acc; acc += (n4s[i] + 255) / 256;
        }
        a.beg[NSEG] = acc;
        k_cvtm<<<acc, T256, 0, stream>>>(a);
    }

    // ---- time embedding path ----
    k_emb<<<(BB * DD + 255) / 256, 256, 0, stream>>>(tarr, emb);
    k_wlin<<<(BB * DFFN) / 4, T256, 0, stream>>>(emb, DD, tm1w, tm1b, h1t, DFFN, 2);
    k_wlin<<<(BB * DD) / 4,   T256, 0, stream>>>(h1t, DFFN, tm2w, tm2b, te, DD, 0);
    k_wlin<<<(BB * DD) / 4,   T256, 0, stream>>>(te, DD, ttw, ttb, ttv, DD, 0);

    // ---- all-layer cross K: kbc6[L] = cond @ ckw[L]^T (z = layer) ----
    k_g128b<false, 0><<<dim3(DD / 128, (BB * LCC) / 128, NLAYER), T256, 0, stream>>>(
        cdb, 0, DD, cwk, WST, DD, kbc6, (long long)BB * LCC * DD, DD, DD, 0, 0);
    // ---- all-layer cross V (transposed): vcT6[L] ----
    k_g128b<true, 7><<<dim3(DD / 128, (BB * LCC) / 128, NLAYER), T256, 0, stream>>>(
        cdb, 0, DD, cwv, WST, DD, vcT6, (long long)BB * HH * HD * LCC, DD, DD,
        ZWT, LCC);

    // ---- input projection: h = x_t @ pinw.T + pinb + ttv[b] ----
    k_g128<float, false><<<dim3(DD / 128, M / 128, 1), T256, 0, stream>>>(
        xtb, LATD, wpi, LATD, h, DD, LATD, pinb, ttv, DD, 9, 0, 0);

    for (int L = 0; L < NLAYER; L++) {
        const size_t LW = (size_t)L * DD * DD;

        // ======== self-attention with QGFD ========
        if (L == 0)
            k_ln<<<M / 4, LN_B, 0, stream>>>(h, xn,
                n1g + (size_t)L * DD, n1b + (size_t)L * DD);
        else
            k_ln2<4><<<M / 4, LN_B, 0, stream>>>(h, pp, ZP,
                f2b + (size_t)(L - 1) * DD, xn,
                n1g + (size_t)L * DD, n1b + (size_t)L * DD);

        // fused QKV (z: 0=q, 1=k, 2=v transposed)
        k_g128q<<<dim3(DD / 128, M / 128, 3), T256, 0, stream>>>(
            xn, DD, wq + LW, wk + LW, wv + LW, DD,
            qb, kb, vbT, DD, DD, ZVT, LQQ);

        // pass A: S+softmax, u=P@v, wT=(0.5u+0.5v)^T, P -> HBM
        k_attn1<<<dim3(1, LQQ / 64, BB * HH), T256, 0, stream>>>(
            qb, kb, vbT, ubT, Pg, 0.125f);

        // pass B: ob = P @ wT (no recompute)
        k_pw<<<dim3(1, LQQ / 64, BB * HH), T256, 0, stream>>>(Pg, ubT, ob);

        // ob @ ow.T -> split-K=2 partials
        k_g128<float, true><<<dim3(DD / 128, M / 128, 2), T256, 0, stream>>>(
            ob, DD, wo + LW, DD, pp, DD, 256, nullptr, nullptr, 0, 0, 0, ZP);

        // n2 LN + reduce wo partials + sa_ob bias
        k_ln2<2><<<M / 4, LN_B, 0, stream>>>(h, pp, ZP,
            sa_ob + (size_t)L * DD, xn,
            n2g + (size_t)L * DD, n2b + (size_t)L * DD);

        // ======== cross-attention (Q projection fused) ========
        k_attn0<<<dim3(1, LQQ / 64, BB * HH), T256, 0, stream>>>(
            xn, cwq + LW,
            kbc6 + (size_t)L * BB * LCC * DD, vcT6 + (size_t)L * BB * HH * HD * LCC,
            ob, cmask, 0.125f);

        // ob @ cow.T -> split-K=2 partials
        k_g128<float, true><<<dim3(DD / 128, M / 128, 2), T256, 0, stream>>>(
            ob, DD, cwo + LW, DD, pp, DD, 256, nullptr, nullptr, 0, 0, 0, ZP);

        // n3 LN + reduce cwo partials + ca_ob bias
        k_ln2<2><<<M / 4, LN_B, 0, stream>>>(h, pp, ZP,
            ca_ob + (size_t)L * DD, xn,
            n3g + (size_t)L * DD, n3b + (size_t)L * DD);

        // ======== FFN ========
        k_g128<u16, false><<<dim3(DFFN / 128, M / 128, 1), T256, 0, stream>>>(
            xn, DD, w1 + (size_t)L * DFFN * DD, DD,
            a1, DFFN, DD, f1b + (size_t)L * DFFN, nullptr, 0, 0, /*act=*/1, 0);

        // w2: split-K=4 partials (K=512/chunk, 256 blocks = 1/CU)
        k_g128<float, true><<<dim3(DD / 128, M / 128, 4), T256, 0, stream>>>(
            a1, DFFN, w2 + (size_t)L * DD * DFFN, DFFN, pp, DD, 512,
            nullptr, nullptr, 0, 0, 0, ZP);
    }

    // ---- final LN (+ last layer w2 partial reduce, NP=4) + output proj ----
    k_ln2<4><<<M / 4, LN_B, 0, stream>>>(h, pp, ZP,
        f2b + (size_t)(NLAYER - 1) * DD, xn, fng, fnb);
    k_g<32, 32, float, false><<<dim3(LATD / 32, M / 32, 1), T256, 0, stream>>>(
        xn, 0, 0, DD, wpo, nullptr, nullptr, 0, 0, DD,
        (float*)d_out, nullptr, nullptr, 0, 0, LATD,
        DD, 1, 1.0f, poutb, nullptr, 0, 0, 0.0f, nullptr, 0, 0, 0, 0, 0, 0, 0);
}

// Round 10
// 1147.490 us; speedup vs baseline: 1.5483x; 1.0032x over previous
//
#include <hip/hip_runtime.h>
#include <hip/hip_bf16.h>
#include <type_traits>

#define DD    512
#define HH    8
#define HD    64
#define NLAYER 6
#define DFFN  2048
#define LATD  256
#define BB    4
#define LQQ   512
#define LCC   128

typedef unsigned short u16;
typedef __attribute__((ext_vector_type(8))) short bf16x8;
typedef __attribute__((ext_vector_type(4))) float f32x4;
typedef __attribute__((ext_vector_type(4))) unsigned short u16x4;

__device__ __forceinline__ u16 f2bf(float f) {
    __hip_bfloat16 h = __float2bfloat16(f);
    return __builtin_bit_cast(u16, h);
}
__device__ __forceinline__ float bf2f(u16 u) {
    return __uint_as_float(((unsigned int)u) << 16);
}

// ---------------------------------------------------------------------------
// Legacy 32/64-tile MFMA GEMM (kept only for the small final projection).
// ---------------------------------------------------------------------------
template<int BM, int BN, typename TC, bool MULTI>
__global__ __launch_bounds__(256)
void k_g(const u16* __restrict__ A, long long sAb, long long sAh, int lda,
         const u16* __restrict__ B1, const u16* __restrict__ B2_, const u16* __restrict__ B3_,
         long long sBb, long long sBh, int ldb,
         TC* __restrict__ C1, TC* __restrict__ C2_, TC* __restrict__ C3_,
         long long sCb, long long sCh, int ldc,
         int K, int Hdim, float alpha,
         const float* __restrict__ bias,
         const float* __restrict__ res, int ldres, int res_shift,
         float beta2, const u16* __restrict__ add2, long long s2b, long long s2h,
         int act, int wt_mask, int wt_shift, long long sbT, int ldct)
{
    constexpr int SK = 72;
    constexpr int FM = BM / 32, FN = BN / 32;
    constexpr int PA = BM / 32, PB = BN / 32;

    const int z = blockIdx.z;
    const u16* Bm;
    TC* C;
    int wt;
    if constexpr (MULTI) {
        Bm = (z == 0) ? B1 : ((z == 1) ? B2_ : B3_);
        C  = (z == 0) ? C1 : ((z == 1) ? C2_ : C3_);
        wt = (wt_mask >> z) & 1;
    } else {
        const int zb = z / Hdim, zh = z % Hdim;
        A += (size_t)(zb * sAb + zh * sAh);
        Bm = B1 + (size_t)(zb * sBb + zh * sBh);
        C  = C1 + (size_t)(zb * sCb + zh * sCh);
        if (add2) add2 += (size_t)(zb * s2b + zh * s2h);
        wt = wt_mask & 1;
    }

    __shared__ u16 Asm[2][BM * SK];
    __shared__ u16 Bsm[2][BN * SK];

    const int t    = threadIdx.x;
    const int wid  = t >> 6, lane = t & 63;
    const int q    = lane >> 4, c = lane & 15;
    const int wm   = (wid >> 1) * (BM / 2), wn = (wid & 1) * (BN / 2);
    const int m0   = blockIdx.y * BM, n0 = blockIdx.x * BN;

    f32x4 acc[FM][FN];
    #pragma unroll
    for (int i = 0; i < FM; i++)
        #pragma unroll
        for (int j = 0; j < FN; j++) acc[i][j] = (f32x4){0.f, 0.f, 0.f, 0.f};

    uint4 ra[2][PA], rb[2][PB];
    const int NI = K >> 6;

    auto loadg = [&](int slot, int kt) {
        #pragma unroll
        for (int p = 0; p < PA; p++) {
            const int idx = p * 256 + t, r = idx >> 3, kg = (idx & 7) << 3;
            ra[slot][p] = *(const uint4*)(A + (size_t)(m0 + r) * lda + kt + kg);
        }
        #pragma unroll
        for (int p = 0; p < PB; p++) {
            const int idx = p * 256 + t, r = idx >> 3, kg = (idx & 7) << 3;
            rb[slot][p] = *(const uint4*)(Bm + (size_t)(n0 + r) * ldb + kt + kg);
        }
    };
    auto store = [&](int buf, int slot) {
        #pragma unroll
        for (int p = 0; p < PA; p++) {
            const int idx = p * 256 + t, r = idx >> 3, kg = (idx & 7) << 3;
            *(uint4*)&Asm[buf][r * SK + kg] = ra[slot][p];
        }
        #pragma unroll
        for (int p = 0; p < PB; p++) {
            const int idx = p * 256 + t, r = idx >> 3, kg = (idx & 7) << 3;
            *(uint4*)&Bsm[buf][r * SK + kg] = rb[slot][p];
        }
    };

    loadg(0, 0);
    if (NI > 1) loadg(1, 64);
    store(0, 0);

    for (int it = 0; it < NI; it++) {
        __syncthreads();
        const int cur = it & 1, nxt = cur ^ 1;
        if (it + 1 < NI) store(nxt, nxt);
        if (it + 2 < NI) loadg(cur, (it + 2) << 6);
        #pragma unroll
        for (int s = 0; s < 2; s++) {
            bf16x8 af[FM], bfv[FN];
            #pragma unroll
            for (int fm = 0; fm < FM; fm++)
                af[fm] = *(const bf16x8*)&Asm[cur][(wm + fm * 16 + c) * SK + s * 32 + q * 8];
            #pragma unroll
            for (int fn = 0; fn < FN; fn++)
                bfv[fn] = *(const bf16x8*)&Bsm[cur][(wn + fn * 16 + c) * SK + s * 32 + q * 8];
            #pragma unroll
            for (int fm = 0; fm < FM; fm++)
                #pragma unroll
                for (int fn = 0; fn < FN; fn++)
                    acc[fm][fn] = __builtin_amdgcn_mfma_f32_16x16x32_bf16(
                        af[fm], bfv[fn], acc[fm][fn], 0, 0, 0);
        }
    }

    if (wt) {
        if constexpr (std::is_same<TC, u16>::value) {
            #pragma unroll
            for (int fm = 0; fm < FM; fm++) {
                const int gm0 = m0 + wm + fm * 16 + q * 4;
                const long long roff =
                    (long long)(gm0 >> wt_shift) * sbT + (gm0 & ((1 << wt_shift) - 1));
                #pragma unroll
                for (int fn = 0; fn < FN; fn++) {
                    const int gn = n0 + wn + fn * 16 + c;
                    const long long a0 = (long long)gn * ldct + roff;
                    u16x4 o;
                    if (add2) {
                        const u16x4 av = *(const u16x4*)&add2[a0];
                        #pragma unroll
                        for (int r = 0; r < 4; r++)
                            o[r] = f2bf(alpha * acc[fm][fn][r] + beta2 * bf2f(av[r]));
                    } else {
                        #pragma unroll
                        for (int r = 0; r < 4; r++)
                            o[r] = f2bf(alpha * acc[fm][fn][r]);
                    }
                    *(u16x4*)&C[a0] = o;
                }
            }
        }
    } else {
        #pragma unroll
        for (int fm = 0; fm < FM; fm++) {
            #pragma unroll
            for (int reg = 0; reg < 4; reg++) {
                const int gm = m0 + wm + fm * 16 + q * 4 + reg;
                #pragma unroll
                for (int fn = 0; fn < FN; fn++) {
                    const int gn = n0 + wn + fn * 16 + c;
                    float v = alpha * acc[fm][fn][reg];
                    if (bias) v += bias[gn];
                    if (act == 1) v = 0.5f * v * (1.0f + erff(v * 0.7071067811865475f));
                    if (res)  v += res[(size_t)(gm >> res_shift) * ldres + gn];
                    if constexpr (std::is_same<TC, u16>::value)
                        C[(size_t)gm * ldc + gn] = f2bf(v);
                    else
                        C[(size_t)gm * ldc + gn] = v;
                }
            }
        }
    }
}

// ---------------------------------------------------------------------------
// Shared 128x128-tile MFMA core (m97 structure).
// ---------------------------------------------------------------------------
#define G128_CORE(Aptr, LDA, Bptr, LDB, KZ, NIV)                               \
    {                                                                          \
        for (int it = 0; it < (NIV); it++) {                                   \
            const int kt = (KZ) + (it << 6);                                   \
            _Pragma("unroll")                                                  \
            for (int j = 0; j < 4; j++) {                                      \
                const int r  = wid * 32 + j * 8 + lr;                          \
                const int kb = lkb ^ (r & 7);                                  \
                const u16* ga = (Aptr) + (size_t)(m0 + r) * (LDA) + kt + kb * 8;\
                const u16* gb = (Bptr) + (size_t)(n0 + r) * (LDB) + kt + kb * 8;\
                u16* la = &As[(wid * 32 + j * 8) * 64];                        \
                u16* lb = &Bs[(wid * 32 + j * 8) * 64];                        \
                __builtin_amdgcn_global_load_lds(                              \
                    (const __attribute__((address_space(1))) void*)ga,         \
                    (__attribute__((address_space(3))) void*)la, 16, 0, 0);    \
                __builtin_amdgcn_global_load_lds(                              \
                    (const __attribute__((address_space(1))) void*)gb,         \
                    (__attribute__((address_space(3))) void*)lb, 16, 0, 0);    \
            }                                                                  \
            __syncthreads();                                                   \
            _Pragma("unroll")                                                  \
            for (int s = 0; s < 2; s++) {                                      \
                bf16x8 af[4], bfv[4];                                          \
                _Pragma("unroll")                                              \
                for (int fm = 0; fm < 4; fm++) {                               \
                    const int row = wr * 64 + fm * 16 + c;                     \
                    const int blk = (s * 4 + q) ^ (row & 7);                   \
                    af[fm] = *(const bf16x8*)&As[row * 64 + blk * 8];          \
                }                                                              \
                _Pragma("unroll")                                              \
                for (int fn = 0; fn < 4; fn++) {                               \
                    const int row = wc * 64 + fn * 16 + c;                     \
                    const int blk = (s * 4 + q) ^ (row & 7);                   \
                    bfv[fn] = *(const bf16x8*)&Bs[row * 64 + blk * 8];         \
                }                                                              \
                _Pragma("unroll")                                              \
                for (int fm = 0; fm < 4; fm++)                                 \
                    _Pragma("unroll")                                          \
                    for (int fn = 0; fn < 4; fn++)                             \
                        acc[fm][fn] = __builtin_amdgcn_mfma_f32_16x16x32_bf16( \
                            af[fm], bfv[fn], acc[fm][fn], 0, 0, 0);            \
            }                                                                  \
            __syncthreads();                                                   \
        }                                                                      \
    }

#define G128_PROLOG                                                            \
    __shared__ u16 As[128 * 64];                                               \
    __shared__ u16 Bs[128 * 64];                                               \
    const int t = threadIdx.x, wid = t >> 6, lane = t & 63;                    \
    const int q = lane >> 4, c = lane & 15;                                    \
    const int wr = wid >> 1, wc = wid & 1;                                     \
    const int m0 = blockIdx.y * 128, n0 = blockIdx.x * 128;                    \
    const int lr  = lane >> 3;                                                 \
    const int lkb = lane & 7;                                                  \
    f32x4 acc[4][4];                                                           \
    _Pragma("unroll")                                                          \
    for (int i = 0; i < 4; i++)                                                \
        _Pragma("unroll")                                                      \
        for (int j = 0; j < 4; j++) acc[i][j] = (f32x4){0.f, 0.f, 0.f, 0.f};

// ---------------------------------------------------------------------------
// General 128x128 GEMM. PART: raw fp32 partial stores into C+z*zstr (split-K).
// ---------------------------------------------------------------------------
template<typename TC, bool PART>
__global__ __launch_bounds__(256)
void k_g128(const u16* __restrict__ A, int lda,
            const u16* __restrict__ B, int ldb,
            TC* __restrict__ C, int ldc, int K,
            const float* __restrict__ bias,
            const float* __restrict__ res, int ldres, int rshift, int act,
            long long zstr)
{
    G128_PROLOG
    const int kz = blockIdx.z * K;
    const int NI = K >> 6;
    G128_CORE(A, lda, B, ldb, kz, NI)

    #pragma unroll
    for (int fm = 0; fm < 4; fm++) {
        #pragma unroll
        for (int reg = 0; reg < 4; reg++) {
            const int gm = m0 + wr * 64 + fm * 16 + q * 4 + reg;
            #pragma unroll
            for (int fn = 0; fn < 4; fn++) {
                const int gn = n0 + wc * 64 + fn * 16 + c;
                float v = acc[fm][fn][reg];
                if constexpr (PART) {
                    ((float*)C)[(size_t)blockIdx.z * zstr + (size_t)gm * ldc + gn] = v;
                } else {
                    if (bias) v += bias[gn];
                    if (act == 1) v = 0.5f * v * (1.0f + erff(v * 0.7071067811865475f));
                    if (res)  v += res[(size_t)(gm >> rshift) * ldres + gn];
                    if constexpr (std::is_same<TC, u16>::value)
                        C[(size_t)gm * ldc + gn] = f2bf(v);
                    else
                        C[(size_t)gm * ldc + gn] = v;
                }
            }
        }
    }
}

// ---------------------------------------------------------------------------
// QKV triple 128x128 GEMM: z selects (B,C); z==2 writes V transposed.
// ---------------------------------------------------------------------------
__global__ __launch_bounds__(256)
void k_g128q(const u16* __restrict__ A, int lda,
             const u16* __restrict__ B1, const u16* __restrict__ B2,
             const u16* __restrict__ B3, int ldb,
             u16* __restrict__ C1, u16* __restrict__ C2, u16* __restrict__ C3,
             int ldc, int K, long long sbT, int ldct)
{
    const int z = blockIdx.z;
    const u16* B = (z == 0) ? B1 : ((z == 1) ? B2 : B3);
    u16* C = (z == 0) ? C1 : ((z == 1) ? C2 : C3);

    G128_PROLOG
    const int NI = K >> 6;
    G128_CORE(A, lda, B, ldb, 0, NI)

    if (z == 2) {
        #pragma unroll
        for (int fm = 0; fm < 4; fm++) {
            const int gm0 = m0 + wr * 64 + fm * 16 + q * 4;
            const long long roff = (long long)(gm0 >> 9) * sbT + (gm0 & 511);
            #pragma unroll
            for (int fn = 0; fn < 4; fn++) {
                const int gn = n0 + wc * 64 + fn * 16 + c;
                const long long a0 = (long long)gn * ldct + roff;
                u16x4 o;
                #pragma unroll
                for (int r = 0; r < 4; r++) o[r] = f2bf(acc[fm][fn][r]);
                *(u16x4*)&C[a0] = o;
            }
        }
    } else {
        #pragma unroll
        for (int fm = 0; fm < 4; fm++)
            #pragma unroll
            for (int reg = 0; reg < 4; reg++) {
                const int gm = m0 + wr * 64 + fm * 16 + q * 4 + reg;
                #pragma unroll
                for (int fn = 0; fn < 4; fn++) {
                    const int gn = n0 + wc * 64 + fn * 16 + c;
                    C[(size_t)gm * ldc + gn] = f2bf(acc[fm][fn][reg]);
                }
            }
    }
}

// ---------------------------------------------------------------------------
// z-batched 128x128 GEMM (per-layer cross K/V precompute).
// ---------------------------------------------------------------------------
template<bool WT, int SH>
__global__ __launch_bounds__(256)
void k_g128b(const u16* __restrict__ A, long long sAz, int lda,
             const u16* __restrict__ B, long long sBz, int ldb,
             u16* __restrict__ C, long long sCz, int ldc, int K,
             long long sbT, int ldct)
{
    const int z = blockIdx.z;
    A += (size_t)z * sAz;
    B += (size_t)z * sBz;
    C += (size_t)z * sCz;

    G128_PROLOG
    const int NI = K >> 6;
    G128_CORE(A, lda, B, ldb, 0, NI)

    if constexpr (WT) {
        #pragma unroll
        for (int fm = 0; fm < 4; fm++) {
            const int gm0 = m0 + wr * 64 + fm * 16 + q * 4;
            const long long roff =
                (long long)(gm0 >> SH) * sbT + (gm0 & ((1 << SH) - 1));
            #pragma unroll
            for (int fn = 0; fn < 4; fn++) {
                const int gn = n0 + wc * 64 + fn * 16 + c;
                const long long a0 = (long long)gn * ldct + roff;
                u16x4 o;
                #pragma unroll
                for (int r = 0; r < 4; r++) o[r] = f2bf(acc[fm][fn][r]);
                *(u16x4*)&C[a0] = o;
            }
        }
    } else {
        #pragma unroll
        for (int fm = 0; fm < 4; fm++)
            #pragma unroll
            for (int reg = 0; reg < 4; reg++) {
                const int gm = m0 + wr * 64 + fm * 16 + q * 4 + reg;
                #pragma unroll
                for (int fn = 0; fn < 4; fn++) {
                    const int gn = n0 + wc * 64 + fn * 16 + c;
                    C[(size_t)gm * ldc + gn] = f2bf(acc[fm][fn][reg]);
                }
            }
    }
}

// ---------------------------------------------------------------------------
// Self-attention pass A: S=q@k^T, softmax -> P; u=P@v;
// wT=(0.5u+0.5v)^T; ALSO writes P (bf16, bit-identical to the Ps LDS values)
// so pass B (k_pw) can skip the recompute.
// ---------------------------------------------------------------------------
__global__ __launch_bounds__(256)
void k_attn1(const u16* __restrict__ qb, const u16* __restrict__ kb,
             const u16* __restrict__ vT, u16* __restrict__ wT,
             u16* __restrict__ Pg, float alpha)
{
    constexpr int NCT = 4;
    constexpr int NJ  = 32;
    constexpr int SM1 = 64 * 72 * 2 + 2 * 128 * 72 * 2;  // 46080
    constexpr int SM2 = 2 * 64 * 136 * 2;                // 34816
    constexpr int SMEM = SM1 > SM2 ? SM1 : SM2;
    __shared__ char smem[SMEM];
    u16* Qs = (u16*)smem;
    u16* Ks = (u16*)(smem + 64 * 72 * 2);
    u16* Ps = (u16*)smem;
    u16* Vs = (u16*)(smem + 64 * 136 * 2);

    const int z = blockIdx.z, b = z >> 3, hh = z & 7;
    const int m0 = blockIdx.y * 64;
    const int t = threadIdx.x, w = t >> 6, lane = t & 63;
    const int q = lane >> 4, c = lane & 15;

    const u16* qbase = qb + ((size_t)(b * LQQ + m0)) * DD + hh * HD;
    const u16* kbase = kb + ((size_t)b * LQQ) * DD + hh * HD;
    const u16* vbase = vT + (size_t)z * HD * LQQ;

    // ---- stage Q (64 x 64) ----
    #pragma unroll
    for (int p = 0; p < 2; p++) {
        const int idx = p * 256 + t, r = idx >> 3, kg = (idx & 7) << 3;
        *(uint4*)&Qs[r * 72 + kg] = *(const uint4*)(qbase + (size_t)r * DD + kg);
    }

    f32x4 acc[NJ];
    #pragma unroll
    for (int j = 0; j < NJ; j++) acc[j] = (f32x4){0.f, 0.f, 0.f, 0.f};

    auto stageK = [&](u16* dst, int ct) {
        #pragma unroll
        for (int p = 0; p < 4; p++) {
            const int idx = p * 256 + t, r = idx >> 3, kg = (idx & 7) << 3;
            *(uint4*)&dst[r * 72 + kg] =
                *(const uint4*)(kbase + (size_t)(ct * 128 + r) * DD + kg);
        }
    };

    stageK(Ks, 0);
    __syncthreads();
    #pragma unroll
    for (int ct = 0; ct < NCT; ct++) {
        u16* cur = Ks + (ct & 1) * (128 * 72);
        if (ct + 1 < NCT) stageK(Ks + ((ct + 1) & 1) * (128 * 72), ct + 1);
        #pragma unroll
        for (int s = 0; s < 2; s++) {
            const bf16x8 af = *(const bf16x8*)&Qs[(w * 16 + c) * 72 + s * 32 + q * 8];
            #pragma unroll
            for (int fn = 0; fn < 8; fn++) {
                const bf16x8 bv = *(const bf16x8*)&cur[(fn * 16 + c) * 72 + s * 32 + q * 8];
                acc[ct * 8 + fn] = __builtin_amdgcn_mfma_f32_16x16x32_bf16(
                    af, bv, acc[ct * 8 + fn], 0, 0, 0);
            }
        }
        if (ct + 1 < NCT) __syncthreads();
    }

    // ---- row softmax ----
    float mx[4] = {-3.402823466e38f, -3.402823466e38f, -3.402823466e38f, -3.402823466e38f};
    #pragma unroll
    for (int j = 0; j < NJ; j++)
        #pragma unroll
        for (int r = 0; r < 4; r++) {
            const float x = alpha * acc[j][r];
            acc[j][r] = x;
            mx[r] = fmaxf(mx[r], x);
        }
    #pragma unroll
    for (int r = 0; r < 4; r++)
        #pragma unroll
        for (int m = 8; m; m >>= 1) mx[r] = fmaxf(mx[r], __shfl_xor(mx[r], m, 64));
    float sum[4] = {0.f, 0.f, 0.f, 0.f};
    #pragma unroll
    for (int j = 0; j < NJ; j++)
        #pragma unroll
        for (int r = 0; r < 4; r++) {
            const float e = expf(acc[j][r] - mx[r]);
            acc[j][r] = e;
            sum[r] += e;
        }
    #pragma unroll
    for (int r = 0; r < 4; r++)
        #pragma unroll
        for (int m = 8; m; m >>= 1) sum[r] += __shfl_xor(sum[r], m, 64);
    #pragma unroll
    for (int r = 0; r < 4; r++) sum[r] = 1.0f / sum[r];
    #pragma unroll
    for (int j = 0; j < NJ; j++)
        #pragma unroll
        for (int r = 0; r < 4; r++) acc[j][r] *= sum[r];

    // ---- phase 2: u = P @ v (writing P to HBM alongside the Ps stores) ----
    f32x4 ua[4];
    #pragma unroll
    for (int fn = 0; fn < 4; fn++) ua[fn] = (f32x4){0.f, 0.f, 0.f, 0.f};

    __syncthreads();   // Qs/Ks -> Ps/Vs alias
    #pragma unroll
    for (int ct = 0; ct < NCT; ct++) {
        #pragma unroll
        for (int j = 0; j < 8; j++)
            #pragma unroll
            for (int r = 0; r < 4; r++) {
                const u16 pv = f2bf(acc[ct * 8 + j][r]);
                Ps[(w * 16 + q * 4 + r) * 136 + j * 16 + c] = pv;
                Pg[((size_t)z * LQQ + m0 + w * 16 + q * 4 + r) * LQQ +
                   ct * 128 + j * 16 + c] = pv;
            }
        #pragma unroll
        for (int p = 0; p < 4; p++) {
            const int idx = p * 256 + t, rr = idx >> 4, kg = (idx & 15) << 3;
            *(uint4*)&Vs[rr * 136 + kg] =
                *(const uint4*)(vbase + (size_t)rr * LQQ + ct * 128 + kg);
        }
        __syncthreads();
        #pragma unroll
        for (int ks = 0; ks < 4; ks++) {
            const bf16x8 af = *(const bf16x8*)&Ps[(w * 16 + c) * 136 + ks * 32 + q * 8];
            #pragma unroll
            for (int fn = 0; fn < 4; fn++) {
                const bf16x8 bv = *(const bf16x8*)&Vs[(fn * 16 + c) * 136 + ks * 32 + q * 8];
                ua[fn] = __builtin_amdgcn_mfma_f32_16x16x32_bf16(af, bv, ua[fn], 0, 0, 0);
            }
        }
        if (ct + 1 < NCT) __syncthreads();
    }

    // wT = (0.5*u + 0.5*v)^T
    #pragma unroll
    for (int fn = 0; fn < 4; fn++) {
        const int col = fn * 16 + c;
        const size_t a0 = ((size_t)z * HD + col) * LQQ + m0 + w * 16 + q * 4;
        const u16x4 vv = *(const u16x4*)&vT[a0];
        u16x4 o;
        #pragma unroll
        for (int r = 0; r < 4; r++)
            o[r] = f2bf(0.5f * ua[fn][r] + 0.5f * bf2f(vv[r]));
        *(u16x4*)&wT[a0] = o;
    }
}

// ---------------------------------------------------------------------------
// Self-attention pass B: ob = P @ wT (P from HBM, no recompute).
// ---------------------------------------------------------------------------
__global__ __launch_bounds__(256)
void k_pw(const u16* __restrict__ Pg, const u16* __restrict__ wT,
          u16* __restrict__ uout)
{
    __shared__ u16 smem[2 * 64 * 136];
    u16* Ps = smem;
    u16* Vs = smem + 64 * 136;

    const int z = blockIdx.z, b = z >> 3, hh = z & 7;
    const int m0 = blockIdx.y * 64;
    const int t = threadIdx.x, w = t >> 6, lane = t & 63;
    const int q = lane >> 4, c = lane & 15;

    const u16* pbase = Pg + ((size_t)z * LQQ + m0) * LQQ;
    const u16* vbase = wT + (size_t)z * HD * LQQ;

    f32x4 ua[4];
    #pragma unroll
    for (int fn = 0; fn < 4; fn++) ua[fn] = (f32x4){0.f, 0.f, 0.f, 0.f};

    #pragma unroll
    for (int ct = 0; ct < 4; ct++) {
        #pragma unroll
        for (int p = 0; p < 4; p++) {
            const int idx = p * 256 + t, rr = idx >> 4, kg = (idx & 15) << 3;
            *(uint4*)&Ps[rr * 136 + kg] =
                *(const uint4*)(pbase + (size_t)rr * LQQ + ct * 128 + kg);
            *(uint4*)&Vs[rr * 136 + kg] =
                *(const uint4*)(vbase + (size_t)rr * LQQ + ct * 128 + kg);
        }
        __syncthreads();
        #pragma unroll
        for (int ks = 0; ks < 4; ks++) {
            const bf16x8 af = *(const bf16x8*)&Ps[(w * 16 + c) * 136 + ks * 32 + q * 8];
            #pragma unroll
            for (int fn = 0; fn < 4; fn++) {
                const bf16x8 bv = *(const bf16x8*)&Vs[(fn * 16 + c) * 136 + ks * 32 + q * 8];
                ua[fn] = __builtin_amdgcn_mfma_f32_16x16x32_bf16(af, bv, ua[fn], 0, 0, 0);
            }
        }
        if (ct + 1 < 4) __syncthreads();
    }

    #pragma unroll
    for (int fn = 0; fn < 4; fn++)
        #pragma unroll
        for (int r = 0; r < 4; r++)
            uout[((size_t)b * LQQ + m0 + w * 16 + q * 4 + r) * DD + hh * HD + fn * 16 + c] =
                f2bf(ua[fn][r]);
}

// ---------------------------------------------------------------------------
// Cross-attention with FUSED Q projection: q = xn[m0..64] @ cwq[h-slice]^T
// computed per block (no redundancy: each block owns its (rows, head) slice).
// Then S=q@k^T + mask + softmax, ob = P@vc. LK=128.
// ---------------------------------------------------------------------------
__global__ __launch_bounds__(256)
void k_attn0(const u16* __restrict__ xnp, const u16* __restrict__ wqp,
             const u16* __restrict__ kbp, const u16* __restrict__ vT,
             u16* __restrict__ uout, const float* __restrict__ mask,
             float alpha)
{
    constexpr int NJ = 8;
    constexpr int SMEM = 2 * 64 * 136 * 2;   // 34816 (covers 27648 phase-1)
    __shared__ char smem[SMEM];
    u16* Qs = (u16*)smem;
    u16* Ks = (u16*)(smem + 64 * 72 * 2);
    u16* Xs = Ks;                  // mini-GEMM staging (aliases Ks region)
    u16* Ws = Ks + 64 * 72;
    u16* Ps = (u16*)smem;
    u16* Vs = (u16*)(smem + 64 * 136 * 2);

    const int z = blockIdx.z, b = z >> 3, hh = z & 7;
    const int m0 = blockIdx.y * 64;
    const int t = threadIdx.x, w = t >> 6, lane = t & 63;
    const int q = lane >> 4, c = lane & 15;

    const u16* xbase = xnp + ((size_t)(b * LQQ + m0)) * DD;
    const u16* wbase = wqp + (size_t)(hh * HD) * DD;
    const u16* kbase = kbp + ((size_t)b * LCC) * DD + hh * HD;
    const u16* vbase = vT + (size_t)z * HD * LCC;

    // ---- fused Q projection: q[64x64] = xn-slice @ wq-slice^T (K=512) ----
    f32x4 qa[4];
    #pragma unroll
    for (int fn = 0; fn < 4; fn++) qa[fn] = (f32x4){0.f, 0.f, 0.f, 0.f};
    for (int kc = 0; kc < 8; kc++) {
        #pragma unroll
        for (int p = 0; p < 2; p++) {
            const int idx = p * 256 + t, r = idx >> 3, kg = (idx & 7) << 3;
            *(uint4*)&Xs[r * 72 + kg] =
                *(const uint4*)(xbase + (size_t)r * DD + kc * 64 + kg);
            *(uint4*)&Ws[r * 72 + kg] =
                *(const uint4*)(wbase + (size_t)r * DD + kc * 64 + kg);
        }
        __syncthreads();
        #pragma unroll
        for (int s = 0; s < 2; s++) {
            const bf16x8 af = *(const bf16x8*)&Xs[(w * 16 + c) * 72 + s * 32 + q * 8];
            #pragma unroll
            for (int fn = 0; fn < 4; fn++) {
                const bf16x8 bv = *(const bf16x8*)&Ws[(fn * 16 + c) * 72 + s * 32 + q * 8];
                qa[fn] = __builtin_amdgcn_mfma_f32_16x16x32_bf16(af, bv, qa[fn], 0, 0, 0);
            }
        }
        __syncthreads();
    }
    // write q to Qs (row = w*16+q*4+r, col = fn*16+c)
    #pragma unroll
    for (int fn = 0; fn < 4; fn++)
        #pragma unroll
        for (int r = 0; r < 4; r++)
            Qs[(w * 16 + q * 4 + r) * 72 + fn * 16 + c] = f2bf(qa[fn][r]);

    // ---- stage K (128 x 64) ----
    #pragma unroll
    for (int p = 0; p < 4; p++) {
        const int idx = p * 256 + t, r = idx >> 3, kg = (idx & 7) << 3;
        *(uint4*)&Ks[r * 72 + kg] = *(const uint4*)(kbase + (size_t)r * DD + kg);
    }
    __syncthreads();

    f32x4 acc[NJ];
    #pragma unroll
    for (int j = 0; j < NJ; j++) acc[j] = (f32x4){0.f, 0.f, 0.f, 0.f};

    #pragma unroll
    for (int s = 0; s < 2; s++) {
        const bf16x8 af = *(const bf16x8*)&Qs[(w * 16 + c) * 72 + s * 32 + q * 8];
        #pragma unroll
        for (int fn = 0; fn < 8; fn++) {
            const bf16x8 bv = *(const bf16x8*)&Ks[(fn * 16 + c) * 72 + s * 32 + q * 8];
            acc[fn] = __builtin_amdgcn_mfma_f32_16x16x32_bf16(af, bv, acc[fn], 0, 0, 0);
        }
    }

    // ---- row softmax with key mask ----
    bool msk[NJ];
    #pragma unroll
    for (int j = 0; j < NJ; j++)
        msk[j] = (mask[b * LCC + j * 16 + c] == 0.0f);
    float mx[4] = {-3.402823466e38f, -3.402823466e38f, -3.402823466e38f, -3.402823466e38f};
    #pragma unroll
    for (int j = 0; j < NJ; j++)
        #pragma unroll
        for (int r = 0; r < 4; r++) {
            float x = alpha * acc[j][r];
            if (msk[j]) x = -3.402823466e38f;
            acc[j][r] = x;
            mx[r] = fmaxf(mx[r], x);
        }
    #pragma unroll
    for (int r = 0; r < 4; r++)
        #pragma unroll
        for (int m = 8; m; m >>= 1) mx[r] = fmaxf(mx[r], __shfl_xor(mx[r], m, 64));
    float sum[4] = {0.f, 0.f, 0.f, 0.f};
    #pragma unroll
    for (int j = 0; j < NJ; j++)
        #pragma unroll
        for (int r = 0; r < 4; r++) {
            const float e = expf(acc[j][r] - mx[r]);
            acc[j][r] = e;
            sum[r] += e;
        }
    #pragma unroll
    for (int r = 0; r < 4; r++)
        #pragma unroll
        for (int m = 8; m; m >>= 1) sum[r] += __shfl_xor(sum[r], m, 64);
    #pragma unroll
    for (int r = 0; r < 4; r++) sum[r] = 1.0f / sum[r];
    #pragma unroll
    for (int j = 0; j < NJ; j++)
        #pragma unroll
        for (int r = 0; r < 4; r++) acc[j][r] *= sum[r];

    // ---- phase 2: ob = P @ vc ----
    f32x4 ua[4];
    #pragma unroll
    for (int fn = 0; fn < 4; fn++) ua[fn] = (f32x4){0.f, 0.f, 0.f, 0.f};

    __syncthreads();   // Qs/Ks -> Ps/Vs alias
    #pragma unroll
    for (int j = 0; j < 8; j++)
        #pragma unroll
        for (int r = 0; r < 4; r++)
            Ps[(w * 16 + q * 4 + r) * 136 + j * 16 + c] = f2bf(acc[j][r]);
    #pragma unroll
    for (int p = 0; p < 4; p++) {
        const int idx = p * 256 + t, rr = idx >> 4, kg = (idx & 15) << 3;
        *(uint4*)&Vs[rr * 136 + kg] =
            *(const uint4*)(vbase + (size_t)rr * LCC + kg);
    }
    __syncthreads();
    #pragma unroll
    for (int ks = 0; ks < 4; ks++) {
        const bf16x8 af = *(const bf16x8*)&Ps[(w * 16 + c) * 136 + ks * 32 + q * 8];
        #pragma unroll
        for (int fn = 0; fn < 4; fn++) {
            const bf16x8 bv = *(const bf16x8*)&Vs[(fn * 16 + c) * 136 + ks * 32 + q * 8];
            ua[fn] = __builtin_amdgcn_mfma_f32_16x16x32_bf16(af, bv, ua[fn], 0, 0, 0);
        }
    }

    #pragma unroll
    for (int fn = 0; fn < 4; fn++)
        #pragma unroll
        for (int r = 0; r < 4; r++)
            uout[((size_t)b * LQQ + m0 + w * 16 + q * 4 + r) * DD + hh * HD + fn * 16 + c] =
                f2bf(ua[fn][r]);
}

// ---------------------------------------------------------------------------
// Fused fp32->bf16 conversion, 8 floats per thread (32B read / 16B write).
// ---------------------------------------------------------------------------
#define NSEG 14
struct CvtArgs {
    const float* src[NSEG];
    u16*         dst[NSEG];
    int          beg[NSEG + 1];
    int          n8[NSEG];
};

__global__ __launch_bounds__(256)
void k_cvtm(CvtArgs a)
{
    const int blk = blockIdx.x;
    int s = 0;
    #pragma unroll
    for (int i = 1; i < NSEG; i++) if (blk >= a.beg[i]) s = i;
    const int i8 = (blk - a.beg[s]) * 256 + threadIdx.x;
    if (i8 >= a.n8[s]) return;
    const float* sp = a.src[s] + (size_t)i8 * 8;
    const float4 v0 = *(const float4*)sp;
    const float4 v1 = *(const float4*)(sp + 4);
    uint4 u;
    u.x = (unsigned)f2bf(v0.x) | ((unsigned)f2bf(v0.y) << 16);
    u.y = (unsigned)f2bf(v0.z) | ((unsigned)f2bf(v0.w) << 16);
    u.z = (unsigned)f2bf(v1.x) | ((unsigned)f2bf(v1.y) << 16);
    u.w = (unsigned)f2bf(v1.z) | ((unsigned)f2bf(v1.w) << 16);
    *(uint4*)(a.dst[s] + (size_t)i8 * 8) = u;
}

// ---------------------------------------------------------------------------
__global__ __launch_bounds__(256)
void k_ln(const float* __restrict__ X, u16* __restrict__ Y,
          const float* __restrict__ g, const float* __restrict__ b)
{
    const int row  = blockIdx.x * 4 + threadIdx.y;
    const int lane = threadIdx.x;
    const float* x = X + (size_t)row * DD;
    float v[8];
    float s = 0.0f;
    #pragma unroll
    for (int i = 0; i < 8; i++) { v[i] = x[lane + i * 64]; s += v[i]; }
    #pragma unroll
    for (int off = 32; off; off >>= 1) s += __shfl_xor(s, off, 64);
    const float m = s * (1.0f / 512.0f);
    float qq = 0.0f;
    #pragma unroll
    for (int i = 0; i < 8; i++) { const float d = v[i] - m; qq += d * d; }
    #pragma unroll
    for (int off = 32; off; off >>= 1) qq += __shfl_xor(qq, off, 64);
    const float r = rsqrtf(qq * (1.0f / 512.0f) + 1e-5f);
    u16* y = Y + (size_t)row * DD;
    #pragma unroll
    for (int i = 0; i < 8; i++) {
        const int c = lane + i * 64;
        y[c] = f2bf((v[i] - m) * r * g[c] + b[c]);
    }
}

// ---------------------------------------------------------------------------
// Accumulating LayerNorm: h += sum(NP partials) + bias, then xn = LN(h).
// ---------------------------------------------------------------------------
template<int NP>
__global__ __launch_bounds__(256)
void k_ln2(float* __restrict__ H, const float* __restrict__ P, long long zstr,
           const float* __restrict__ bias, u16* __restrict__ Y,
           const float* __restrict__ g, const float* __restrict__ b)
{
    const int row  = blockIdx.x * 4 + threadIdx.y;
    const int lane = threadIdx.x;
    float* x = H + (size_t)row * DD;
    const float* pb = P + (size_t)row * DD;
    float v[8];
    float s = 0.0f;
    #pragma unroll
    for (int i = 0; i < 8; i++) {
        const int c = lane + i * 64;
        float t = x[c] + bias[c];
        #pragma unroll
        for (int p = 0; p < NP; p++) t += pb[(size_t)p * zstr + c];
        v[i] = t;
        s += t;
    }
    #pragma unroll
    for (int off = 32; off; off >>= 1) s += __shfl_xor(s, off, 64);
    const float m = s * (1.0f / 512.0f);
    float qq = 0.0f;
    #pragma unroll
    for (int i = 0; i < 8; i++) { const float d = v[i] - m; qq += d * d; }
    #pragma unroll
    for (int off = 32; off; off >>= 1) qq += __shfl_xor(qq, off, 64);
    const float r = rsqrtf(qq * (1.0f / 512.0f) + 1e-5f);
    u16* y = Y + (size_t)row * DD;
    #pragma unroll
    for (int i = 0; i < 8; i++) {
        const int c = lane + i * 64;
        x[c] = v[i];
        y[c] = f2bf((v[i] - m) * r * g[c] + b[c]);
    }
}

// ---------------------------------------------------------------------------
__global__ void k_emb(const int* __restrict__ t, float* __restrict__ emb)
{
    const int idx = blockIdx.x * 256 + threadIdx.x;
    if (idx >= BB * DD) return;
    const int b = idx / DD, c = idx % DD;
    const int j = (c < 256) ? c : (c - 256);
    const float freq = expf((float)j * (-9.210340371976184f / 255.0f));
    const float arg = (float)t[b] * freq;
    emb[idx] = (c < 256) ? sinf(arg) : cosf(arg);
}

__global__ __launch_bounds__(256)
void k_wlin(const float* __restrict__ in, int K,
            const float* __restrict__ W, const float* __restrict__ bias,
            float* __restrict__ out, int N, int act)
{
    const int gw   = blockIdx.x * 4 + (threadIdx.x >> 6);
    const int lane = threadIdx.x & 63;
    const int b = gw / N, n = gw % N;
    const float* x = in + (size_t)b * K;
    const float* w = W + (size_t)n * K;
    float s = 0.0f;
    for (int k = lane; k < K; k += 64) s += x[k] * w[k];
    #pragma unroll
    for (int off = 32; off; off >>= 1) s += __shfl_xor(s, off, 64);
    if (lane == 0) {
        s += bias[n];
        if (act == 2) s = s / (1.0f + expf(-s));
        out[gw] = s;
    }
}

// ---------------------------------------------------------------------------

extern "C" void kernel_launch(void* const* d_in, const int* in_sizes, int n_in,
                              void* d_out, int out_size, void* d_ws, size_t ws_size,
                              hipStream_t stream)
{
    const float* x_t   = (const float*)d_in[0];
    const int*   tarr  = (const int*)  d_in[1];
    const float* cond  = (const float*)d_in[2];
    const float* cmask = (const float*)d_in[3];
    const float* sa_qw = (const float*)d_in[4];
    const float* sa_kw = (const float*)d_in[5];
    const float* sa_vw = (const float*)d_in[6];
    const float* sa_ow = (const float*)d_in[7];
    const float* sa_ob = (const float*)d_in[8];
    const float* ca_qw = (const float*)d_in[9];
    const float* ca_kw = (const float*)d_in[10];
    const float* ca_vw = (const float*)d_in[11];
    const float* ca_ow = (const float*)d_in[12];
    const float* ca_ob = (const float*)d_in[13];
    const float* f1w   = (const float*)d_in[14];
    const float* f1b   = (const float*)d_in[15];
    const float* f2w   = (const float*)d_in[16];
    const float* f2b   = (const float*)d_in[17];
    const float* n1g   = (const float*)d_in[18];
    const float* n1b   = (const float*)d_in[19];
    const float* n2g   = (const float*)d_in[20];
    const float* n2b   = (const float*)d_in[21];
    const float* n3g   = (const float*)d_in[22];
    const float* n3b   = (const float*)d_in[23];
    const float* tm1w  = (const float*)d_in[24];
    const float* tm1b  = (const float*)d_in[25];
    const float* tm2w  = (const float*)d_in[26];
    const float* tm2b  = (const float*)d_in[27];
    const float* ttw   = (const float*)d_in[28];
    const float* ttb   = (const float*)d_in[29];
    const float* pinw  = (const float*)d_in[30];
    const float* pinb  = (const float*)d_in[31];
    const float* poutw = (const float*)d_in[32];
    const float* poutb = (const float*)d_in[33];
    const float* fng   = (const float*)d_in[34];
    const float* fnb   = (const float*)d_in[35];

    const int M = BB * LQQ; // 2048
    const size_t MB = 1048576;

    char* w8 = (char*)d_ws;
    float* h   = (float*)(w8);                      // [2048,512] fp32  4 MB
    u16*  xn  = (u16*)(w8 +  4 * MB);               // 2 MB
    u16*  qb  = (u16*)(w8 +  6 * MB);               // 2 MB
    u16*  kb  = (u16*)(w8 +  8 * MB);               // 2 MB (self K)
    u16*  vbT = (u16*)(w8 + 10 * MB);               // [B,H,64,512] 2 MB
    u16*  ubT = (u16*)(w8 + 12 * MB);               // [B,H,64,512] wT 2 MB
    u16*  ob  = (u16*)(w8 + 14 * MB);               // 2 MB
    u16*  a1  = (u16*)(w8 + 16 * MB);               // FFN hidden 8 MB
    u16*  xtb = (u16*)(w8 + 16 * MB);               // aliases a1 (dead before FFN)
    u16*  cdb = (u16*)(w8 + 17 * MB);               // aliases a1 (dead before FFN)
    u16*  kbc6 = (u16*)(w8 + 32 * MB);              // 6 x [B*LCC, DD] = 3 MB
    u16*  vcT6 = (u16*)(w8 + 35 * MB);              // 6 x [B,H,64,128] = 3 MB
    float* emb = (float*)(w8 + 38 * MB);
    float* h1t = emb + BB * DD;
    float* te  = h1t + BB * DFFN;
    float* ttv = te  + BB * DD;
    u16* wq  = (u16*)(w8 + 39 * MB);
    u16* wk  = (u16*)(w8 + 42 * MB);
    u16* wv  = (u16*)(w8 + 45 * MB);
    u16* wo  = (u16*)(w8 + 48 * MB);
    u16* cwq = (u16*)(w8 + 51 * MB);
    u16* cwk = (u16*)(w8 + 54 * MB);
    u16* cwv = (u16*)(w8 + 57 * MB);
    u16* cwo = (u16*)(w8 + 60 * MB);
    u16* w1  = (u16*)(w8 + 63 * MB);                // 12 MB
    u16* w2  = (u16*)(w8 + 75 * MB);                // 12 MB
    u16* wpi = (u16*)(w8 + 87 * MB);                // 256 KB
    u16* wpo = (u16*)(w8 + 87 * MB + 262144);       // 256 KB
    float* pp  = (float*)(w8 + 88 * MB);            // split-K partials 4x4MB
    u16*  Pg  = (u16*)(w8 + 104 * MB);              // P [B*H,512,512] bf16 16 MB

    const dim3 T256(256);
    const dim3 LN_B(64, 4);
    const long long ZVT = (long long)HH * HD * LQQ; // 262144
    const long long ZWT = (long long)HH * HD * LCC; // 65536
    const long long ZP  = (long long)M * DD;        // partial stride 1048576
    const long long WST = (long long)DD * DD;       // 262144

    // ---- one fused bf16 conversion dispatch (8 floats/thread) ----
    {
        const int NW8 = NLAYER * DD * DD / 8;
        const int NF8 = NLAYER * DFFN * DD / 8;
        CvtArgs a;
        const float* srcs[NSEG] = { sa_qw, sa_kw, sa_vw, sa_ow, ca_qw, ca_kw, ca_vw, ca_ow,
                                    f1w, f2w, pinw, poutw, x_t, cond };
        u16* dsts[NSEG] = { wq, wk, wv, wo, cwq, cwk, cwv, cwo,
                            w1, w2, wpi, wpo, xtb, cdb };
        const int n8s[NSEG] = { NW8, NW8, NW8, NW8, NW8, NW8, NW8, NW8,
                                NF8, NF8, DD * LATD / 8, LATD * DD / 8,
                                M * LATD / 8, BB * LCC * DD / 8 };
        int acc = 0;
        for (int i = 0; i < NSEG; i++) {
            a.src[i] = srcs[i]; a.dst[i] = dsts[i]; a.n8[i] = n8s[i];
            a.beg[i] = acc; acc += (n8s[i] + 255) / 256;
        }
        a.beg[NSEG] = acc;
        k_cvtm<<<acc, T256, 0, stream>>>(a);
    }

    // ---- time embedding path ----
    k_emb<<<(BB * DD + 255) / 256, 256, 0, stream>>>(tarr, emb);
    k_wlin<<<(BB * DFFN) / 4, T256, 0, stream>>>(emb, DD, tm1w, tm1b, h1t, DFFN, 2);
    k_wlin<<<(BB * DD) / 4,   T256, 0, stream>>>(h1t, DFFN, tm2w, tm2b, te, DD, 0);
    k_wlin<<<(BB * DD) / 4,   T256, 0, stream>>>(te, DD, ttw, ttb, ttv, DD, 0);

    // ---- all-layer cross K: kbc6[L] = cond @ ckw[L]^T (z = layer) ----
    k_g128b<false, 0><<<dim3(DD / 128, (BB * LCC) / 128, NLAYER), T256, 0, stream>>>(
        cdb, 0, DD, cwk, WST, DD, kbc6, (long long)BB * LCC * DD, DD, DD, 0, 0);
    // ---- all-layer cross V (transposed): vcT6[L] ----
    k_g128b<true, 7><<<dim3(DD / 128, (BB * LCC) / 128, NLAYER), T256, 0, stream>>>(
        cdb, 0, DD, cwv, WST, DD, vcT6, (long long)BB * HH * HD * LCC, DD, DD,
        ZWT, LCC);

    // ---- input projection: h = x_t @ pinw.T + pinb + ttv[b] ----
    k_g128<float, false><<<dim3(DD / 128, M / 128, 1), T256, 0, stream>>>(
        xtb, LATD, wpi, LATD, h, DD, LATD, pinb, ttv, DD, 9, 0, 0);

    for (int L = 0; L < NLAYER; L++) {
        const size_t LW = (size_t)L * DD * DD;

        // ======== self-attention with QGFD ========
        if (L == 0)
            k_ln<<<M / 4, LN_B, 0, stream>>>(h, xn,
                n1g + (size_t)L * DD, n1b + (size_t)L * DD);
        else
            k_ln2<4><<<M / 4, LN_B, 0, stream>>>(h, pp, ZP,
                f2b + (size_t)(L - 1) * DD, xn,
                n1g + (size_t)L * DD, n1b + (size_t)L * DD);

        // fused QKV (z: 0=q, 1=k, 2=v transposed)
        k_g128q<<<dim3(DD / 128, M / 128, 3), T256, 0, stream>>>(
            xn, DD, wq + LW, wk + LW, wv + LW, DD,
            qb, kb, vbT, DD, DD, ZVT, LQQ);

        // pass A: S+softmax, u=P@v, wT=(0.5u+0.5v)^T, P -> HBM
        k_attn1<<<dim3(1, LQQ / 64, BB * HH), T256, 0, stream>>>(
            qb, kb, vbT, ubT, Pg, 0.125f);

        // pass B: ob = P @ wT (no recompute)
        k_pw<<<dim3(1, LQQ / 64, BB * HH), T256, 0, stream>>>(Pg, ubT, ob);

        // ob @ ow.T -> split-K=4 partials (K=128/chunk, 256 blocks = 1/CU)
        k_g128<float, true><<<dim3(DD / 128, M / 128, 4), T256, 0, stream>>>(
            ob, DD, wo + LW, DD, pp, DD, 128, nullptr, nullptr, 0, 0, 0, ZP);

        // n2 LN + reduce wo partials + sa_ob bias
        k_ln2<4><<<M / 4, LN_B, 0, stream>>>(h, pp, ZP,
            sa_ob + (size_t)L * DD, xn,
            n2g + (size_t)L * DD, n2b + (size_t)L * DD);

        // ======== cross-attention (Q projection fused) ========
        k_attn0<<<dim3(1, LQQ / 64, BB * HH), T256, 0, stream>>>(
            xn, cwq + LW,
            kbc6 + (size_t)L * BB * LCC * DD, vcT6 + (size_t)L * BB * HH * HD * LCC,
            ob, cmask, 0.125f);

        // ob @ cow.T -> split-K=4 partials
        k_g128<float, true><<<dim3(DD / 128, M / 128, 4), T256, 0, stream>>>(
            ob, DD, cwo + LW, DD, pp, DD, 128, nullptr, nullptr, 0, 0, 0, ZP);

        // n3 LN + reduce cwo partials + ca_ob bias
        k_ln2<4><<<M / 4, LN_B, 0, stream>>>(h, pp, ZP,
            ca_ob + (size_t)L * DD, xn,
            n3g + (size_t)L * DD, n3b + (size_t)L * DD);

        // ======== FFN ========
        k_g128<u16, false><<<dim3(DFFN / 128, M / 128, 1), T256, 0, stream>>>(
            xn, DD, w1 + (size_t)L * DFFN * DD, DD,
            a1, DFFN, DD, f1b + (size_t)L * DFFN, nullptr, 0, 0, /*act=*/1, 0);

        // w2: split-K=4 partials (K=512/chunk, 256 blocks = 1/CU)
        k_g128<float, true><<<dim3(DD / 128, M / 128, 4), T256, 0, stream>>>(
            a1, DFFN, w2 + (size_t)L * DD * DFFN, DFFN, pp, DD, 512,
            nullptr, nullptr, 0, 0, 0, ZP);
    }

    // ---- final LN (+ last layer w2 partial reduce, NP=4) + output proj ----
    k_ln2<4><<<M / 4, LN_B, 0, stream>>>(h, pp, ZP,
        f2b + (size_t)(NLAYER - 1) * DD, xn, fng, fnb);
    k_g<32, 32, float, false><<<dim3(LATD / 32, M / 32, 1), T256, 0, stream>>>(
        xn, 0, 0, DD, wpo, nullptr, nullptr, 0, 0, DD,
        (float*)d_out, nullptr, nullptr, 0, 0, LATD,
        DD, 1, 1.0f, poutb, nullptr, 0, 0, 0.0f, nullptr, 0, 0, 0, 0, 0, 0, 0);
}

// Round 11
// 1143.232 us; speedup vs baseline: 1.5540x; 1.0037x over previous
//
#include <hip/hip_runtime.h>
#include <hip/hip_bf16.h>
#include <type_traits>

#define DD    512
#define HH    8
#define HD    64
#define NLAYER 6
#define DFFN  2048
#define LATD  256
#define BB    4
#define LQQ   512
#define LCC   128

typedef unsigned short u16;
typedef __attribute__((ext_vector_type(8))) short bf16x8;
typedef __attribute__((ext_vector_type(4))) float f32x4;
typedef __attribute__((ext_vector_type(4))) unsigned short u16x4;

__device__ __forceinline__ u16 f2bf(float f) {
    __hip_bfloat16 h = __float2bfloat16(f);
    return __builtin_bit_cast(u16, h);
}
__device__ __forceinline__ float bf2f(u16 u) {
    return __uint_as_float(((unsigned int)u) << 16);
}

// ---------------------------------------------------------------------------
// Legacy 32/64-tile MFMA GEMM (kept only for the small final projection).
// ---------------------------------------------------------------------------
template<int BM, int BN, typename TC, bool MULTI>
__global__ __launch_bounds__(256)
void k_g(const u16* __restrict__ A, long long sAb, long long sAh, int lda,
         const u16* __restrict__ B1, const u16* __restrict__ B2_, const u16* __restrict__ B3_,
         long long sBb, long long sBh, int ldb,
         TC* __restrict__ C1, TC* __restrict__ C2_, TC* __restrict__ C3_,
         long long sCb, long long sCh, int ldc,
         int K, int Hdim, float alpha,
         const float* __restrict__ bias,
         const float* __restrict__ res, int ldres, int res_shift,
         float beta2, const u16* __restrict__ add2, long long s2b, long long s2h,
         int act, int wt_mask, int wt_shift, long long sbT, int ldct)
{
    constexpr int SK = 72;
    constexpr int FM = BM / 32, FN = BN / 32;
    constexpr int PA = BM / 32, PB = BN / 32;

    const int z = blockIdx.z;
    const u16* Bm;
    TC* C;
    int wt;
    if constexpr (MULTI) {
        Bm = (z == 0) ? B1 : ((z == 1) ? B2_ : B3_);
        C  = (z == 0) ? C1 : ((z == 1) ? C2_ : C3_);
        wt = (wt_mask >> z) & 1;
    } else {
        const int zb = z / Hdim, zh = z % Hdim;
        A += (size_t)(zb * sAb + zh * sAh);
        Bm = B1 + (size_t)(zb * sBb + zh * sBh);
        C  = C1 + (size_t)(zb * sCb + zh * sCh);
        if (add2) add2 += (size_t)(zb * s2b + zh * s2h);
        wt = wt_mask & 1;
    }

    __shared__ u16 Asm[2][BM * SK];
    __shared__ u16 Bsm[2][BN * SK];

    const int t    = threadIdx.x;
    const int wid  = t >> 6, lane = t & 63;
    const int q    = lane >> 4, c = lane & 15;
    const int wm   = (wid >> 1) * (BM / 2), wn = (wid & 1) * (BN / 2);
    const int m0   = blockIdx.y * BM, n0 = blockIdx.x * BN;

    f32x4 acc[FM][FN];
    #pragma unroll
    for (int i = 0; i < FM; i++)
        #pragma unroll
        for (int j = 0; j < FN; j++) acc[i][j] = (f32x4){0.f, 0.f, 0.f, 0.f};

    uint4 ra[2][PA], rb[2][PB];
    const int NI = K >> 6;

    auto loadg = [&](int slot, int kt) {
        #pragma unroll
        for (int p = 0; p < PA; p++) {
            const int idx = p * 256 + t, r = idx >> 3, kg = (idx & 7) << 3;
            ra[slot][p] = *(const uint4*)(A + (size_t)(m0 + r) * lda + kt + kg);
        }
        #pragma unroll
        for (int p = 0; p < PB; p++) {
            const int idx = p * 256 + t, r = idx >> 3, kg = (idx & 7) << 3;
            rb[slot][p] = *(const uint4*)(Bm + (size_t)(n0 + r) * ldb + kt + kg);
        }
    };
    auto store = [&](int buf, int slot) {
        #pragma unroll
        for (int p = 0; p < PA; p++) {
            const int idx = p * 256 + t, r = idx >> 3, kg = (idx & 7) << 3;
            *(uint4*)&Asm[buf][r * SK + kg] = ra[slot][p];
        }
        #pragma unroll
        for (int p = 0; p < PB; p++) {
            const int idx = p * 256 + t, r = idx >> 3, kg = (idx & 7) << 3;
            *(uint4*)&Bsm[buf][r * SK + kg] = rb[slot][p];
        }
    };

    loadg(0, 0);
    if (NI > 1) loadg(1, 64);
    store(0, 0);

    for (int it = 0; it < NI; it++) {
        __syncthreads();
        const int cur = it & 1, nxt = cur ^ 1;
        if (it + 1 < NI) store(nxt, nxt);
        if (it + 2 < NI) loadg(cur, (it + 2) << 6);
        #pragma unroll
        for (int s = 0; s < 2; s++) {
            bf16x8 af[FM], bfv[FN];
            #pragma unroll
            for (int fm = 0; fm < FM; fm++)
                af[fm] = *(const bf16x8*)&Asm[cur][(wm + fm * 16 + c) * SK + s * 32 + q * 8];
            #pragma unroll
            for (int fn = 0; fn < FN; fn++)
                bfv[fn] = *(const bf16x8*)&Bsm[cur][(wn + fn * 16 + c) * SK + s * 32 + q * 8];
            #pragma unroll
            for (int fm = 0; fm < FM; fm++)
                #pragma unroll
                for (int fn = 0; fn < FN; fn++)
                    acc[fm][fn] = __builtin_amdgcn_mfma_f32_16x16x32_bf16(
                        af[fm], bfv[fn], acc[fm][fn], 0, 0, 0);
        }
    }

    if (wt) {
        if constexpr (std::is_same<TC, u16>::value) {
            #pragma unroll
            for (int fm = 0; fm < FM; fm++) {
                const int gm0 = m0 + wm + fm * 16 + q * 4;
                const long long roff =
                    (long long)(gm0 >> wt_shift) * sbT + (gm0 & ((1 << wt_shift) - 1));
                #pragma unroll
                for (int fn = 0; fn < FN; fn++) {
                    const int gn = n0 + wn + fn * 16 + c;
                    const long long a0 = (long long)gn * ldct + roff;
                    u16x4 o;
                    if (add2) {
                        const u16x4 av = *(const u16x4*)&add2[a0];
                        #pragma unroll
                        for (int r = 0; r < 4; r++)
                            o[r] = f2bf(alpha * acc[fm][fn][r] + beta2 * bf2f(av[r]));
                    } else {
                        #pragma unroll
                        for (int r = 0; r < 4; r++)
                            o[r] = f2bf(alpha * acc[fm][fn][r]);
                    }
                    *(u16x4*)&C[a0] = o;
                }
            }
        }
    } else {
        #pragma unroll
        for (int fm = 0; fm < FM; fm++) {
            #pragma unroll
            for (int reg = 0; reg < 4; reg++) {
                const int gm = m0 + wm + fm * 16 + q * 4 + reg;
                #pragma unroll
                for (int fn = 0; fn < FN; fn++) {
                    const int gn = n0 + wn + fn * 16 + c;
                    float v = alpha * acc[fm][fn][reg];
                    if (bias) v += bias[gn];
                    if (act == 1) v = 0.5f * v * (1.0f + erff(v * 0.7071067811865475f));
                    if (res)  v += res[(size_t)(gm >> res_shift) * ldres + gn];
                    if constexpr (std::is_same<TC, u16>::value)
                        C[(size_t)gm * ldc + gn] = f2bf(v);
                    else
                        C[(size_t)gm * ldc + gn] = v;
                }
            }
        }
    }
}

// ---------------------------------------------------------------------------
// Shared 128x128-tile MFMA core (m97 structure).
// ---------------------------------------------------------------------------
#define G128_CORE(Aptr, LDA, Bptr, LDB, KZ, NIV)                               \
    {                                                                          \
        for (int it = 0; it < (NIV); it++) {                                   \
            const int kt = (KZ) + (it << 6);                                   \
            _Pragma("unroll")                                                  \
            for (int j = 0; j < 4; j++) {                                      \
                const int r  = wid * 32 + j * 8 + lr;                          \
                const int kb = lkb ^ (r & 7);                                  \
                const u16* ga = (Aptr) + (size_t)(m0 + r) * (LDA) + kt + kb * 8;\
                const u16* gb = (Bptr) + (size_t)(n0 + r) * (LDB) + kt + kb * 8;\
                u16* la = &As[(wid * 32 + j * 8) * 64];                        \
                u16* lb = &Bs[(wid * 32 + j * 8) * 64];                        \
                __builtin_amdgcn_global_load_lds(                              \
                    (const __attribute__((address_space(1))) void*)ga,         \
                    (__attribute__((address_space(3))) void*)la, 16, 0, 0);    \
                __builtin_amdgcn_global_load_lds(                              \
                    (const __attribute__((address_space(1))) void*)gb,         \
                    (__attribute__((address_space(3))) void*)lb, 16, 0, 0);    \
            }                                                                  \
            __syncthreads();                                                   \
            _Pragma("unroll")                                                  \
            for (int s = 0; s < 2; s++) {                                      \
                bf16x8 af[4], bfv[4];                                          \
                _Pragma("unroll")                                              \
                for (int fm = 0; fm < 4; fm++) {                               \
                    const int row = wr * 64 + fm * 16 + c;                     \
                    const int blk = (s * 4 + q) ^ (row & 7);                   \
                    af[fm] = *(const bf16x8*)&As[row * 64 + blk * 8];          \
                }                                                              \
                _Pragma("unroll")                                              \
                for (int fn = 0; fn < 4; fn++) {                               \
                    const int row = wc * 64 + fn * 16 + c;                     \
                    const int blk = (s * 4 + q) ^ (row & 7);                   \
                    bfv[fn] = *(const bf16x8*)&Bs[row * 64 + blk * 8];         \
                }                                                              \
                _Pragma("unroll")                                              \
                for (int fm = 0; fm < 4; fm++)                                 \
                    _Pragma("unroll")                                          \
                    for (int fn = 0; fn < 4; fn++)                             \
                        acc[fm][fn] = __builtin_amdgcn_mfma_f32_16x16x32_bf16( \
                            af[fm], bfv[fn], acc[fm][fn], 0, 0, 0);            \
            }                                                                  \
            __syncthreads();                                                   \
        }                                                                      \
    }

#define G128_PROLOG                                                            \
    __shared__ u16 As[128 * 64];                                               \
    __shared__ u16 Bs[128 * 64];                                               \
    const int t = threadIdx.x, wid = t >> 6, lane = t & 63;                    \
    const int q = lane >> 4, c = lane & 15;                                    \
    const int wr = wid >> 1, wc = wid & 1;                                     \
    const int m0 = blockIdx.y * 128, n0 = blockIdx.x * 128;                    \
    const int lr  = lane >> 3;                                                 \
    const int lkb = lane & 7;                                                  \
    f32x4 acc[4][4];                                                           \
    _Pragma("unroll")                                                          \
    for (int i = 0; i < 4; i++)                                                \
        _Pragma("unroll")                                                      \
        for (int j = 0; j < 4; j++) acc[i][j] = (f32x4){0.f, 0.f, 0.f, 0.f};

// ---------------------------------------------------------------------------
// General 128x128 GEMM. PART: raw fp32 partial stores into C+z*zstr (split-K).
// ---------------------------------------------------------------------------
template<typename TC, bool PART>
__global__ __launch_bounds__(256)
void k_g128(const u16* __restrict__ A, int lda,
            const u16* __restrict__ B, int ldb,
            TC* __restrict__ C, int ldc, int K,
            const float* __restrict__ bias,
            const float* __restrict__ res, int ldres, int rshift, int act,
            long long zstr)
{
    G128_PROLOG
    const int kz = blockIdx.z * K;
    const int NI = K >> 6;
    G128_CORE(A, lda, B, ldb, kz, NI)

    #pragma unroll
    for (int fm = 0; fm < 4; fm++) {
        #pragma unroll
        for (int reg = 0; reg < 4; reg++) {
            const int gm = m0 + wr * 64 + fm * 16 + q * 4 + reg;
            #pragma unroll
            for (int fn = 0; fn < 4; fn++) {
                const int gn = n0 + wc * 64 + fn * 16 + c;
                float v = acc[fm][fn][reg];
                if constexpr (PART) {
                    ((float*)C)[(size_t)blockIdx.z * zstr + (size_t)gm * ldc + gn] = v;
                } else {
                    if (bias) v += bias[gn];
                    if (act == 1) v = 0.5f * v * (1.0f + erff(v * 0.7071067811865475f));
                    if (res)  v += res[(size_t)(gm >> rshift) * ldres + gn];
                    if constexpr (std::is_same<TC, u16>::value)
                        C[(size_t)gm * ldc + gn] = f2bf(v);
                    else
                        C[(size_t)gm * ldc + gn] = v;
                }
            }
        }
    }
}

// ---------------------------------------------------------------------------
// QKV triple 128x128 GEMM: z selects (B,C); z==2 writes V transposed.
// ---------------------------------------------------------------------------
__global__ __launch_bounds__(256)
void k_g128q(const u16* __restrict__ A, int lda,
             const u16* __restrict__ B1, const u16* __restrict__ B2,
             const u16* __restrict__ B3, int ldb,
             u16* __restrict__ C1, u16* __restrict__ C2, u16* __restrict__ C3,
             int ldc, int K, long long sbT, int ldct)
{
    const int z = blockIdx.z;
    const u16* B = (z == 0) ? B1 : ((z == 1) ? B2 : B3);
    u16* C = (z == 0) ? C1 : ((z == 1) ? C2 : C3);

    G128_PROLOG
    const int NI = K >> 6;
    G128_CORE(A, lda, B, ldb, 0, NI)

    if (z == 2) {
        #pragma unroll
        for (int fm = 0; fm < 4; fm++) {
            const int gm0 = m0 + wr * 64 + fm * 16 + q * 4;
            const long long roff = (long long)(gm0 >> 9) * sbT + (gm0 & 511);
            #pragma unroll
            for (int fn = 0; fn < 4; fn++) {
                const int gn = n0 + wc * 64 + fn * 16 + c;
                const long long a0 = (long long)gn * ldct + roff;
                u16x4 o;
                #pragma unroll
                for (int r = 0; r < 4; r++) o[r] = f2bf(acc[fm][fn][r]);
                *(u16x4*)&C[a0] = o;
            }
        }
    } else {
        #pragma unroll
        for (int fm = 0; fm < 4; fm++)
            #pragma unroll
            for (int reg = 0; reg < 4; reg++) {
                const int gm = m0 + wr * 64 + fm * 16 + q * 4 + reg;
                #pragma unroll
                for (int fn = 0; fn < 4; fn++) {
                    const int gn = n0 + wc * 64 + fn * 16 + c;
                    C[(size_t)gm * ldc + gn] = f2bf(acc[fm][fn][reg]);
                }
            }
    }
}

// ---------------------------------------------------------------------------
// z-batched 128x128 GEMM (per-layer cross K/V precompute).
// ---------------------------------------------------------------------------
template<bool WT, int SH>
__global__ __launch_bounds__(256)
void k_g128b(const u16* __restrict__ A, long long sAz, int lda,
             const u16* __restrict__ B, long long sBz, int ldb,
             u16* __restrict__ C, long long sCz, int ldc, int K,
             long long sbT, int ldct)
{
    const int z = blockIdx.z;
    A += (size_t)z * sAz;
    B += (size_t)z * sBz;
    C += (size_t)z * sCz;

    G128_PROLOG
    const int NI = K >> 6;
    G128_CORE(A, lda, B, ldb, 0, NI)

    if constexpr (WT) {
        #pragma unroll
        for (int fm = 0; fm < 4; fm++) {
            const int gm0 = m0 + wr * 64 + fm * 16 + q * 4;
            const long long roff =
                (long long)(gm0 >> SH) * sbT + (gm0 & ((1 << SH) - 1));
            #pragma unroll
            for (int fn = 0; fn < 4; fn++) {
                const int gn = n0 + wc * 64 + fn * 16 + c;
                const long long a0 = (long long)gn * ldct + roff;
                u16x4 o;
                #pragma unroll
                for (int r = 0; r < 4; r++) o[r] = f2bf(acc[fm][fn][r]);
                *(u16x4*)&C[a0] = o;
            }
        }
    } else {
        #pragma unroll
        for (int fm = 0; fm < 4; fm++)
            #pragma unroll
            for (int reg = 0; reg < 4; reg++) {
                const int gm = m0 + wr * 64 + fm * 16 + q * 4 + reg;
                #pragma unroll
                for (int fn = 0; fn < 4; fn++) {
                    const int gn = n0 + wc * 64 + fn * 16 + c;
                    C[(size_t)gm * ldc + gn] = f2bf(acc[fm][fn][reg]);
                }
            }
    }
}

// ---------------------------------------------------------------------------
// Self-attention pass A: S=q@k^T, softmax -> P; u=P@v;
// wT=(0.5u+0.5v)^T; ALSO writes P (bf16, bit-identical) via a coalesced
// LDS->HBM copy of the Ps image, so pass B (k_pw) can skip the recompute.
// ---------------------------------------------------------------------------
__global__ __launch_bounds__(256)
void k_attn1(const u16* __restrict__ qb, const u16* __restrict__ kb,
             const u16* __restrict__ vT, u16* __restrict__ wT,
             u16* __restrict__ Pg, float alpha)
{
    constexpr int NCT = 4;
    constexpr int NJ  = 32;
    constexpr int SM1 = 64 * 72 * 2 + 2 * 128 * 72 * 2;  // 46080
    constexpr int SM2 = 2 * 64 * 136 * 2;                // 34816
    constexpr int SMEM = SM1 > SM2 ? SM1 : SM2;
    __shared__ char smem[SMEM];
    u16* Qs = (u16*)smem;
    u16* Ks = (u16*)(smem + 64 * 72 * 2);
    u16* Ps = (u16*)smem;
    u16* Vs = (u16*)(smem + 64 * 136 * 2);

    const int z = blockIdx.z, b = z >> 3, hh = z & 7;
    const int m0 = blockIdx.y * 64;
    const int t = threadIdx.x, w = t >> 6, lane = t & 63;
    const int q = lane >> 4, c = lane & 15;

    const u16* qbase = qb + ((size_t)(b * LQQ + m0)) * DD + hh * HD;
    const u16* kbase = kb + ((size_t)b * LQQ) * DD + hh * HD;
    const u16* vbase = vT + (size_t)z * HD * LQQ;

    // ---- stage Q (64 x 64) ----
    #pragma unroll
    for (int p = 0; p < 2; p++) {
        const int idx = p * 256 + t, r = idx >> 3, kg = (idx & 7) << 3;
        *(uint4*)&Qs[r * 72 + kg] = *(const uint4*)(qbase + (size_t)r * DD + kg);
    }

    f32x4 acc[NJ];
    #pragma unroll
    for (int j = 0; j < NJ; j++) acc[j] = (f32x4){0.f, 0.f, 0.f, 0.f};

    auto stageK = [&](u16* dst, int ct) {
        #pragma unroll
        for (int p = 0; p < 4; p++) {
            const int idx = p * 256 + t, r = idx >> 3, kg = (idx & 7) << 3;
            *(uint4*)&dst[r * 72 + kg] =
                *(const uint4*)(kbase + (size_t)(ct * 128 + r) * DD + kg);
        }
    };

    stageK(Ks, 0);
    __syncthreads();
    #pragma unroll
    for (int ct = 0; ct < NCT; ct++) {
        u16* cur = Ks + (ct & 1) * (128 * 72);
        if (ct + 1 < NCT) stageK(Ks + ((ct + 1) & 1) * (128 * 72), ct + 1);
        #pragma unroll
        for (int s = 0; s < 2; s++) {
            const bf16x8 af = *(const bf16x8*)&Qs[(w * 16 + c) * 72 + s * 32 + q * 8];
            #pragma unroll
            for (int fn = 0; fn < 8; fn++) {
                const bf16x8 bv = *(const bf16x8*)&cur[(fn * 16 + c) * 72 + s * 32 + q * 8];
                acc[ct * 8 + fn] = __builtin_amdgcn_mfma_f32_16x16x32_bf16(
                    af, bv, acc[ct * 8 + fn], 0, 0, 0);
            }
        }
        if (ct + 1 < NCT) __syncthreads();
    }

    // ---- row softmax ----
    float mx[4] = {-3.402823466e38f, -3.402823466e38f, -3.402823466e38f, -3.402823466e38f};
    #pragma unroll
    for (int j = 0; j < NJ; j++)
        #pragma unroll
        for (int r = 0; r < 4; r++) {
            const float x = alpha * acc[j][r];
            acc[j][r] = x;
            mx[r] = fmaxf(mx[r], x);
        }
    #pragma unroll
    for (int r = 0; r < 4; r++)
        #pragma unroll
        for (int m = 8; m; m >>= 1) mx[r] = fmaxf(mx[r], __shfl_xor(mx[r], m, 64));
    float sum[4] = {0.f, 0.f, 0.f, 0.f};
    #pragma unroll
    for (int j = 0; j < NJ; j++)
        #pragma unroll
        for (int r = 0; r < 4; r++) {
            const float e = expf(acc[j][r] - mx[r]);
            acc[j][r] = e;
            sum[r] += e;
        }
    #pragma unroll
    for (int r = 0; r < 4; r++)
        #pragma unroll
        for (int m = 8; m; m >>= 1) sum[r] += __shfl_xor(sum[r], m, 64);
    #pragma unroll
    for (int r = 0; r < 4; r++) sum[r] = 1.0f / sum[r];
    #pragma unroll
    for (int j = 0; j < NJ; j++)
        #pragma unroll
        for (int r = 0; r < 4; r++) acc[j][r] *= sum[r];

    // ---- phase 2: u = P @ v (P -> HBM via coalesced LDS copy) ----
    f32x4 ua[4];
    #pragma unroll
    for (int fn = 0; fn < 4; fn++) ua[fn] = (f32x4){0.f, 0.f, 0.f, 0.f};

    __syncthreads();   // Qs/Ks -> Ps/Vs alias
    #pragma unroll
    for (int ct = 0; ct < NCT; ct++) {
        #pragma unroll
        for (int j = 0; j < 8; j++)
            #pragma unroll
            for (int r = 0; r < 4; r++)
                Ps[(w * 16 + q * 4 + r) * 136 + j * 16 + c] = f2bf(acc[ct * 8 + j][r]);
        #pragma unroll
        for (int p = 0; p < 4; p++) {
            const int idx = p * 256 + t, rr = idx >> 4, kg = (idx & 15) << 3;
            *(uint4*)&Vs[rr * 136 + kg] =
                *(const uint4*)(vbase + (size_t)rr * LQQ + ct * 128 + kg);
        }
        __syncthreads();
        // coalesced P writeback (reads the Ps image just written; bit-identical)
        #pragma unroll
        for (int p = 0; p < 4; p++) {
            const int idx = p * 256 + t, rr = idx >> 4, kg = (idx & 15) << 3;
            *(uint4*)&Pg[((size_t)z * LQQ + m0 + rr) * LQQ + ct * 128 + kg] =
                *(const uint4*)&Ps[rr * 136 + kg];
        }
        #pragma unroll
        for (int ks = 0; ks < 4; ks++) {
            const bf16x8 af = *(const bf16x8*)&Ps[(w * 16 + c) * 136 + ks * 32 + q * 8];
            #pragma unroll
            for (int fn = 0; fn < 4; fn++) {
                const bf16x8 bv = *(const bf16x8*)&Vs[(fn * 16 + c) * 136 + ks * 32 + q * 8];
                ua[fn] = __builtin_amdgcn_mfma_f32_16x16x32_bf16(af, bv, ua[fn], 0, 0, 0);
            }
        }
        if (ct + 1 < NCT) __syncthreads();
    }

    // wT = (0.5*u + 0.5*v)^T
    #pragma unroll
    for (int fn = 0; fn < 4; fn++) {
        const int col = fn * 16 + c;
        const size_t a0 = ((size_t)z * HD + col) * LQQ + m0 + w * 16 + q * 4;
        const u16x4 vv = *(const u16x4*)&vT[a0];
        u16x4 o;
        #pragma unroll
        for (int r = 0; r < 4; r++)
            o[r] = f2bf(0.5f * ua[fn][r] + 0.5f * bf2f(vv[r]));
        *(u16x4*)&wT[a0] = o;
    }
}

// ---------------------------------------------------------------------------
// Self-attention pass B: ob = P @ wT (P from HBM, no recompute).
// Output written via LDS bounce -> fully coalesced uint4 stores.
// ---------------------------------------------------------------------------
__global__ __launch_bounds__(256)
void k_pw(const u16* __restrict__ Pg, const u16* __restrict__ wT,
          u16* __restrict__ uout)
{
    __shared__ u16 smem[2 * 64 * 136];
    u16* Ps = smem;
    u16* Vs = smem + 64 * 136;

    const int z = blockIdx.z, b = z >> 3, hh = z & 7;
    const int m0 = blockIdx.y * 64;
    const int t = threadIdx.x, w = t >> 6, lane = t & 63;
    const int q = lane >> 4, c = lane & 15;

    const u16* pbase = Pg + ((size_t)z * LQQ + m0) * LQQ;
    const u16* vbase = wT + (size_t)z * HD * LQQ;

    f32x4 ua[4];
    #pragma unroll
    for (int fn = 0; fn < 4; fn++) ua[fn] = (f32x4){0.f, 0.f, 0.f, 0.f};

    #pragma unroll
    for (int ct = 0; ct < 4; ct++) {
        #pragma unroll
        for (int p = 0; p < 4; p++) {
            const int idx = p * 256 + t, rr = idx >> 4, kg = (idx & 15) << 3;
            *(uint4*)&Ps[rr * 136 + kg] =
                *(const uint4*)(pbase + (size_t)rr * LQQ + ct * 128 + kg);
            *(uint4*)&Vs[rr * 136 + kg] =
                *(const uint4*)(vbase + (size_t)rr * LQQ + ct * 128 + kg);
        }
        __syncthreads();
        #pragma unroll
        for (int ks = 0; ks < 4; ks++) {
            const bf16x8 af = *(const bf16x8*)&Ps[(w * 16 + c) * 136 + ks * 32 + q * 8];
            #pragma unroll
            for (int fn = 0; fn < 4; fn++) {
                const bf16x8 bv = *(const bf16x8*)&Vs[(fn * 16 + c) * 136 + ks * 32 + q * 8];
                ua[fn] = __builtin_amdgcn_mfma_f32_16x16x32_bf16(af, bv, ua[fn], 0, 0, 0);
            }
        }
        __syncthreads();
    }

    // LDS bounce -> coalesced output (64 rows x 64 cols, stride 72)
    #pragma unroll
    for (int fn = 0; fn < 4; fn++)
        #pragma unroll
        for (int r = 0; r < 4; r++)
            Ps[(w * 16 + q * 4 + r) * 72 + fn * 16 + c] = f2bf(ua[fn][r]);
    __syncthreads();
    #pragma unroll
    for (int p = 0; p < 2; p++) {
        const int idx = p * 256 + t, rr = idx >> 3, kg = (idx & 7) << 3;
        *(uint4*)&uout[((size_t)b * LQQ + m0 + rr) * DD + hh * HD + kg] =
            *(const uint4*)&Ps[rr * 72 + kg];
    }
}

// ---------------------------------------------------------------------------
// Cross-attention with FUSED Q projection: q = xn[m0..64] @ cwq[h-slice]^T
// computed per block. Then S=q@k^T + mask + softmax, ob = P@vc. LK=128.
// Output via LDS bounce -> coalesced uint4 stores.
// ---------------------------------------------------------------------------
__global__ __launch_bounds__(256)
void k_attn0(const u16* __restrict__ xnp, const u16* __restrict__ wqp,
             const u16* __restrict__ kbp, const u16* __restrict__ vT,
             u16* __restrict__ uout, const float* __restrict__ mask,
             float alpha)
{
    constexpr int NJ = 8;
    constexpr int SMEM = 2 * 64 * 136 * 2;   // 34816 (covers 27648 phase-1)
    __shared__ char smem[SMEM];
    u16* Qs = (u16*)smem;
    u16* Ks = (u16*)(smem + 64 * 72 * 2);
    u16* Xs = Ks;                  // mini-GEMM staging (aliases Ks region)
    u16* Ws = Ks + 64 * 72;
    u16* Ps = (u16*)smem;
    u16* Vs = (u16*)(smem + 64 * 136 * 2);

    const int z = blockIdx.z, b = z >> 3, hh = z & 7;
    const int m0 = blockIdx.y * 64;
    const int t = threadIdx.x, w = t >> 6, lane = t & 63;
    const int q = lane >> 4, c = lane & 15;

    const u16* xbase = xnp + ((size_t)(b * LQQ + m0)) * DD;
    const u16* wbase = wqp + (size_t)(hh * HD) * DD;
    const u16* kbase = kbp + ((size_t)b * LCC) * DD + hh * HD;
    const u16* vbase = vT + (size_t)z * HD * LCC;

    // ---- fused Q projection: q[64x64] = xn-slice @ wq-slice^T (K=512) ----
    f32x4 qa[4];
    #pragma unroll
    for (int fn = 0; fn < 4; fn++) qa[fn] = (f32x4){0.f, 0.f, 0.f, 0.f};
    for (int kc = 0; kc < 8; kc++) {
        #pragma unroll
        for (int p = 0; p < 2; p++) {
            const int idx = p * 256 + t, r = idx >> 3, kg = (idx & 7) << 3;
            *(uint4*)&Xs[r * 72 + kg] =
                *(const uint4*)(xbase + (size_t)r * DD + kc * 64 + kg);
            *(uint4*)&Ws[r * 72 + kg] =
                *(const uint4*)(wbase + (size_t)r * DD + kc * 64 + kg);
        }
        __syncthreads();
        #pragma unroll
        for (int s = 0; s < 2; s++) {
            const bf16x8 af = *(const bf16x8*)&Xs[(w * 16 + c) * 72 + s * 32 + q * 8];
            #pragma unroll
            for (int fn = 0; fn < 4; fn++) {
                const bf16x8 bv = *(const bf16x8*)&Ws[(fn * 16 + c) * 72 + s * 32 + q * 8];
                qa[fn] = __builtin_amdgcn_mfma_f32_16x16x32_bf16(af, bv, qa[fn], 0, 0, 0);
            }
        }
        __syncthreads();
    }
    // write q to Qs (row = w*16+q*4+r, col = fn*16+c)
    #pragma unroll
    for (int fn = 0; fn < 4; fn++)
        #pragma unroll
        for (int r = 0; r < 4; r++)
            Qs[(w * 16 + q * 4 + r) * 72 + fn * 16 + c] = f2bf(qa[fn][r]);

    // ---- stage K (128 x 64) ----
    #pragma unroll
    for (int p = 0; p < 4; p++) {
        const int idx = p * 256 + t, r = idx >> 3, kg = (idx & 7) << 3;
        *(uint4*)&Ks[r * 72 + kg] = *(const uint4*)(kbase + (size_t)r * DD + kg);
    }
    __syncthreads();

    f32x4 acc[NJ];
    #pragma unroll
    for (int j = 0; j < NJ; j++) acc[j] = (f32x4){0.f, 0.f, 0.f, 0.f};

    #pragma unroll
    for (int s = 0; s < 2; s++) {
        const bf16x8 af = *(const bf16x8*)&Qs[(w * 16 + c) * 72 + s * 32 + q * 8];
        #pragma unroll
        for (int fn = 0; fn < 8; fn++) {
            const bf16x8 bv = *(const bf16x8*)&Ks[(fn * 16 + c) * 72 + s * 32 + q * 8];
            acc[fn] = __builtin_amdgcn_mfma_f32_16x16x32_bf16(af, bv, acc[fn], 0, 0, 0);
        }
    }

    // ---- row softmax with key mask ----
    bool msk[NJ];
    #pragma unroll
    for (int j = 0; j < NJ; j++)
        msk[j] = (mask[b * LCC + j * 16 + c] == 0.0f);
    float mx[4] = {-3.402823466e38f, -3.402823466e38f, -3.402823466e38f, -3.402823466e38f};
    #pragma unroll
    for (int j = 0; j < NJ; j++)
        #pragma unroll
        for (int r = 0; r < 4; r++) {
            float x = alpha * acc[j][r];
            if (msk[j]) x = -3.402823466e38f;
            acc[j][r] = x;
            mx[r] = fmaxf(mx[r], x);
        }
    #pragma unroll
    for (int r = 0; r < 4; r++)
        #pragma unroll
        for (int m = 8; m; m >>= 1) mx[r] = fmaxf(mx[r], __shfl_xor(mx[r], m, 64));
    float sum[4] = {0.f, 0.f, 0.f, 0.f};
    #pragma unroll
    for (int j = 0; j < NJ; j++)
        #pragma unroll
        for (int r = 0; r < 4; r++) {
            const float e = expf(acc[j][r] - mx[r]);
            acc[j][r] = e;
            sum[r] += e;
        }
    #pragma unroll
    for (int r = 0; r < 4; r++)
        #pragma unroll
        for (int m = 8; m; m >>= 1) sum[r] += __shfl_xor(sum[r], m, 64);
    #pragma unroll
    for (int r = 0; r < 4; r++) sum[r] = 1.0f / sum[r];
    #pragma unroll
    for (int j = 0; j < NJ; j++)
        #pragma unroll
        for (int r = 0; r < 4; r++) acc[j][r] *= sum[r];

    // ---- phase 2: ob = P @ vc ----
    f32x4 ua[4];
    #pragma unroll
    for (int fn = 0; fn < 4; fn++) ua[fn] = (f32x4){0.f, 0.f, 0.f, 0.f};

    __syncthreads();   // Qs/Ks -> Ps/Vs alias
    #pragma unroll
    for (int j = 0; j < 8; j++)
        #pragma unroll
        for (int r = 0; r < 4; r++)
            Ps[(w * 16 + q * 4 + r) * 136 + j * 16 + c] = f2bf(acc[j][r]);
    #pragma unroll
    for (int p = 0; p < 4; p++) {
        const int idx = p * 256 + t, rr = idx >> 4, kg = (idx & 15) << 3;
        *(uint4*)&Vs[rr * 136 + kg] =
            *(const uint4*)(vbase + (size_t)rr * LCC + kg);
    }
    __syncthreads();
    #pragma unroll
    for (int ks = 0; ks < 4; ks++) {
        const bf16x8 af = *(const bf16x8*)&Ps[(w * 16 + c) * 136 + ks * 32 + q * 8];
        #pragma unroll
        for (int fn = 0; fn < 4; fn++) {
            const bf16x8 bv = *(const bf16x8*)&Vs[(fn * 16 + c) * 136 + ks * 32 + q * 8];
            ua[fn] = __builtin_amdgcn_mfma_f32_16x16x32_bf16(af, bv, ua[fn], 0, 0, 0);
        }
    }

    // LDS bounce -> coalesced output (64 rows x 64 cols, stride 72)
    __syncthreads();
    #pragma unroll
    for (int fn = 0; fn < 4; fn++)
        #pragma unroll
        for (int r = 0; r < 4; r++)
            Ps[(w * 16 + q * 4 + r) * 72 + fn * 16 + c] = f2bf(ua[fn][r]);
    __syncthreads();
    #pragma unroll
    for (int p = 0; p < 2; p++) {
        const int idx = p * 256 + t, rr = idx >> 3, kg = (idx & 7) << 3;
        *(uint4*)&uout[((size_t)b * LQQ + m0 + rr) * DD + hh * HD + kg] =
            *(const uint4*)&Ps[rr * 72 + kg];
    }
}

// ---------------------------------------------------------------------------
// Fused fp32->bf16 conversion, 8 floats per thread (32B read / 16B write).
// ---------------------------------------------------------------------------
#define NSEG 14
struct CvtArgs {
    const float* src[NSEG];
    u16*         dst[NSEG];
    int          beg[NSEG + 1];
    int          n8[NSEG];
};

__global__ __launch_bounds__(256)
void k_cvtm(CvtArgs a)
{
    const int blk = blockIdx.x;
    int s = 0;
    #pragma unroll
    for (int i = 1; i < NSEG; i++) if (blk >= a.beg[i]) s = i;
    const int i8 = (blk - a.beg[s]) * 256 + threadIdx.x;
    if (i8 >= a.n8[s]) return;
    const float* sp = a.src[s] + (size_t)i8 * 8;
    const float4 v0 = *(const float4*)sp;
    const float4 v1 = *(const float4*)(sp + 4);
    uint4 u;
    u.x = (unsigned)f2bf(v0.x) | ((unsigned)f2bf(v0.y) << 16);
    u.y = (unsigned)f2bf(v0.z) | ((unsigned)f2bf(v0.w) << 16);
    u.z = (unsigned)f2bf(v1.x) | ((unsigned)f2bf(v1.y) << 16);
    u.w = (unsigned)f2bf(v1.z) | ((unsigned)f2bf(v1.w) << 16);
    *(uint4*)(a.dst[s] + (size_t)i8 * 8) = u;
}

// ---------------------------------------------------------------------------
__global__ __launch_bounds__(256)
void k_ln(const float* __restrict__ X, u16* __restrict__ Y,
          const float* __restrict__ g, const float* __restrict__ b)
{
    const int row  = blockIdx.x * 4 + threadIdx.y;
    const int lane = threadIdx.x;
    const float* x = X + (size_t)row * DD;
    float v[8];
    float s = 0.0f;
    #pragma unroll
    for (int i = 0; i < 8; i++) { v[i] = x[lane + i * 64]; s += v[i]; }
    #pragma unroll
    for (int off = 32; off; off >>= 1) s += __shfl_xor(s, off, 64);
    const float m = s * (1.0f / 512.0f);
    float qq = 0.0f;
    #pragma unroll
    for (int i = 0; i < 8; i++) { const float d = v[i] - m; qq += d * d; }
    #pragma unroll
    for (int off = 32; off; off >>= 1) qq += __shfl_xor(qq, off, 64);
    const float r = rsqrtf(qq * (1.0f / 512.0f) + 1e-5f);
    u16* y = Y + (size_t)row * DD;
    #pragma unroll
    for (int i = 0; i < 8; i++) {
        const int c = lane + i * 64;
        y[c] = f2bf((v[i] - m) * r * g[c] + b[c]);
    }
}

// ---------------------------------------------------------------------------
// Accumulating LayerNorm: h += sum(NP partials) + bias, then xn = LN(h).
// ---------------------------------------------------------------------------
template<int NP>
__global__ __launch_bounds__(256)
void k_ln2(float* __restrict__ H, const float* __restrict__ P, long long zstr,
           const float* __restrict__ bias, u16* __restrict__ Y,
           const float* __restrict__ g, const float* __restrict__ b)
{
    const int row  = blockIdx.x * 4 + threadIdx.y;
    const int lane = threadIdx.x;
    float* x = H + (size_t)row * DD;
    const float* pb = P + (size_t)row * DD;
    float v[8];
    float s = 0.0f;
    #pragma unroll
    for (int i = 0; i < 8; i++) {
        const int c = lane + i * 64;
        float t = x[c] + bias[c];
        #pragma unroll
        for (int p = 0; p < NP; p++) t += pb[(size_t)p * zstr + c];
        v[i] = t;
        s += t;
    }
    #pragma unroll
    for (int off = 32; off; off >>= 1) s += __shfl_xor(s, off, 64);
    const float m = s * (1.0f / 512.0f);
    float qq = 0.0f;
    #pragma unroll
    for (int i = 0; i < 8; i++) { const float d = v[i] - m; qq += d * d; }
    #pragma unroll
    for (int off = 32; off; off >>= 1) qq += __shfl_xor(qq, off, 64);
    const float r = rsqrtf(qq * (1.0f / 512.0f) + 1e-5f);
    u16* y = Y + (size_t)row * DD;
    #pragma unroll
    for (int i = 0; i < 8; i++) {
        const int c = lane + i * 64;
        x[c] = v[i];
        y[c] = f2bf((v[i] - m) * r * g[c] + b[c]);
    }
}

// ---------------------------------------------------------------------------
__global__ void k_emb(const int* __restrict__ t, float* __restrict__ emb)
{
    const int idx = blockIdx.x * 256 + threadIdx.x;
    if (idx >= BB * DD) return;
    const int b = idx / DD, c = idx % DD;
    const int j = (c < 256) ? c : (c - 256);
    const float freq = expf((float)j * (-9.210340371976184f / 255.0f));
    const float arg = (float)t[b] * freq;
    emb[idx] = (c < 256) ? sinf(arg) : cosf(arg);
}

__global__ __launch_bounds__(256)
void k_wlin(const float* __restrict__ in, int K,
            const float* __restrict__ W, const float* __restrict__ bias,
            float* __restrict__ out, int N, int act)
{
    const int gw   = blockIdx.x * 4 + (threadIdx.x >> 6);
    const int lane = threadIdx.x & 63;
    const int b = gw / N, n = gw % N;
    const float* x = in + (size_t)b * K;
    const float* w = W + (size_t)n * K;
    float s = 0.0f;
    for (int k = lane; k < K; k += 64) s += x[k] * w[k];
    #pragma unroll
    for (int off = 32; off; off >>= 1) s += __shfl_xor(s, off, 64);
    if (lane == 0) {
        s += bias[n];
        if (act == 2) s = s / (1.0f + expf(-s));
        out[gw] = s;
    }
}

// ---------------------------------------------------------------------------

extern "C" void kernel_launch(void* const* d_in, const int* in_sizes, int n_in,
                              void* d_out, int out_size, void* d_ws, size_t ws_size,
                              hipStream_t stream)
{
    const float* x_t   = (const float*)d_in[0];
    const int*   tarr  = (const int*)  d_in[1];
    const float* cond  = (const float*)d_in[2];
    const float* cmask = (const float*)d_in[3];
    const float* sa_qw = (const float*)d_in[4];
    const float* sa_kw = (const float*)d_in[5];
    const float* sa_vw = (const float*)d_in[6];
    const float* sa_ow = (const float*)d_in[7];
    const float* sa_ob = (const float*)d_in[8];
    const float* ca_qw = (const float*)d_in[9];
    const float* ca_kw = (const float*)d_in[10];
    const float* ca_vw = (const float*)d_in[11];
    const float* ca_ow = (const float*)d_in[12];
    const float* ca_ob = (const float*)d_in[13];
    const float* f1w   = (const float*)d_in[14];
    const float* f1b   = (const float*)d_in[15];
    const float* f2w   = (const float*)d_in[16];
    const float* f2b   = (const float*)d_in[17];
    const float* n1g   = (const float*)d_in[18];
    const float* n1b   = (const float*)d_in[19];
    const float* n2g   = (const float*)d_in[20];
    const float* n2b   = (const float*)d_in[21];
    const float* n3g   = (const float*)d_in[22];
    const float* n3b   = (const float*)d_in[23];
    const float* tm1w  = (const float*)d_in[24];
    const float* tm1b  = (const float*)d_in[25];
    const float* tm2w  = (const float*)d_in[26];
    const float* tm2b  = (const float*)d_in[27];
    const float* ttw   = (const float*)d_in[28];
    const float* ttb   = (const float*)d_in[29];
    const float* pinw  = (const float*)d_in[30];
    const float* pinb  = (const float*)d_in[31];
    const float* poutw = (const float*)d_in[32];
    const float* poutb = (const float*)d_in[33];
    const float* fng   = (const float*)d_in[34];
    const float* fnb   = (const float*)d_in[35];

    const int M = BB * LQQ; // 2048
    const size_t MB = 1048576;

    char* w8 = (char*)d_ws;
    float* h   = (float*)(w8);                      // [2048,512] fp32  4 MB
    u16*  xn  = (u16*)(w8 +  4 * MB);               // 2 MB
    u16*  qb  = (u16*)(w8 +  6 * MB);               // 2 MB
    u16*  kb  = (u16*)(w8 +  8 * MB);               // 2 MB (self K)
    u16*  vbT = (u16*)(w8 + 10 * MB);               // [B,H,64,512] 2 MB
    u16*  ubT = (u16*)(w8 + 12 * MB);               // [B,H,64,512] wT 2 MB
    u16*  ob  = (u16*)(w8 + 14 * MB);               // 2 MB
    u16*  a1  = (u16*)(w8 + 16 * MB);               // FFN hidden 8 MB
    u16*  xtb = (u16*)(w8 + 16 * MB);               // aliases a1 (dead before FFN)
    u16*  cdb = (u16*)(w8 + 17 * MB);               // aliases a1 (dead before FFN)
    u16*  kbc6 = (u16*)(w8 + 32 * MB);              // 6 x [B*LCC, DD] = 3 MB
    u16*  vcT6 = (u16*)(w8 + 35 * MB);              // 6 x [B,H,64,128] = 3 MB
    float* emb = (float*)(w8 + 38 * MB);
    float* h1t = emb + BB * DD;
    float* te  = h1t + BB * DFFN;
    float* ttv = te  + BB * DD;
    u16* wq  = (u16*)(w8 + 39 * MB);
    u16* wk  = (u16*)(w8 + 42 * MB);
    u16* wv  = (u16*)(w8 + 45 * MB);
    u16* wo  = (u16*)(w8 + 48 * MB);
    u16* cwq = (u16*)(w8 + 51 * MB);
    u16* cwk = (u16*)(w8 + 54 * MB);
    u16* cwv = (u16*)(w8 + 57 * MB);
    u16* cwo = (u16*)(w8 + 60 * MB);
    u16* w1  = (u16*)(w8 + 63 * MB);                // 12 MB
    u16* w2  = (u16*)(w8 + 75 * MB);                // 12 MB
    u16* wpi = (u16*)(w8 + 87 * MB);                // 256 KB
    u16* wpo = (u16*)(w8 + 87 * MB + 262144);       // 256 KB
    float* pp  = (float*)(w8 + 88 * MB);            // split-K partials 4x4MB
    u16*  Pg  = (u16*)(w8 + 104 * MB);              // P [B*H,512,512] bf16 16 MB

    const dim3 T256(256);
    const dim3 LN_B(64, 4);
    const long long ZVT = (long long)HH * HD * LQQ; // 262144
    const long long ZWT = (long long)HH * HD * LCC; // 65536
    const long long ZP  = (long long)M * DD;        // partial stride 1048576
    const long long WST = (long long)DD * DD;       // 262144

    // ---- one fused bf16 conversion dispatch (8 floats/thread) ----
    {
        const int NW8 = NLAYER * DD * DD / 8;
        const int NF8 = NLAYER * DFFN * DD / 8;
        CvtArgs a;
        const float* srcs[NSEG] = { sa_qw, sa_kw, sa_vw, sa_ow, ca_qw, ca_kw, ca_vw, ca_ow,
                                    f1w, f2w, pinw, poutw, x_t, cond };
        u16* dsts[NSEG] = { wq, wk, wv, wo, cwq, cwk, cwv, cwo,
                            w1, w2, wpi, wpo, xtb, cdb };
        const int n8s[NSEG] = { NW8, NW8, NW8, NW8, NW8, NW8, NW8, NW8,
                                NF8, NF8, DD * LATD / 8, LATD * DD / 8,
                                M * LATD / 8, BB * LCC * DD / 8 };
        int acc = 0;
        for (int i = 0; i < NSEG; i++) {
            a.src[i] = srcs[i]; a.dst[i] = dsts[i]; a.n8[i] = n8s[i];
            a.beg[i] = acc; acc += (n8s[i] + 255) / 256;
        }
        a.beg[NSEG] = acc;
        k_cvtm<<<acc, T256, 0, stream>>>(a);
    }

    // ---- time embedding path ----
    k_emb<<<(BB * DD + 255) / 256, 256, 0, stream>>>(tarr, emb);
    k_wlin<<<(BB * DFFN) / 4, T256, 0, stream>>>(emb, DD, tm1w, tm1b, h1t, DFFN, 2);
    k_wlin<<<(BB * DD) / 4,   T256, 0, stream>>>(h1t, DFFN, tm2w, tm2b, te, DD, 0);
    k_wlin<<<(BB * DD) / 4,   T256, 0, stream>>>(te, DD, ttw, ttb, ttv, DD, 0);

    // ---- all-layer cross K: kbc6[L] = cond @ ckw[L]^T (z = layer) ----
    k_g128b<false, 0><<<dim3(DD / 128, (BB * LCC) / 128, NLAYER), T256, 0, stream>>>(
        cdb, 0, DD, cwk, WST, DD, kbc6, (long long)BB * LCC * DD, DD, DD, 0, 0);
    // ---- all-layer cross V (transposed): vcT6[L] ----
    k_g128b<true, 7><<<dim3(DD / 128, (BB * LCC) / 128, NLAYER), T256, 0, stream>>>(
        cdb, 0, DD, cwv, WST, DD, vcT6, (long long)BB * HH * HD * LCC, DD, DD,
        ZWT, LCC);

    // ---- input projection: h = x_t @ pinw.T + pinb + ttv[b] ----
    k_g128<float, false><<<dim3(DD / 128, M / 128, 1), T256, 0, stream>>>(
        xtb, LATD, wpi, LATD, h, DD, LATD, pinb, ttv, DD, 9, 0, 0);

    for (int L = 0; L < NLAYER; L++) {
        const size_t LW = (size_t)L * DD * DD;

        // ======== self-attention with QGFD ========
        if (L == 0)
            k_ln<<<M / 4, LN_B, 0, stream>>>(h, xn,
                n1g + (size_t)L * DD, n1b + (size_t)L * DD);
        else
            k_ln2<4><<<M / 4, LN_B, 0, stream>>>(h, pp, ZP,
                f2b + (size_t)(L - 1) * DD, xn,
                n1g + (size_t)L * DD, n1b + (size_t)L * DD);

        // fused QKV (z: 0=q, 1=k, 2=v transposed)
        k_g128q<<<dim3(DD / 128, M / 128, 3), T256, 0, stream>>>(
            xn, DD, wq + LW, wk + LW, wv + LW, DD,
            qb, kb, vbT, DD, DD, ZVT, LQQ);

        // pass A: S+softmax, u=P@v, wT=(0.5u+0.5v)^T, P -> HBM (coalesced)
        k_attn1<<<dim3(1, LQQ / 64, BB * HH), T256, 0, stream>>>(
            qb, kb, vbT, ubT, Pg, 0.125f);

        // pass B: ob = P @ wT (no recompute)
        k_pw<<<dim3(1, LQQ / 64, BB * HH), T256, 0, stream>>>(Pg, ubT, ob);

        // ob @ ow.T -> split-K=2 partials
        k_g128<float, true><<<dim3(DD / 128, M / 128, 2), T256, 0, stream>>>(
            ob, DD, wo + LW, DD, pp, DD, 256, nullptr, nullptr, 0, 0, 0, ZP);

        // n2 LN + reduce wo partials + sa_ob bias
        k_ln2<2><<<M / 4, LN_B, 0, stream>>>(h, pp, ZP,
            sa_ob + (size_t)L * DD, xn,
            n2g + (size_t)L * DD, n2b + (size_t)L * DD);

        // ======== cross-attention (Q projection fused) ========
        k_attn0<<<dim3(1, LQQ / 64, BB * HH), T256, 0, stream>>>(
            xn, cwq + LW,
            kbc6 + (size_t)L * BB * LCC * DD, vcT6 + (size_t)L * BB * HH * HD * LCC,
            ob, cmask, 0.125f);

        // ob @ cow.T -> split-K=2 partials
        k_g128<float, true><<<dim3(DD / 128, M / 128, 2), T256, 0, stream>>>(
            ob, DD, cwo + LW, DD, pp, DD, 256, nullptr, nullptr, 0, 0, 0, ZP);

        // n3 LN + reduce cwo partials + ca_ob bias
        k_ln2<2><<<M / 4, LN_B, 0, stream>>>(h, pp, ZP,
            ca_ob + (size_t)L * DD, xn,
            n3g + (size_t)L * DD, n3b + (size_t)L * DD);

        // ======== FFN ========
        k_g128<u16, false><<<dim3(DFFN / 128, M / 128, 1), T256, 0, stream>>>(
            xn, DD, w1 + (size_t)L * DFFN * DD, DD,
            a1, DFFN, DD, f1b + (size_t)L * DFFN, nullptr, 0, 0, /*act=*/1, 0);

        // w2: split-K=4 partials (K=512/chunk, 256 blocks = 1/CU)
        k_g128<float, true><<<dim3(DD / 128, M / 128, 4), T256, 0, stream>>>(
            a1, DFFN, w2 + (size_t)L * DD * DFFN, DFFN, pp, DD, 512,
            nullptr, nullptr, 0, 0, 0, ZP);
    }

    // ---- final LN (+ last layer w2 partial reduce, NP=4) + output proj ----
    k_ln2<4><<<M / 4, LN_B, 0, stream>>>(h, pp, ZP,
        f2b + (size_t)(NLAYER - 1) * DD, xn, fng, fnb);
    k_g<32, 32, float, false><<<dim3(LATD / 32, M / 32, 1), T256, 0, stream>>>(
        xn, 0, 0, DD, wpo, nullptr, nullptr, 0, 0, DD,
        (float*)d_out, nullptr, nullptr, 0, 0, LATD,
        DD, 1, 1.0f, poutb, nullptr, 0, 0, 0.0f, nullptr, 0, 0, 0, 0, 0, 0, 0);
}